// Round 8
// baseline (642.674 us; speedup 1.0000x reference)
//
#include <hip/hip_runtime.h>

typedef unsigned short u16;
typedef unsigned int u32;
typedef unsigned long long u64;
typedef __attribute__((ext_vector_type(4))) float f32x4;
typedef __attribute__((ext_vector_type(8))) short bf16x8;   // 8 bf16 (4 VGPRs)
typedef __attribute__((ext_vector_type(4))) u16 u16x4;
typedef __attribute__((ext_vector_type(2))) u32 u32x2;

#define DEV __device__ __forceinline__

DEV u16 f2bf(float f) {               // RNE fp32 -> bf16
  union { float f; u32 u; } c; c.f = f;
  u32 u = c.u;
  u += 0x7fffu + ((u >> 16) & 1u);
  return (u16)(u >> 16);
}
DEV float bf2f(u16 h) {
  union { u32 u; float f; } c; c.u = ((u32)h) << 16;
  return c.f;
}
DEV u32 fbits(float f) { union { float f; u32 u; } c; c.f = f; return c.u; }
// pack two fp32 -> two truncated bf16 in one u32 (a = low, b = high)
DEV u32 packtrunc(float a, float b) {
  return (fbits(b) & 0xFFFF0000u) | (fbits(a) >> 16);
}

// async global->LDS, 16B per lane. Dest is WAVE-UNIFORM base + lane*16 (m104/m108).
DEV void gload_lds16(const void* g, void* l) {
  __builtin_amdgcn_global_load_lds(
      (const __attribute__((address_space(1))) u32*)(u64)g,
      (__attribute__((address_space(3))) u32*)(u32)(u64)l,   // low 32 bits = LDS offset
      16, 0, 0);
}

// ---------------- fused prep: x split + 6 weight transposes + mask pack ----------------
struct PrepW { const float* w; u16* th; u16* tl; int R, C, gxmask, gxshift; };
struct PrepArgs {
  const float* x; u16* xh; u16* xl;
  const int* mask; unsigned long long* mbits;
  PrepW pw[6];
};

__global__ __launch_bounds__(256) void prep(PrepArgs a) {
  __shared__ float t[32][33];
  int b = blockIdx.x, tid = threadIdx.x;
  if (b < 2048) {                       // x -> bf16 hi/lo
    int i = (b * 256 + tid) * 4;
    f32x4 v = *(const f32x4*)(a.x + i);
    u16x4 h, l;
#pragma unroll
    for (int j = 0; j < 4; ++j) { h[j] = f2bf(v[j]); l[j] = f2bf(v[j] - bf2f(h[j])); }
    *(u16x4*)(a.xh + i) = h;
    *(u16x4*)(a.xl + i) = l;
    return;
  }
  b -= 2048;
  if (b < 3072) {                       // weight (R,C) -> transposed hi(/lo) (C,R)
    int wi, base;
    if (b < 1024) { wi = b >> 8; base = b & 255; }
    else if (b < 2048) { wi = 4; base = b - 1024; }
    else { wi = 5; base = b - 2048; }
    PrepW p = a.pw[wi];
    int c0 = (base & p.gxmask) * 32, r0 = (base >> p.gxshift) * 32;
    int tx = tid & 31, ty = tid >> 5;
#pragma unroll
    for (int i = 0; i < 4; ++i)
      t[ty + 8 * i][tx] = p.w[(size_t)(r0 + ty + 8 * i) * p.C + c0 + tx];
    __syncthreads();
#pragma unroll
    for (int i = 0; i < 4; ++i) {
      float v = t[tx][ty + 8 * i];
      u16 h = f2bf(v);
      size_t o = (size_t)(c0 + ty + 8 * i) * p.R + r0 + tx;
      p.th[o] = h;
      if (p.tl) p.tl[o] = f2bf(v - bf2f(h));
    }
    return;
  }
  b -= 3072;                            // mask -> bitmask
  size_t i = (size_t)b * 256 + tid;
  unsigned long long bb = __ballot(a.mask[i] != 0);
  if ((tid & 63) == 0) a.mbits[i >> 6] = bb;
}

// ---------------- QKV GEMM: staged, hi/lo split (3 MFMA) ----------------
// z=0 -> Qh (prescaled by log2e), z=1 -> Kh, z=2 -> Vt (transposed bf16).
struct QkvArgs {
  const u16 *Ah, *Al;
  const u16 *Bh[3], *Bl[3];
  const float* bias[3];
  u16 *Qh, *Kh, *Vt;
};

__global__ __launch_bounds__(256) void gemm_qkv(QkvArgs a) {
  const int K = 512;
  const float L2E = 1.44269504088896340736f;
  const int z = blockIdx.z;
  const u16* __restrict__ Bh = a.Bh[z];
  const u16* __restrict__ Bl = a.Bl[z];
  const float* __restrict__ bias = a.bias[z];
  const int bn = blockIdx.x * 128, bm = blockIdx.y * 128;
  const int tid = threadIdx.x;
  const int wave = tid >> 6, lane = tid & 63;
  const int l16 = lane & 15, quad = lane >> 4;
  const int wm = (wave >> 1) * 64, wn = (wave & 1) * 64;

  __shared__ u16 sA[128 * 32];
  __shared__ u16 sB[128 * 32];
  __shared__ u16 sAl[128 * 32];
  __shared__ u16 sBl[128 * 32];

  const int srow = wave * 32 + (lane >> 2);
  const int scol = (lane & 3) * 8;
  const u16* srcA0 = a.Ah + (size_t)(bm + srow) * K + scol;
  const u16* srcB0 = Bh + (size_t)(bn + srow) * K + scol;
  const u16* srcAl0 = a.Al + (size_t)(bm + srow) * K + scol;
  const u16* srcBl0 = Bl + (size_t)(bn + srow) * K + scol;
  const size_t half_off = (size_t)16 * K;
  u16* dstA = sA + wave * 1024;
  u16* dstB = sB + wave * 1024;
  u16* dstAl = sAl + wave * 1024;
  u16* dstBl = sBl + wave * 1024;

  f32x4 acc[4][4] = {};

  for (int kt = 0; kt < K; kt += 32) {
    gload_lds16(srcA0 + kt, dstA);
    gload_lds16(srcA0 + half_off + kt, dstA + 512);
    gload_lds16(srcB0 + kt, dstB);
    gload_lds16(srcB0 + half_off + kt, dstB + 512);
    gload_lds16(srcAl0 + kt, dstAl);
    gload_lds16(srcAl0 + half_off + kt, dstAl + 512);
    gload_lds16(srcBl0 + kt, dstBl);
    gload_lds16(srcBl0 + half_off + kt, dstBl + 512);
    __syncthreads();

    bf16x8 a_h[4], b_h[4], a_l[4], b_l[4];
#pragma unroll
    for (int mt = 0; mt < 4; ++mt) {
      a_h[mt] = *(const bf16x8*)(sA + (wm + mt * 16 + l16) * 32 + quad * 8);
      a_l[mt] = *(const bf16x8*)(sAl + (wm + mt * 16 + l16) * 32 + quad * 8);
    }
#pragma unroll
    for (int nt = 0; nt < 4; ++nt) {
      b_h[nt] = *(const bf16x8*)(sB + (wn + nt * 16 + l16) * 32 + quad * 8);
      b_l[nt] = *(const bf16x8*)(sBl + (wn + nt * 16 + l16) * 32 + quad * 8);
    }
#pragma unroll
    for (int mt = 0; mt < 4; ++mt)
#pragma unroll
      for (int nt = 0; nt < 4; ++nt) {
        acc[mt][nt] = __builtin_amdgcn_mfma_f32_16x16x32_bf16(a_h[mt], b_h[nt], acc[mt][nt], 0, 0, 0);
        acc[mt][nt] = __builtin_amdgcn_mfma_f32_16x16x32_bf16(a_h[mt], b_l[nt], acc[mt][nt], 0, 0, 0);
        acc[mt][nt] = __builtin_amdgcn_mfma_f32_16x16x32_bf16(a_l[mt], b_h[nt], acc[mt][nt], 0, 0, 0);
      }
    __syncthreads();
  }

  if (z == 2) {
    // V: write transposed bf16 Vt[dim][seq]; r-regs are seq-contiguous -> 8B stores
#pragma unroll
    for (int nt = 0; nt < 4; ++nt) {
      int col = bn + wn + nt * 16 + l16;
      float bv = bias[col];
#pragma unroll
      for (int mt = 0; mt < 4; ++mt) {
        int row0 = bm + wm + mt * 16 + quad * 4;
        u16x4 o;
#pragma unroll
        for (int r = 0; r < 4; ++r) o[r] = f2bf(acc[mt][nt][r] + bv);
        *(u16x4*)(a.Vt + (size_t)col * 4096 + row0) = o;
      }
    }
  } else {
    u16* __restrict__ C = (z == 0) ? a.Qh : a.Kh;
    float scale = (z == 0) ? L2E : 1.f;
#pragma unroll
    for (int mt = 0; mt < 4; ++mt)
#pragma unroll
      for (int nt = 0; nt < 4; ++nt) {
        int col = bn + wn + nt * 16 + l16;
        float bv = bias[col];
#pragma unroll
        for (int r = 0; r < 4; ++r) {
          int row = bm + wm + mt * 16 + quad * 4 + r;
          C[(size_t)row * 512 + col] = f2bf((acc[mt][nt][r] + bv) * scale);
        }
      }
  }
}

// ---------------- generic staged GEMM, double-buffered, optional split-K ----------
// NSPLIT>1: fp32 atomicAdd partials (accumulator pre-zeroed by attn_combine);
// bias added by split 0 only.
template <int RELU, int BF16OUT, int NSPLIT>
__global__ __launch_bounds__(256) void gemm_bt(const u16* __restrict__ Ah,
                                               const u16* __restrict__ Bh,
                                               const float* __restrict__ bias,
                                               float* __restrict__ Cf,
                                               u16* __restrict__ Ch,
                                               int N, int K) {
  const int bn = blockIdx.x * 128, bm = blockIdx.y * 128;
  const int kbeg = blockIdx.z * (K / NSPLIT);
  const int tid = threadIdx.x;
  const int wave = tid >> 6, lane = tid & 63;
  const int l16 = lane & 15, quad = lane >> 4;
  const int wm = (wave >> 1) * 64, wn = (wave & 1) * 64;

  __shared__ u16 sA[2][128 * 32];
  __shared__ u16 sB[2][128 * 32];

  const int srow = wave * 32 + (lane >> 2);
  const int scol = (lane & 3) * 8;
  const u16* srcA0 = Ah + (size_t)(bm + srow) * K + kbeg + scol;
  const u16* srcB0 = Bh + (size_t)(bn + srow) * K + kbeg + scol;
  const size_t half_off = (size_t)16 * K;

  auto prefetchG = [&](int kt, int buf) {
    u16* dA = sA[buf] + wave * 1024;
    u16* dB = sB[buf] + wave * 1024;
    gload_lds16(srcA0 + kt, dA);
    gload_lds16(srcA0 + half_off + kt, dA + 512);
    gload_lds16(srcB0 + kt, dB);
    gload_lds16(srcB0 + half_off + kt, dB + 512);
  };

  f32x4 acc[4][4] = {};
  prefetchG(0, 0);

  const int steps = (K / NSPLIT) >> 5;
  for (int i = 0; i < steps; ++i) {
    __syncthreads();                       // drains prefetch issued one compute-phase ago
    if (i + 1 < steps) prefetchG((i + 1) << 5, (i + 1) & 1);
    const u16* bufA = sA[i & 1];
    const u16* bufB = sB[i & 1];

    bf16x8 a_h[4], b_h[4];
#pragma unroll
    for (int mt = 0; mt < 4; ++mt)
      a_h[mt] = *(const bf16x8*)(bufA + (wm + mt * 16 + l16) * 32 + quad * 8);
#pragma unroll
    for (int nt = 0; nt < 4; ++nt)
      b_h[nt] = *(const bf16x8*)(bufB + (wn + nt * 16 + l16) * 32 + quad * 8);
#pragma unroll
    for (int mt = 0; mt < 4; ++mt)
#pragma unroll
      for (int nt = 0; nt < 4; ++nt)
        acc[mt][nt] = __builtin_amdgcn_mfma_f32_16x16x32_bf16(a_h[mt], b_h[nt], acc[mt][nt], 0, 0, 0);
  }

#pragma unroll
  for (int mt = 0; mt < 4; ++mt)
#pragma unroll
    for (int nt = 0; nt < 4; ++nt) {
      int col = bn + wn + nt * 16 + l16;
      float bv = (bias && (NSPLIT == 1 || blockIdx.z == 0)) ? bias[col] : 0.f;
#pragma unroll
      for (int r = 0; r < 4; ++r) {
        int row = bm + wm + mt * 16 + quad * 4 + r;
        float v = acc[mt][nt][r] + bv;
        size_t oidx = (size_t)row * N + col;
        if (NSPLIT == 1) {
          if (RELU) v = fmaxf(v, 0.f);
          if (BF16OUT) Ch[oidx] = f2bf(v);
          else Cf[oidx] = v;
        } else {
          atomicAdd(&Cf[oidx], v);
        }
      }
    }
}

// ---------------- flash attention v5: S^T, 32q/wave, split-K x8, 26.6KB LDS ---------
// Grid (64 = 8h x 8chunk, 32 qb) = 2048 blocks; 6 blocks/CU by LDS, launch_bounds
// caps VGPR for 6 waves/EU. Q single bf16 (prescaled by log2e), K single bf16.
// P processed per 32-key half through a 10KB stride-40 LDS buffer; l accumulated
// in VALU (+2 end shuffles). Single K/V buffer (dbuf regressed occupancy in r7).
struct AttnIO { float* O[8]; float* lp; };

__global__ __launch_bounds__(256, 6) void attn(const u16* __restrict__ Qh,
                                               const u16* __restrict__ Kh,
                                               const u16* __restrict__ Vt,
                                               const u64* __restrict__ mb64,
                                               AttnIO io) {
  const int S = 4096, D = 512;
  const int h = blockIdx.x >> 3, chunk = blockIdx.x & 7;
  const int tid = threadIdx.x, wave = tid >> 6, lane = tid & 63;
  const int l16 = lane & 15, quad = lane >> 4;
  const int q0w = blockIdx.y * 128 + wave * 32;
  const int kbeg = chunk * 512;
  const int sw = l16 & 7;                       // bank-swizzle key

  __shared__ u16 sK[64 * 64];                   // [key][dim]   8 KB
  __shared__ u16 sV[64 * 64];                   // [dim][key]   8 KB
  __shared__ u16 sP[4][32 * 40];                // per-wave P, 32 keys, stride 40: 10 KB
  u16* myP = &sP[wave][0];

  const int skey = lane >> 3;
  const int sch  = lane & 7;
  const u16* srcK = Kh + (size_t)(kbeg + wave * 8 + skey) * D + h * 64 + ((sch ^ skey) * 8);
  const u16* srcV = Vt + (size_t)(h * 64 + wave * 8 + skey) * S + kbeg + ((sch ^ skey) * 8);
  u16* dstK = sK + wave * 512;
  u16* dstV = sV + wave * 512;

  // Q prefetch: B-frags (n=l16 -> q, k=quad*8 dims), single bf16
  bf16x8 qf[2][2];
#pragma unroll
  for (int qt = 0; qt < 2; ++qt)
#pragma unroll
    for (int kd = 0; kd < 2; ++kd)
      qf[qt][kd] = *(const bf16x8*)(Qh + (size_t)(q0w + qt * 16 + l16) * D + h * 64 + kd * 32 + quad * 8);

  f32x4 accO[2][4] = {};
  float l_lane[2] = {0.f, 0.f};
  const int wbase = kbeg >> 6;

  for (int it = 0; it < 8; ++it) {
    gload_lds16(srcK, dstK);
    gload_lds16(srcK + (size_t)32 * D, dstK + 32 * 64);
    gload_lds16(srcV, dstV);
    gload_lds16(srcV + (size_t)32 * S, dstV + 32 * 64);
    srcK += (size_t)64 * D; srcV += 64;
    __syncthreads();

    u64 wm[2];
#pragma unroll
    for (int qt = 0; qt < 2; ++qt)
      wm[qt] = mb64[(size_t)(q0w + qt * 16 + l16) * 64 + wbase + it];

#pragma unroll
    for (int half = 0; half < 2; ++half) {
      f32x4 sc[2][2];
#pragma unroll
      for (int k2 = 0; k2 < 2; ++k2) {
        const int kt4 = half * 2 + k2;
        const u16* arow = sK + (kt4 * 16 + l16) * 64;
        bf16x8 ka0 = *(const bf16x8*)(arow + ((quad ^ sw) * 8));
        bf16x8 ka1 = *(const bf16x8*)(arow + (((4 + quad) ^ sw) * 8));
#pragma unroll
        for (int qt = 0; qt < 2; ++qt) {
          f32x4 s = {};
          s = __builtin_amdgcn_mfma_f32_16x16x32_bf16(ka0, qf[qt][0], s, 0, 0, 0);
          s = __builtin_amdgcn_mfma_f32_16x16x32_bf16(ka1, qf[qt][1], s, 0, 0, 0);
          sc[k2][qt] = s;
        }
      }
      // mask + exp2 + l + pack into P (32-key half)
#pragma unroll
      for (int k2 = 0; k2 < 2; ++k2) {
        const int baseb = half * 32 + k2 * 16 + quad * 4;
#pragma unroll
        for (int qt = 0; qt < 2; ++qt) {
          float p[4];
#pragma unroll
          for (int r = 0; r < 4; ++r) {
            bool keep = (wm[qt] >> (baseb + r)) & 1ull;
            p[r] = exp2f(keep ? sc[k2][qt][r] : -1e9f);
          }
          l_lane[qt] += (p[0] + p[1]) + (p[2] + p[3]);
          u32x2 pk = {packtrunc(p[0], p[1]), packtrunc(p[2], p[3])};
          *(u32x2*)(myP + (qt * 16 + l16) * 40 + k2 * 16 + quad * 4) = pk;
        }
      }
      // PV for this 32-key half (same-wave LDS RAW: compiler lgkmcnt orders it)
      bf16x8 pa[2];
#pragma unroll
      for (int qt = 0; qt < 2; ++qt)
        pa[qt] = *(const bf16x8*)(myP + (qt * 16 + l16) * 40 + quad * 8);
#pragma unroll
      for (int nt = 0; nt < 4; ++nt) {
        bf16x8 vf = *(const bf16x8*)(sV + (nt * 16 + l16) * 64 + (((half * 4 + quad) ^ sw) * 8));
#pragma unroll
        for (int qt = 0; qt < 2; ++qt)
          accO[qt][nt] = __builtin_amdgcn_mfma_f32_16x16x32_bf16(pa[qt], vf, accO[qt][nt], 0, 0, 0);
      }
    }
    __syncthreads();   // all waves done reading K/V before next stage
  }

  // l: sum the 4 quads of each q (q = l16 in the sc layout)
#pragma unroll
  for (int qt = 0; qt < 2; ++qt) {
    float s = l_lane[qt];
    s += __shfl_xor(s, 16);
    s += __shfl_xor(s, 32);
    l_lane[qt] = s;
  }
  float* Op = io.O[chunk];
#pragma unroll
  for (int qt = 0; qt < 2; ++qt)
#pragma unroll
    for (int nt = 0; nt < 4; ++nt)
#pragma unroll
      for (int r = 0; r < 4; ++r) {
        int row = q0w + qt * 16 + quad * 4 + r;
        Op[((size_t)h * S + row) * 64 + nt * 16 + l16] = accO[qt][nt][r];
      }
  if (quad == 0)
#pragma unroll
    for (int qt = 0; qt < 2; ++qt)
      io.lp[((size_t)h * 8 + chunk) * S + q0w + qt * 16 + l16] = l_lane[qt];
}

// ---------------- combine 8 split-K partials -> ctx (bf16); zero OP/FF2 accumulators --
__global__ __launch_bounds__(256) void attn_combine(AttnIO io, u16* __restrict__ ctx) {
  const int S = 4096;
  int i = (blockIdx.x * 256 + threadIdx.x);
  int row = i >> 7;
  int col4 = (i & 127) * 4;
  int h = col4 >> 6, c = col4 & 63;
  size_t ob = ((size_t)h * S + row) * 64 + c;
  f32x4 o = {0.f, 0.f, 0.f, 0.f};
  float l = 0.f;
#pragma unroll
  for (int p = 0; p < 8; ++p) {
    o += *(const f32x4*)(io.O[p] + ob);
    l += io.lp[((size_t)h * 8 + p) * S + row];
  }
  float rl = 1.f / l;
  u16x4 out;
#pragma unroll
  for (int j = 0; j < 4; ++j) out[j] = f2bf(o[j] * rl);
  *(u16x4*)(ctx + (size_t)row * 512 + col4) = out;
  // zero the atomic accumulators for OP (O[0]=proj) and FF2 (O[2]=ff2)
  f32x4 z = {0.f, 0.f, 0.f, 0.f};
  *(f32x4*)(io.O[0] + ob) = z;
  *(f32x4*)(io.O[2] + ob) = z;
}

// ---------------- residual + layernorm (rows of 512) ----------------
__global__ __launch_bounds__(256) void resid_ln(const float* __restrict__ X,
                                                const float* __restrict__ Y,
                                                const float* __restrict__ g,
                                                const float* __restrict__ b,
                                                float* __restrict__ outF,
                                                u16* __restrict__ outH) {
  int row = blockIdx.x * 4 + (int)(threadIdx.x >> 6);
  int lane = threadIdx.x & 63;
  const float* x0 = X + (size_t)row * 512;
  const float* y0 = Y + (size_t)row * 512;
  int c0 = lane * 4, c1 = 256 + lane * 4;
  f32x4 v0 = *(const f32x4*)(x0 + c0) + *(const f32x4*)(y0 + c0);
  f32x4 v1 = *(const f32x4*)(x0 + c1) + *(const f32x4*)(y0 + c1);
  float s = 0.f, s2 = 0.f;
#pragma unroll
  for (int j = 0; j < 4; ++j) {
    s += v0[j] + v1[j];
    s2 += v0[j] * v0[j] + v1[j] * v1[j];
  }
#pragma unroll
  for (int m = 1; m < 64; m <<= 1) {
    s += __shfl_xor(s, m);
    s2 += __shfl_xor(s2, m);
  }
  float mean = s * (1.f / 512.f);
  float var = s2 * (1.f / 512.f) - mean * mean;
  float rs = rsqrtf(var + 1e-5f);
  f32x4 o0, o1;
#pragma unroll
  for (int j = 0; j < 4; ++j) {
    o0[j] = (v0[j] - mean) * rs * g[c0 + j] + b[c0 + j];
    o1[j] = (v1[j] - mean) * rs * g[c1 + j] + b[c1 + j];
  }
  if (outF) {
    *(f32x4*)(outF + (size_t)row * 512 + c0) = o0;
    *(f32x4*)(outF + (size_t)row * 512 + c1) = o1;
  }
  if (outH) {
    u16x4 h0, h1;
#pragma unroll
    for (int j = 0; j < 4; ++j) { h0[j] = f2bf(o0[j]); h1[j] = f2bf(o1[j]); }
    *(u16x4*)(outH + (size_t)row * 512 + c0) = h0;
    *(u16x4*)(outH + (size_t)row * 512 + c1) = h1;
  }
}

extern "C" void kernel_launch(void* const* d_in, const int* in_sizes, int n_in,
                              void* d_out, int out_size, void* d_ws, size_t ws_size,
                              hipStream_t stream) {
  (void)in_sizes; (void)n_in; (void)out_size; (void)ws_size;
  const float* x   = (const float*)d_in[0];
  const int*   mask= (const int*)d_in[1];
  const float* wq  = (const float*)d_in[2];
  const float* bq  = (const float*)d_in[3];
  const float* wk  = (const float*)d_in[4];
  const float* bk  = (const float*)d_in[5];
  const float* wv  = (const float*)d_in[6];
  const float* bv  = (const float*)d_in[7];
  const float* wo  = (const float*)d_in[8];
  const float* bo  = (const float*)d_in[9];
  const float* w1  = (const float*)d_in[10];
  const float* b1  = (const float*)d_in[11];
  const float* w2  = (const float*)d_in[12];
  const float* b2  = (const float*)d_in[13];
  const float* g1  = (const float*)d_in[14];
  const float* be1 = (const float*)d_in[15];
  const float* g2  = (const float*)d_in[16];
  const float* be2 = (const float*)d_in[17];

  const int S = 4096, D = 512, F = 2048;
  char* ws = (char*)d_ws;
  size_t cur = 0;
  auto alloc = [&](size_t bytes) {
    char* p = ws + cur;
    cur += (bytes + 255) & ~(size_t)255;
    return p;
  };
  u16* wqT_h = (u16*)alloc((size_t)D * D * 2); u16* wqT_l = (u16*)alloc((size_t)D * D * 2);
  u16* wkT_h = (u16*)alloc((size_t)D * D * 2); u16* wkT_l = (u16*)alloc((size_t)D * D * 2);
  u16* wvT_h = (u16*)alloc((size_t)D * D * 2); u16* wvT_l = (u16*)alloc((size_t)D * D * 2);
  u16* woT_h = (u16*)alloc((size_t)D * D * 2);
  u16* w1T_h = (u16*)alloc((size_t)D * F * 2);
  u16* w2T_h = (u16*)alloc((size_t)D * F * 2);
  u32* mbits = (u32*)alloc((size_t)S * S / 8);
  u16* xh = (u16*)alloc((size_t)S * D * 2);
  u16* xl = (u16*)alloc((size_t)S * D * 2);
  // Qh,Kh,Vt contiguous (12MB); FF1's 16MB hbuf spans Qh..Vt+ctx
  u16* Qh = (u16*)alloc((size_t)S * D * 2);
  u16* Kh = (u16*)alloc((size_t)S * D * 2);
  u16* Vt = (u16*)alloc((size_t)S * D * 2);
  u16* hx = (u16*)alloc((size_t)S * D * 2);    // 4th quarter of hbuf
  u16* ctx = (u16*)alloc((size_t)S * D * 2);
  float* x1 = (float*)alloc((size_t)S * D * 4);
  u16* x1h = (u16*)alloc((size_t)S * D * 2);
  float* Oex = (float*)alloc((size_t)6 * S * D * 4);   // O2..O7 (48MB fresh)
  // aliases (lifetimes disjoint by stream order):
  AttnIO io;
  io.O[0] = (float*)xh;            // 8MB over xh+xl (dead after QKV gemm)
  io.O[1] = x1;                    // 8MB (x1 written later by resid_ln)
  for (int p = 2; p < 8; ++p) io.O[p] = Oex + (size_t)(p - 2) * S * D;
  io.lp = (float*)x1h;             // 2MB (x1h written later by resid_ln)
  float* proj = (float*)xh;        // OP atomic accumulator (= O[0], zeroed by combine)
  u16* hbuf = Qh;                  // FF1 output (16MB over Qh,Kh,Vt,hx), after attn
  float* ff2 = Oex;                // FF2 atomic accumulator (= O[2], zeroed by combine)

  PrepArgs pa;
  pa.x = x; pa.xh = xh; pa.xl = xl;
  pa.mask = mask; pa.mbits = (unsigned long long*)mbits;
  pa.pw[0] = {wq, wqT_h, wqT_l, D, D, 15, 4};
  pa.pw[1] = {wk, wkT_h, wkT_l, D, D, 15, 4};
  pa.pw[2] = {wv, wvT_h, wvT_l, D, D, 15, 4};
  pa.pw[3] = {wo, woT_h, nullptr, D, D, 15, 4};
  pa.pw[4] = {w1, w1T_h, nullptr, D, F, 63, 6};
  pa.pw[5] = {w2, w2T_h, nullptr, F, D, 15, 4};

  QkvArgs qa;
  qa.Ah = xh; qa.Al = xl;
  qa.Bh[0] = wqT_h; qa.Bh[1] = wkT_h; qa.Bh[2] = wvT_h;
  qa.Bl[0] = wqT_l; qa.Bl[1] = wkT_l; qa.Bl[2] = wvT_l;
  qa.bias[0] = bq; qa.bias[1] = bk; qa.bias[2] = bv;
  qa.Qh = Qh; qa.Kh = Kh; qa.Vt = Vt;

  // 1. fused prep
  prep<<<70656, 256, 0, stream>>>(pa);
  // 2. QKV projection (Q prescaled bf16, K bf16, V transposed)
  gemm_qkv<<<dim3(4, 32, 3), 256, 0, stream>>>(qa);
  // 3. flash attention (split-K x8) + combine (also zeroes OP/FF2 accumulators)
  attn<<<dim3(64, 32), 256, 0, stream>>>(Qh, Kh, Vt, (const u64*)mbits, io);
  attn_combine<<<(S * D / 4) / 256, 256, 0, stream>>>(io, ctx);
  // 4. output projection, split-K x4 atomic -> proj fp32
  gemm_bt<0, 0, 4><<<dim3(4, 32, 4), 256, 0, stream>>>(ctx, woT_h, bo, proj, nullptr, D, D);
  // 5. residual + LN1
  resid_ln<<<S / 4, 256, 0, stream>>>(x, proj, g1, be1, x1, x1h);
  // 6. FFN: FF1 direct, FF2 split-K x4 atomic
  gemm_bt<1, 1, 1><<<dim3(16, 32, 1), 256, 0, stream>>>(x1h, w1T_h, b1, nullptr, hbuf, F, D);
  gemm_bt<0, 0, 4><<<dim3(4, 32, 4), 256, 0, stream>>>(hbuf, w2T_h, b2, ff2, nullptr, D, F);
  // 7. residual + LN2 -> final fp32 output
  resid_ln<<<S / 4, 256, 0, stream>>>(x1, ff2, g2, be2, (float*)d_out, nullptr);
}

// Round 9
// 375.205 us; speedup vs baseline: 1.7129x; 1.7129x over previous
//
#include <hip/hip_runtime.h>

typedef unsigned short u16;
typedef unsigned int u32;
typedef unsigned long long u64;
typedef __attribute__((ext_vector_type(4))) float f32x4;
typedef __attribute__((ext_vector_type(8))) short bf16x8;   // 8 bf16 (4 VGPRs)
typedef __attribute__((ext_vector_type(4))) u16 u16x4;
typedef __attribute__((ext_vector_type(2))) u32 u32x2;

#define DEV __device__ __forceinline__

DEV u16 f2bf(float f) {               // RNE fp32 -> bf16
  union { float f; u32 u; } c; c.f = f;
  u32 u = c.u;
  u += 0x7fffu + ((u >> 16) & 1u);
  return (u16)(u >> 16);
}
DEV float bf2f(u16 h) {
  union { u32 u; float f; } c; c.u = ((u32)h) << 16;
  return c.f;
}
DEV u32 fbits(float f) { union { float f; u32 u; } c; c.f = f; return c.u; }
// pack two fp32 -> two truncated bf16 in one u32 (a = low, b = high)
DEV u32 packtrunc(float a, float b) {
  return (fbits(b) & 0xFFFF0000u) | (fbits(a) >> 16);
}

// async global->LDS, 16B per lane. Dest is WAVE-UNIFORM base + lane*16 (m104/m108).
DEV void gload_lds16(const void* g, void* l) {
  __builtin_amdgcn_global_load_lds(
      (const __attribute__((address_space(1))) u32*)(u64)g,
      (__attribute__((address_space(3))) u32*)(u32)(u64)l,   // low 32 bits = LDS offset
      16, 0, 0);
}

// ---------------- fused prep: x split + 6 weight transposes + mask pack ----------------
struct PrepW { const float* w; u16* th; u16* tl; int R, C, gxmask, gxshift; };
struct PrepArgs {
  const float* x; u16* xh; u16* xl;
  const int* mask; unsigned long long* mbits;
  PrepW pw[6];
};

__global__ __launch_bounds__(256) void prep(PrepArgs a) {
  __shared__ float t[32][33];
  int b = blockIdx.x, tid = threadIdx.x;
  if (b < 2048) {                       // x -> bf16 hi/lo
    int i = (b * 256 + tid) * 4;
    f32x4 v = *(const f32x4*)(a.x + i);
    u16x4 h, l;
#pragma unroll
    for (int j = 0; j < 4; ++j) { h[j] = f2bf(v[j]); l[j] = f2bf(v[j] - bf2f(h[j])); }
    *(u16x4*)(a.xh + i) = h;
    *(u16x4*)(a.xl + i) = l;
    return;
  }
  b -= 2048;
  if (b < 3072) {                       // weight (R,C) -> transposed hi(/lo) (C,R)
    int wi, base;
    if (b < 1024) { wi = b >> 8; base = b & 255; }
    else if (b < 2048) { wi = 4; base = b - 1024; }
    else { wi = 5; base = b - 2048; }
    PrepW p = a.pw[wi];
    int c0 = (base & p.gxmask) * 32, r0 = (base >> p.gxshift) * 32;
    int tx = tid & 31, ty = tid >> 5;
#pragma unroll
    for (int i = 0; i < 4; ++i)
      t[ty + 8 * i][tx] = p.w[(size_t)(r0 + ty + 8 * i) * p.C + c0 + tx];
    __syncthreads();
#pragma unroll
    for (int i = 0; i < 4; ++i) {
      float v = t[tx][ty + 8 * i];
      u16 h = f2bf(v);
      size_t o = (size_t)(c0 + ty + 8 * i) * p.R + r0 + tx;
      p.th[o] = h;
      if (p.tl) p.tl[o] = f2bf(v - bf2f(h));
    }
    return;
  }
  b -= 3072;                            // mask -> bitmask
  size_t i = (size_t)b * 256 + tid;
  unsigned long long bb = __ballot(a.mask[i] != 0);
  if ((tid & 63) == 0) a.mbits[i >> 6] = bb;
}

// ---------------- QKV GEMM: staged, hi/lo split (3 MFMA) ----------------
// z=0 -> Qh (prescaled by log2e), z=1 -> Kh, z=2 -> Vt (transposed bf16).
struct QkvArgs {
  const u16 *Ah, *Al;
  const u16 *Bh[3], *Bl[3];
  const float* bias[3];
  u16 *Qh, *Kh, *Vt;
};

__global__ __launch_bounds__(256) void gemm_qkv(QkvArgs a) {
  const int K = 512;
  const float L2E = 1.44269504088896340736f;
  const int z = blockIdx.z;
  const u16* __restrict__ Bh = a.Bh[z];
  const u16* __restrict__ Bl = a.Bl[z];
  const float* __restrict__ bias = a.bias[z];
  const int bn = blockIdx.x * 128, bm = blockIdx.y * 128;
  const int tid = threadIdx.x;
  const int wave = tid >> 6, lane = tid & 63;
  const int l16 = lane & 15, quad = lane >> 4;
  const int wm = (wave >> 1) * 64, wn = (wave & 1) * 64;

  __shared__ u16 sA[128 * 32];
  __shared__ u16 sB[128 * 32];
  __shared__ u16 sAl[128 * 32];
  __shared__ u16 sBl[128 * 32];

  const int srow = wave * 32 + (lane >> 2);
  const int scol = (lane & 3) * 8;
  const u16* srcA0 = a.Ah + (size_t)(bm + srow) * K + scol;
  const u16* srcB0 = Bh + (size_t)(bn + srow) * K + scol;
  const u16* srcAl0 = a.Al + (size_t)(bm + srow) * K + scol;
  const u16* srcBl0 = Bl + (size_t)(bn + srow) * K + scol;
  const size_t half_off = (size_t)16 * K;
  u16* dstA = sA + wave * 1024;
  u16* dstB = sB + wave * 1024;
  u16* dstAl = sAl + wave * 1024;
  u16* dstBl = sBl + wave * 1024;

  f32x4 acc[4][4] = {};

  for (int kt = 0; kt < K; kt += 32) {
    gload_lds16(srcA0 + kt, dstA);
    gload_lds16(srcA0 + half_off + kt, dstA + 512);
    gload_lds16(srcB0 + kt, dstB);
    gload_lds16(srcB0 + half_off + kt, dstB + 512);
    gload_lds16(srcAl0 + kt, dstAl);
    gload_lds16(srcAl0 + half_off + kt, dstAl + 512);
    gload_lds16(srcBl0 + kt, dstBl);
    gload_lds16(srcBl0 + half_off + kt, dstBl + 512);
    __syncthreads();

    bf16x8 a_h[4], b_h[4], a_l[4], b_l[4];
#pragma unroll
    for (int mt = 0; mt < 4; ++mt) {
      a_h[mt] = *(const bf16x8*)(sA + (wm + mt * 16 + l16) * 32 + quad * 8);
      a_l[mt] = *(const bf16x8*)(sAl + (wm + mt * 16 + l16) * 32 + quad * 8);
    }
#pragma unroll
    for (int nt = 0; nt < 4; ++nt) {
      b_h[nt] = *(const bf16x8*)(sB + (wn + nt * 16 + l16) * 32 + quad * 8);
      b_l[nt] = *(const bf16x8*)(sBl + (wn + nt * 16 + l16) * 32 + quad * 8);
    }
#pragma unroll
    for (int mt = 0; mt < 4; ++mt)
#pragma unroll
      for (int nt = 0; nt < 4; ++nt) {
        acc[mt][nt] = __builtin_amdgcn_mfma_f32_16x16x32_bf16(a_h[mt], b_h[nt], acc[mt][nt], 0, 0, 0);
        acc[mt][nt] = __builtin_amdgcn_mfma_f32_16x16x32_bf16(a_h[mt], b_l[nt], acc[mt][nt], 0, 0, 0);
        acc[mt][nt] = __builtin_amdgcn_mfma_f32_16x16x32_bf16(a_l[mt], b_h[nt], acc[mt][nt], 0, 0, 0);
      }
    __syncthreads();
  }

  if (z == 2) {
    // V: write transposed bf16 Vt[dim][seq]; r-regs are seq-contiguous -> 8B stores
#pragma unroll
    for (int nt = 0; nt < 4; ++nt) {
      int col = bn + wn + nt * 16 + l16;
      float bv = bias[col];
#pragma unroll
      for (int mt = 0; mt < 4; ++mt) {
        int row0 = bm + wm + mt * 16 + quad * 4;
        u16x4 o;
#pragma unroll
        for (int r = 0; r < 4; ++r) o[r] = f2bf(acc[mt][nt][r] + bv);
        *(u16x4*)(a.Vt + (size_t)col * 4096 + row0) = o;
      }
    }
  } else {
    u16* __restrict__ C = (z == 0) ? a.Qh : a.Kh;
    float scale = (z == 0) ? L2E : 1.f;
#pragma unroll
    for (int mt = 0; mt < 4; ++mt)
#pragma unroll
      for (int nt = 0; nt < 4; ++nt) {
        int col = bn + wn + nt * 16 + l16;
        float bv = bias[col];
#pragma unroll
        for (int r = 0; r < 4; ++r) {
          int row = bm + wm + mt * 16 + quad * 4 + r;
          C[(size_t)row * 512 + col] = f2bf((acc[mt][nt][r] + bv) * scale);
        }
      }
  }
}

// ---------------- generic staged GEMM, double-buffered, optional split-K ----------
// NSPLIT>1: fp32 atomicAdd partials (accumulator pre-zeroed by attn_combine);
// bias added by split 0 only.
template <int RELU, int BF16OUT, int NSPLIT>
__global__ __launch_bounds__(256) void gemm_bt(const u16* __restrict__ Ah,
                                               const u16* __restrict__ Bh,
                                               const float* __restrict__ bias,
                                               float* __restrict__ Cf,
                                               u16* __restrict__ Ch,
                                               int N, int K) {
  const int bn = blockIdx.x * 128, bm = blockIdx.y * 128;
  const int kbeg = blockIdx.z * (K / NSPLIT);
  const int tid = threadIdx.x;
  const int wave = tid >> 6, lane = tid & 63;
  const int l16 = lane & 15, quad = lane >> 4;
  const int wm = (wave >> 1) * 64, wn = (wave & 1) * 64;

  __shared__ u16 sA[2][128 * 32];
  __shared__ u16 sB[2][128 * 32];

  const int srow = wave * 32 + (lane >> 2);
  const int scol = (lane & 3) * 8;
  const u16* srcA0 = Ah + (size_t)(bm + srow) * K + kbeg + scol;
  const u16* srcB0 = Bh + (size_t)(bn + srow) * K + kbeg + scol;
  const size_t half_off = (size_t)16 * K;

  auto prefetchG = [&](int kt, int buf) {
    u16* dA = sA[buf] + wave * 1024;
    u16* dB = sB[buf] + wave * 1024;
    gload_lds16(srcA0 + kt, dA);
    gload_lds16(srcA0 + half_off + kt, dA + 512);
    gload_lds16(srcB0 + kt, dB);
    gload_lds16(srcB0 + half_off + kt, dB + 512);
  };

  f32x4 acc[4][4] = {};
  prefetchG(0, 0);

  const int steps = (K / NSPLIT) >> 5;
  for (int i = 0; i < steps; ++i) {
    __syncthreads();                       // drains prefetch issued one compute-phase ago
    if (i + 1 < steps) prefetchG((i + 1) << 5, (i + 1) & 1);
    const u16* bufA = sA[i & 1];
    const u16* bufB = sB[i & 1];

    bf16x8 a_h[4], b_h[4];
#pragma unroll
    for (int mt = 0; mt < 4; ++mt)
      a_h[mt] = *(const bf16x8*)(bufA + (wm + mt * 16 + l16) * 32 + quad * 8);
#pragma unroll
    for (int nt = 0; nt < 4; ++nt)
      b_h[nt] = *(const bf16x8*)(bufB + (wn + nt * 16 + l16) * 32 + quad * 8);
#pragma unroll
    for (int mt = 0; mt < 4; ++mt)
#pragma unroll
      for (int nt = 0; nt < 4; ++nt)
        acc[mt][nt] = __builtin_amdgcn_mfma_f32_16x16x32_bf16(a_h[mt], b_h[nt], acc[mt][nt], 0, 0, 0);
  }

#pragma unroll
  for (int mt = 0; mt < 4; ++mt)
#pragma unroll
    for (int nt = 0; nt < 4; ++nt) {
      int col = bn + wn + nt * 16 + l16;
      float bv = (bias && (NSPLIT == 1 || blockIdx.z == 0)) ? bias[col] : 0.f;
#pragma unroll
      for (int r = 0; r < 4; ++r) {
        int row = bm + wm + mt * 16 + quad * 4 + r;
        float v = acc[mt][nt][r] + bv;
        size_t oidx = (size_t)row * N + col;
        if (NSPLIT == 1) {
          if (RELU) v = fmaxf(v, 0.f);
          if (BF16OUT) Ch[oidx] = f2bf(v);
          else Cf[oidx] = v;
        } else {
          atomicAdd(&Cf[oidx], v);
        }
      }
    }
}

// ---------------- flash attention v5b: S^T, 32q/wave, split-K x8, 26.6KB LDS ---------
// Grid (64 = 8h x 8chunk, 32 qb) = 2048 blocks; 6 blocks/CU by LDS.
// NO min-waves launch_bounds clause: r8's (256,6) capped VGPRs at ~85 and the
// compiler SPILLED accO/qf to scratch -> 1.6 GB/dispatch of HBM spill traffic
// (VGPR_Count=40, FETCH 805MB). Natural allocation (~70-80 VGPRs) gives the
// same 6 blocks/CU without spills.
struct AttnIO { float* O[8]; float* lp; };

__global__ __launch_bounds__(256) void attn(const u16* __restrict__ Qh,
                                            const u16* __restrict__ Kh,
                                            const u16* __restrict__ Vt,
                                            const u64* __restrict__ mb64,
                                            AttnIO io) {
  const int S = 4096, D = 512;
  const int h = blockIdx.x >> 3, chunk = blockIdx.x & 7;
  const int tid = threadIdx.x, wave = tid >> 6, lane = tid & 63;
  const int l16 = lane & 15, quad = lane >> 4;
  const int q0w = blockIdx.y * 128 + wave * 32;
  const int kbeg = chunk * 512;
  const int sw = l16 & 7;                       // bank-swizzle key

  __shared__ u16 sK[64 * 64];                   // [key][dim]   8 KB
  __shared__ u16 sV[64 * 64];                   // [dim][key]   8 KB
  __shared__ u16 sP[4][32 * 40];                // per-wave P, 32 keys, stride 40: 10 KB
  u16* myP = &sP[wave][0];

  const int skey = lane >> 3;
  const int sch  = lane & 7;
  const u16* srcK = Kh + (size_t)(kbeg + wave * 8 + skey) * D + h * 64 + ((sch ^ skey) * 8);
  const u16* srcV = Vt + (size_t)(h * 64 + wave * 8 + skey) * S + kbeg + ((sch ^ skey) * 8);
  u16* dstK = sK + wave * 512;
  u16* dstV = sV + wave * 512;

  // Q prefetch: B-frags (n=l16 -> q, k=quad*8 dims), single bf16
  bf16x8 qf[2][2];
#pragma unroll
  for (int qt = 0; qt < 2; ++qt)
#pragma unroll
    for (int kd = 0; kd < 2; ++kd)
      qf[qt][kd] = *(const bf16x8*)(Qh + (size_t)(q0w + qt * 16 + l16) * D + h * 64 + kd * 32 + quad * 8);

  f32x4 accO[2][4] = {};
  float l_lane[2] = {0.f, 0.f};
  const int wbase = kbeg >> 6;

  for (int it = 0; it < 8; ++it) {
    gload_lds16(srcK, dstK);
    gload_lds16(srcK + (size_t)32 * D, dstK + 32 * 64);
    gload_lds16(srcV, dstV);
    gload_lds16(srcV + (size_t)32 * S, dstV + 32 * 64);
    srcK += (size_t)64 * D; srcV += 64;
    __syncthreads();

    u64 wm[2];
#pragma unroll
    for (int qt = 0; qt < 2; ++qt)
      wm[qt] = mb64[(size_t)(q0w + qt * 16 + l16) * 64 + wbase + it];

#pragma unroll
    for (int half = 0; half < 2; ++half) {
      f32x4 sc[2][2];
#pragma unroll
      for (int k2 = 0; k2 < 2; ++k2) {
        const int kt4 = half * 2 + k2;
        const u16* arow = sK + (kt4 * 16 + l16) * 64;
        bf16x8 ka0 = *(const bf16x8*)(arow + ((quad ^ sw) * 8));
        bf16x8 ka1 = *(const bf16x8*)(arow + (((4 + quad) ^ sw) * 8));
#pragma unroll
        for (int qt = 0; qt < 2; ++qt) {
          f32x4 s = {};
          s = __builtin_amdgcn_mfma_f32_16x16x32_bf16(ka0, qf[qt][0], s, 0, 0, 0);
          s = __builtin_amdgcn_mfma_f32_16x16x32_bf16(ka1, qf[qt][1], s, 0, 0, 0);
          sc[k2][qt] = s;
        }
      }
      // mask + exp2 + l + pack into P (32-key half)
#pragma unroll
      for (int k2 = 0; k2 < 2; ++k2) {
        const int baseb = half * 32 + k2 * 16 + quad * 4;
#pragma unroll
        for (int qt = 0; qt < 2; ++qt) {
          float p[4];
#pragma unroll
          for (int r = 0; r < 4; ++r) {
            bool keep = (wm[qt] >> (baseb + r)) & 1ull;
            p[r] = exp2f(keep ? sc[k2][qt][r] : -1e9f);
          }
          l_lane[qt] += (p[0] + p[1]) + (p[2] + p[3]);
          u32x2 pk = {packtrunc(p[0], p[1]), packtrunc(p[2], p[3])};
          *(u32x2*)(myP + (qt * 16 + l16) * 40 + k2 * 16 + quad * 4) = pk;
        }
      }
      // PV for this 32-key half (same-wave LDS RAW: compiler lgkmcnt orders it)
      bf16x8 pa[2];
#pragma unroll
      for (int qt = 0; qt < 2; ++qt)
        pa[qt] = *(const bf16x8*)(myP + (qt * 16 + l16) * 40 + quad * 8);
#pragma unroll
      for (int nt = 0; nt < 4; ++nt) {
        bf16x8 vf = *(const bf16x8*)(sV + (nt * 16 + l16) * 64 + (((half * 4 + quad) ^ sw) * 8));
#pragma unroll
        for (int qt = 0; qt < 2; ++qt)
          accO[qt][nt] = __builtin_amdgcn_mfma_f32_16x16x32_bf16(pa[qt], vf, accO[qt][nt], 0, 0, 0);
      }
    }
    __syncthreads();   // all waves done reading K/V before next stage
  }

  // l: sum the 4 quads of each q (q = l16 in the sc layout)
#pragma unroll
  for (int qt = 0; qt < 2; ++qt) {
    float s = l_lane[qt];
    s += __shfl_xor(s, 16);
    s += __shfl_xor(s, 32);
    l_lane[qt] = s;
  }
  float* Op = io.O[chunk];
#pragma unroll
  for (int qt = 0; qt < 2; ++qt)
#pragma unroll
    for (int nt = 0; nt < 4; ++nt)
#pragma unroll
      for (int r = 0; r < 4; ++r) {
        int row = q0w + qt * 16 + quad * 4 + r;
        Op[((size_t)h * S + row) * 64 + nt * 16 + l16] = accO[qt][nt][r];
      }
  if (quad == 0)
#pragma unroll
    for (int qt = 0; qt < 2; ++qt)
      io.lp[((size_t)h * 8 + chunk) * S + q0w + qt * 16 + l16] = l_lane[qt];
}

// ---------------- combine 8 split-K partials -> ctx (bf16); zero OP/FF2 accumulators --
__global__ __launch_bounds__(256) void attn_combine(AttnIO io, u16* __restrict__ ctx) {
  const int S = 4096;
  int i = (blockIdx.x * 256 + threadIdx.x);
  int row = i >> 7;
  int col4 = (i & 127) * 4;
  int h = col4 >> 6, c = col4 & 63;
  size_t ob = ((size_t)h * S + row) * 64 + c;
  f32x4 o = {0.f, 0.f, 0.f, 0.f};
  float l = 0.f;
#pragma unroll
  for (int p = 0; p < 8; ++p) {
    o += *(const f32x4*)(io.O[p] + ob);
    l += io.lp[((size_t)h * 8 + p) * S + row];
  }
  float rl = 1.f / l;
  u16x4 out;
#pragma unroll
  for (int j = 0; j < 4; ++j) out[j] = f2bf(o[j] * rl);
  *(u16x4*)(ctx + (size_t)row * 512 + col4) = out;
  // zero the atomic accumulators for OP (O[0]=proj) and FF2 (O[2]=ff2)
  f32x4 z = {0.f, 0.f, 0.f, 0.f};
  *(f32x4*)(io.O[0] + ob) = z;
  *(f32x4*)(io.O[2] + ob) = z;
}

// ---------------- residual + layernorm (rows of 512) ----------------
__global__ __launch_bounds__(256) void resid_ln(const float* __restrict__ X,
                                                const float* __restrict__ Y,
                                                const float* __restrict__ g,
                                                const float* __restrict__ b,
                                                float* __restrict__ outF,
                                                u16* __restrict__ outH) {
  int row = blockIdx.x * 4 + (int)(threadIdx.x >> 6);
  int lane = threadIdx.x & 63;
  const float* x0 = X + (size_t)row * 512;
  const float* y0 = Y + (size_t)row * 512;
  int c0 = lane * 4, c1 = 256 + lane * 4;
  f32x4 v0 = *(const f32x4*)(x0 + c0) + *(const f32x4*)(y0 + c0);
  f32x4 v1 = *(const f32x4*)(x0 + c1) + *(const f32x4*)(y0 + c1);
  float s = 0.f, s2 = 0.f;
#pragma unroll
  for (int j = 0; j < 4; ++j) {
    s += v0[j] + v1[j];
    s2 += v0[j] * v0[j] + v1[j] * v1[j];
  }
#pragma unroll
  for (int m = 1; m < 64; m <<= 1) {
    s += __shfl_xor(s, m);
    s2 += __shfl_xor(s2, m);
  }
  float mean = s * (1.f / 512.f);
  float var = s2 * (1.f / 512.f) - mean * mean;
  float rs = rsqrtf(var + 1e-5f);
  f32x4 o0, o1;
#pragma unroll
  for (int j = 0; j < 4; ++j) {
    o0[j] = (v0[j] - mean) * rs * g[c0 + j] + b[c0 + j];
    o1[j] = (v1[j] - mean) * rs * g[c1 + j] + b[c1 + j];
  }
  if (outF) {
    *(f32x4*)(outF + (size_t)row * 512 + c0) = o0;
    *(f32x4*)(outF + (size_t)row * 512 + c1) = o1;
  }
  if (outH) {
    u16x4 h0, h1;
#pragma unroll
    for (int j = 0; j < 4; ++j) { h0[j] = f2bf(o0[j]); h1[j] = f2bf(o1[j]); }
    *(u16x4*)(outH + (size_t)row * 512 + c0) = h0;
    *(u16x4*)(outH + (size_t)row * 512 + c1) = h1;
  }
}

extern "C" void kernel_launch(void* const* d_in, const int* in_sizes, int n_in,
                              void* d_out, int out_size, void* d_ws, size_t ws_size,
                              hipStream_t stream) {
  (void)in_sizes; (void)n_in; (void)out_size; (void)ws_size;
  const float* x   = (const float*)d_in[0];
  const int*   mask= (const int*)d_in[1];
  const float* wq  = (const float*)d_in[2];
  const float* bq  = (const float*)d_in[3];
  const float* wk  = (const float*)d_in[4];
  const float* bk  = (const float*)d_in[5];
  const float* wv  = (const float*)d_in[6];
  const float* bv  = (const float*)d_in[7];
  const float* wo  = (const float*)d_in[8];
  const float* bo  = (const float*)d_in[9];
  const float* w1  = (const float*)d_in[10];
  const float* b1  = (const float*)d_in[11];
  const float* w2  = (const float*)d_in[12];
  const float* b2  = (const float*)d_in[13];
  const float* g1  = (const float*)d_in[14];
  const float* be1 = (const float*)d_in[15];
  const float* g2  = (const float*)d_in[16];
  const float* be2 = (const float*)d_in[17];

  const int S = 4096, D = 512, F = 2048;
  char* ws = (char*)d_ws;
  size_t cur = 0;
  auto alloc = [&](size_t bytes) {
    char* p = ws + cur;
    cur += (bytes + 255) & ~(size_t)255;
    return p;
  };
  u16* wqT_h = (u16*)alloc((size_t)D * D * 2); u16* wqT_l = (u16*)alloc((size_t)D * D * 2);
  u16* wkT_h = (u16*)alloc((size_t)D * D * 2); u16* wkT_l = (u16*)alloc((size_t)D * D * 2);
  u16* wvT_h = (u16*)alloc((size_t)D * D * 2); u16* wvT_l = (u16*)alloc((size_t)D * D * 2);
  u16* woT_h = (u16*)alloc((size_t)D * D * 2);
  u16* w1T_h = (u16*)alloc((size_t)D * F * 2);
  u16* w2T_h = (u16*)alloc((size_t)D * F * 2);
  u32* mbits = (u32*)alloc((size_t)S * S / 8);
  u16* xh = (u16*)alloc((size_t)S * D * 2);
  u16* xl = (u16*)alloc((size_t)S * D * 2);
  // Qh,Kh,Vt contiguous (12MB); FF1's 16MB hbuf spans Qh..Vt+hx
  u16* Qh = (u16*)alloc((size_t)S * D * 2);
  u16* Kh = (u16*)alloc((size_t)S * D * 2);
  u16* Vt = (u16*)alloc((size_t)S * D * 2);
  u16* hx = (u16*)alloc((size_t)S * D * 2);    // 4th quarter of hbuf
  u16* ctx = (u16*)alloc((size_t)S * D * 2);
  float* x1 = (float*)alloc((size_t)S * D * 4);
  u16* x1h = (u16*)alloc((size_t)S * D * 2);
  float* Oex = (float*)alloc((size_t)6 * S * D * 4);   // O2..O7 (48MB fresh)
  // aliases (lifetimes disjoint by stream order):
  AttnIO io;
  io.O[0] = (float*)xh;            // 8MB over xh+xl (dead after QKV gemm)
  io.O[1] = x1;                    // 8MB (x1 written later by resid_ln)
  for (int p = 2; p < 8; ++p) io.O[p] = Oex + (size_t)(p - 2) * S * D;
  io.lp = (float*)x1h;             // 2MB (x1h written later by resid_ln)
  float* proj = (float*)xh;        // OP atomic accumulator (= O[0], zeroed by combine)
  u16* hbuf = Qh;                  // FF1 output (16MB over Qh,Kh,Vt,hx), after attn
  float* ff2 = Oex;                // FF2 atomic accumulator (= O[2], zeroed by combine)

  PrepArgs pa;
  pa.x = x; pa.xh = xh; pa.xl = xl;
  pa.mask = mask; pa.mbits = (unsigned long long*)mbits;
  pa.pw[0] = {wq, wqT_h, wqT_l, D, D, 15, 4};
  pa.pw[1] = {wk, wkT_h, wkT_l, D, D, 15, 4};
  pa.pw[2] = {wv, wvT_h, wvT_l, D, D, 15, 4};
  pa.pw[3] = {wo, woT_h, nullptr, D, D, 15, 4};
  pa.pw[4] = {w1, w1T_h, nullptr, D, F, 63, 6};
  pa.pw[5] = {w2, w2T_h, nullptr, F, D, 15, 4};

  QkvArgs qa;
  qa.Ah = xh; qa.Al = xl;
  qa.Bh[0] = wqT_h; qa.Bh[1] = wkT_h; qa.Bh[2] = wvT_h;
  qa.Bl[0] = wqT_l; qa.Bl[1] = wkT_l; qa.Bl[2] = wvT_l;
  qa.bias[0] = bq; qa.bias[1] = bk; qa.bias[2] = bv;
  qa.Qh = Qh; qa.Kh = Kh; qa.Vt = Vt;

  // 1. fused prep
  prep<<<70656, 256, 0, stream>>>(pa);
  // 2. QKV projection (Q prescaled bf16, K bf16, V transposed)
  gemm_qkv<<<dim3(4, 32, 3), 256, 0, stream>>>(qa);
  // 3. flash attention (split-K x8) + combine (also zeroes OP/FF2 accumulators)
  attn<<<dim3(64, 32), 256, 0, stream>>>(Qh, Kh, Vt, (const u64*)mbits, io);
  attn_combine<<<(S * D / 4) / 256, 256, 0, stream>>>(io, ctx);
  // 4. output projection, split-K x4 atomic -> proj fp32
  gemm_bt<0, 0, 4><<<dim3(4, 32, 4), 256, 0, stream>>>(ctx, woT_h, bo, proj, nullptr, D, D);
  // 5. residual + LN1
  resid_ln<<<S / 4, 256, 0, stream>>>(x, proj, g1, be1, x1, x1h);
  // 6. FFN: FF1 direct, FF2 split-K x4 atomic
  gemm_bt<1, 1, 1><<<dim3(16, 32, 1), 256, 0, stream>>>(x1h, w1T_h, b1, nullptr, hbuf, F, D);
  gemm_bt<0, 0, 4><<<dim3(4, 32, 4), 256, 0, stream>>>(hbuf, w2T_h, b2, ff2, nullptr, D, F);
  // 7. residual + LN2 -> final fp32 output
  resid_ln<<<S / 4, 256, 0, stream>>>(x1, ff2, g2, be2, (float*)d_out, nullptr);
}

// Round 10
// 340.533 us; speedup vs baseline: 1.8873x; 1.1018x over previous
//
#include <hip/hip_runtime.h>

typedef unsigned short u16;
typedef unsigned int u32;
typedef unsigned long long u64;
typedef __attribute__((ext_vector_type(4))) float f32x4;
typedef __attribute__((ext_vector_type(8))) short bf16x8;   // 8 bf16 (4 VGPRs)
typedef __attribute__((ext_vector_type(4))) u16 u16x4;
typedef __attribute__((ext_vector_type(2))) u32 u32x2;

#define DEV __device__ __forceinline__

DEV u16 f2bf(float f) {               // RNE fp32 -> bf16
  union { float f; u32 u; } c; c.f = f;
  u32 u = c.u;
  u += 0x7fffu + ((u >> 16) & 1u);
  return (u16)(u >> 16);
}
DEV float bf2f(u16 h) {
  union { u32 u; float f; } c; c.u = ((u32)h) << 16;
  return c.f;
}
DEV u32 fbits(float f) { union { float f; u32 u; } c; c.f = f; return c.u; }
// pack two fp32 -> two truncated bf16 in one u32 (a = low, b = high)
DEV u32 packtrunc(float a, float b) {
  return (fbits(b) & 0xFFFF0000u) | (fbits(a) >> 16);
}

// async global->LDS, 16B per lane. Dest is WAVE-UNIFORM base + lane*16 (m104/m108).
DEV void gload_lds16(const void* g, void* l) {
  __builtin_amdgcn_global_load_lds(
      (const __attribute__((address_space(1))) u32*)(u64)g,
      (__attribute__((address_space(3))) u32*)(u32)(u64)l,   // low 32 bits = LDS offset
      16, 0, 0);
}

// ---------------- fused prep: x split + 6 weight transposes (hi only) + mask pack -----
struct PrepW { const float* w; u16* th; u16* tl; int R, C, gxmask, gxshift; };
struct PrepArgs {
  const float* x; u16* xh; u16* xl;
  const int* mask; unsigned long long* mbits;
  PrepW pw[6];
};

__global__ __launch_bounds__(256) void prep(PrepArgs a) {
  __shared__ float t[32][33];
  int b = blockIdx.x, tid = threadIdx.x;
  if (b < 2048) {                       // x -> bf16 hi/lo
    int i = (b * 256 + tid) * 4;
    f32x4 v = *(const f32x4*)(a.x + i);
    u16x4 h, l;
#pragma unroll
    for (int j = 0; j < 4; ++j) { h[j] = f2bf(v[j]); l[j] = f2bf(v[j] - bf2f(h[j])); }
    *(u16x4*)(a.xh + i) = h;
    *(u16x4*)(a.xl + i) = l;
    return;
  }
  b -= 2048;
  if (b < 3072) {                       // weight (R,C) -> transposed (C,R)
    int wi, base;
    if (b < 1024) { wi = b >> 8; base = b & 255; }
    else if (b < 2048) { wi = 4; base = b - 1024; }
    else { wi = 5; base = b - 2048; }
    PrepW p = a.pw[wi];
    int c0 = (base & p.gxmask) * 32, r0 = (base >> p.gxshift) * 32;
    int tx = tid & 31, ty = tid >> 5;
#pragma unroll
    for (int i = 0; i < 4; ++i)
      t[ty + 8 * i][tx] = p.w[(size_t)(r0 + ty + 8 * i) * p.C + c0 + tx];
    __syncthreads();
#pragma unroll
    for (int i = 0; i < 4; ++i) {
      float v = t[tx][ty + 8 * i];
      u16 h = f2bf(v);
      size_t o = (size_t)(c0 + ty + 8 * i) * p.R + r0 + tx;
      p.th[o] = h;
      if (p.tl) p.tl[o] = f2bf(v - bf2f(h));
    }
    return;
  }
  b -= 3072;                            // mask -> bitmask
  size_t i = (size_t)b * 256 + tid;
  unsigned long long bb = __ballot(a.mask[i] != 0);
  if ((tid & 63) == 0) a.mbits[i >> 6] = bb;
}

// ---------------- QKV GEMM: double-buffered, x hi/lo (2 MFMA), w single bf16 ---------
// z=0 -> Qh (prescaled by log2e), z=1 -> Kh, z=2 -> Vt (transposed bf16).
struct QkvArgs {
  const u16 *Ah, *Al;
  const u16 *Bh[3];
  const float* bias[3];
  u16 *Qh, *Kh, *Vt;
};

__global__ __launch_bounds__(256) void gemm_qkv(QkvArgs a) {
  const int K = 512;
  const float L2E = 1.44269504088896340736f;
  const int z = blockIdx.z;
  const u16* __restrict__ Bh = a.Bh[z];
  const float* __restrict__ bias = a.bias[z];
  const int bn = blockIdx.x * 128, bm = blockIdx.y * 128;
  const int tid = threadIdx.x;
  const int wave = tid >> 6, lane = tid & 63;
  const int l16 = lane & 15, quad = lane >> 4;
  const int wm = (wave >> 1) * 64, wn = (wave & 1) * 64;

  __shared__ u16 sA[2][128 * 32];
  __shared__ u16 sAl[2][128 * 32];
  __shared__ u16 sB[2][128 * 32];

  const int srow = wave * 32 + (lane >> 2);
  const int scol = (lane & 3) * 8;
  const u16* srcA0 = a.Ah + (size_t)(bm + srow) * K + scol;
  const u16* srcAl0 = a.Al + (size_t)(bm + srow) * K + scol;
  const u16* srcB0 = Bh + (size_t)(bn + srow) * K + scol;
  const size_t half_off = (size_t)16 * K;

  auto prefetchG = [&](int kt, int buf) {
    u16* dA = sA[buf] + wave * 1024;
    u16* dAl = sAl[buf] + wave * 1024;
    u16* dB = sB[buf] + wave * 1024;
    gload_lds16(srcA0 + kt, dA);
    gload_lds16(srcA0 + half_off + kt, dA + 512);
    gload_lds16(srcAl0 + kt, dAl);
    gload_lds16(srcAl0 + half_off + kt, dAl + 512);
    gload_lds16(srcB0 + kt, dB);
    gload_lds16(srcB0 + half_off + kt, dB + 512);
  };

  f32x4 acc[4][4] = {};
  prefetchG(0, 0);

  for (int i = 0; i < 16; ++i) {
    __syncthreads();
    if (i + 1 < 16) prefetchG((i + 1) << 5, (i + 1) & 1);
    const u16* bufA = sA[i & 1];
    const u16* bufAl = sAl[i & 1];
    const u16* bufB = sB[i & 1];

    bf16x8 a_h[4], a_l[4], b_h[4];
#pragma unroll
    for (int mt = 0; mt < 4; ++mt) {
      a_h[mt] = *(const bf16x8*)(bufA + (wm + mt * 16 + l16) * 32 + quad * 8);
      a_l[mt] = *(const bf16x8*)(bufAl + (wm + mt * 16 + l16) * 32 + quad * 8);
    }
#pragma unroll
    for (int nt = 0; nt < 4; ++nt)
      b_h[nt] = *(const bf16x8*)(bufB + (wn + nt * 16 + l16) * 32 + quad * 8);
#pragma unroll
    for (int mt = 0; mt < 4; ++mt)
#pragma unroll
      for (int nt = 0; nt < 4; ++nt) {
        acc[mt][nt] = __builtin_amdgcn_mfma_f32_16x16x32_bf16(a_h[mt], b_h[nt], acc[mt][nt], 0, 0, 0);
        acc[mt][nt] = __builtin_amdgcn_mfma_f32_16x16x32_bf16(a_l[mt], b_h[nt], acc[mt][nt], 0, 0, 0);
      }
  }

  if (z == 2) {
    // V: write transposed bf16 Vt[dim][seq]; r-regs are seq-contiguous -> 8B stores
#pragma unroll
    for (int nt = 0; nt < 4; ++nt) {
      int col = bn + wn + nt * 16 + l16;
      float bv = bias[col];
#pragma unroll
      for (int mt = 0; mt < 4; ++mt) {
        int row0 = bm + wm + mt * 16 + quad * 4;
        u16x4 o;
#pragma unroll
        for (int r = 0; r < 4; ++r) o[r] = f2bf(acc[mt][nt][r] + bv);
        *(u16x4*)(a.Vt + (size_t)col * 4096 + row0) = o;
      }
    }
  } else {
    u16* __restrict__ C = (z == 0) ? a.Qh : a.Kh;
    float scale = (z == 0) ? L2E : 1.f;
#pragma unroll
    for (int mt = 0; mt < 4; ++mt)
#pragma unroll
      for (int nt = 0; nt < 4; ++nt) {
        int col = bn + wn + nt * 16 + l16;
        float bv = bias[col];
#pragma unroll
        for (int r = 0; r < 4; ++r) {
          int row = bm + wm + mt * 16 + quad * 4 + r;
          C[(size_t)row * 512 + col] = f2bf((acc[mt][nt][r] + bv) * scale);
        }
      }
  }
}

// ---------------- generic staged GEMM, double-buffered (r7 best-known) ----------------
template <int RELU, int BF16OUT>
__global__ __launch_bounds__(256) void gemm_bt(const u16* __restrict__ Ah,
                                               const u16* __restrict__ Bh,
                                               const float* __restrict__ bias,
                                               float* __restrict__ Cf,
                                               u16* __restrict__ Ch,
                                               int N, int K) {
  const int bn = blockIdx.x * 128, bm = blockIdx.y * 128;
  const int tid = threadIdx.x;
  const int wave = tid >> 6, lane = tid & 63;
  const int l16 = lane & 15, quad = lane >> 4;
  const int wm = (wave >> 1) * 64, wn = (wave & 1) * 64;

  __shared__ u16 sA[2][128 * 32];
  __shared__ u16 sB[2][128 * 32];

  const int srow = wave * 32 + (lane >> 2);
  const int scol = (lane & 3) * 8;
  const u16* srcA0 = Ah + (size_t)(bm + srow) * K + scol;
  const u16* srcB0 = Bh + (size_t)(bn + srow) * K + scol;
  const size_t half_off = (size_t)16 * K;

  auto prefetchG = [&](int kt, int buf) {
    u16* dA = sA[buf] + wave * 1024;
    u16* dB = sB[buf] + wave * 1024;
    gload_lds16(srcA0 + kt, dA);
    gload_lds16(srcA0 + half_off + kt, dA + 512);
    gload_lds16(srcB0 + kt, dB);
    gload_lds16(srcB0 + half_off + kt, dB + 512);
  };

  f32x4 acc[4][4] = {};
  prefetchG(0, 0);

  const int steps = K >> 5;
  for (int i = 0; i < steps; ++i) {
    __syncthreads();
    if (i + 1 < steps) prefetchG((i + 1) << 5, (i + 1) & 1);
    const u16* bufA = sA[i & 1];
    const u16* bufB = sB[i & 1];

    bf16x8 a_h[4], b_h[4];
#pragma unroll
    for (int mt = 0; mt < 4; ++mt)
      a_h[mt] = *(const bf16x8*)(bufA + (wm + mt * 16 + l16) * 32 + quad * 8);
#pragma unroll
    for (int nt = 0; nt < 4; ++nt)
      b_h[nt] = *(const bf16x8*)(bufB + (wn + nt * 16 + l16) * 32 + quad * 8);
#pragma unroll
    for (int mt = 0; mt < 4; ++mt)
#pragma unroll
      for (int nt = 0; nt < 4; ++nt)
        acc[mt][nt] = __builtin_amdgcn_mfma_f32_16x16x32_bf16(a_h[mt], b_h[nt], acc[mt][nt], 0, 0, 0);
  }

#pragma unroll
  for (int mt = 0; mt < 4; ++mt)
#pragma unroll
    for (int nt = 0; nt < 4; ++nt) {
      int col = bn + wn + nt * 16 + l16;
      float bv = bias ? bias[col] : 0.f;
#pragma unroll
      for (int r = 0; r < 4; ++r) {
        int row = bm + wm + mt * 16 + quad * 4 + r;
        float v = acc[mt][nt][r] + bv;
        if (RELU) v = fmaxf(v, 0.f);
        size_t oidx = (size_t)row * N + col;
        if (BF16OUT) Ch[oidx] = f2bf(v);
        else Cf[oidx] = v;
      }
    }
}

// ---------------- flash attention v6: split-phase pipeline ----------------
// Grid (32 = 8h x 4chunk, 32 qb) = 1024 blocks. Per 64-key iter:
//   [A] -> issue V(it+1) (V double-buffered) -> QK (sole sK reader) + softmax/P half0
//   [B] -> issue K(it+1) (sK free after B)   -> PV half0, softmax half1, PV half1
// Each barrier's vmcnt(0) drain covers loads issued a compute-phase earlier --
// removes the issue-then-drain stall that pinned attn at ~90-120us (r3-r9).
// LDS 34KB -> 4 blocks/CU. Q/K single bf16 (Q prescaled by log2e).
struct AttnIO { float* O[4]; float* lp; };

__global__ __launch_bounds__(256) void attn(const u16* __restrict__ Qh,
                                            const u16* __restrict__ Kh,
                                            const u16* __restrict__ Vt,
                                            const u64* __restrict__ mb64,
                                            AttnIO io) {
  const int S = 4096, D = 512;
  const int h = blockIdx.x >> 2, chunk = blockIdx.x & 3;
  const int tid = threadIdx.x, wave = tid >> 6, lane = tid & 63;
  const int l16 = lane & 15, quad = lane >> 4;
  const int q0w = blockIdx.y * 128 + wave * 32;
  const int kbeg = chunk * 1024;
  const int sw = l16 & 7;                       // bank-swizzle key

  __shared__ u16 sK[64 * 64];                   // [key][dim]        8 KB
  __shared__ u16 sV[2][64 * 64];                // [dim][key] dbuf  16 KB
  __shared__ u16 sP[4][32 * 40];                // per-wave P       10 KB
  u16* myP = &sP[wave][0];

  const int skey = lane >> 3;
  const int sch  = lane & 7;
  const u16* srcK = Kh + (size_t)(kbeg + wave * 8 + skey) * D + h * 64 + ((sch ^ skey) * 8);
  const u16* srcV = Vt + (size_t)(h * 64 + wave * 8 + skey) * S + kbeg + ((sch ^ skey) * 8);
  u16* dstK = sK + wave * 512;

  auto stageK = [&](int it) {
    const u16* p = srcK + (size_t)it * 64 * D;
    gload_lds16(p, dstK);
    gload_lds16(p + (size_t)32 * D, dstK + 32 * 64);
  };
  auto stageV = [&](int it) {
    const u16* p = srcV + it * 64;
    u16* d = sV[it & 1] + wave * 512;
    gload_lds16(p, d);
    gload_lds16(p + (size_t)32 * S, d + 32 * 64);
  };

  // Q prefetch: B-frags (n=l16 -> q, k=quad*8 dims), single bf16 prescaled
  bf16x8 qf[2][2];
#pragma unroll
  for (int qt = 0; qt < 2; ++qt)
#pragma unroll
    for (int kd = 0; kd < 2; ++kd)
      qf[qt][kd] = *(const bf16x8*)(Qh + (size_t)(q0w + qt * 16 + l16) * D + h * 64 + kd * 32 + quad * 8);

  f32x4 accO[2][4] = {};
  float l_lane[2] = {0.f, 0.f};
  const int wbase = kbeg >> 6;

  stageV(0);
  stageK(0);
  u64 wmCur[2];
#pragma unroll
  for (int qt = 0; qt < 2; ++qt)
    wmCur[qt] = mb64[(size_t)(q0w + qt * 16 + l16) * 64 + wbase];

  for (int it = 0; it < 16; ++it) {
    __syncthreads();                          // A: V(it)/K(it) staged (issued a phase ago)
    if (it + 1 < 16) stageV(it + 1);          // into the other V buffer
    u64 wmNext[2] = {0, 0};
    if (it + 1 < 16) {
#pragma unroll
      for (int qt = 0; qt < 2; ++qt)
        wmNext[qt] = mb64[(size_t)(q0w + qt * 16 + l16) * 64 + wbase + it + 1];
    }

    // ---- QK phase: the ONLY sK reads ----
    f32x4 sc[4][2];
#pragma unroll
    for (int kt4 = 0; kt4 < 4; ++kt4) {
      const u16* arow = sK + (kt4 * 16 + l16) * 64;
      bf16x8 ka0 = *(const bf16x8*)(arow + ((quad ^ sw) * 8));
      bf16x8 ka1 = *(const bf16x8*)(arow + (((4 + quad) ^ sw) * 8));
#pragma unroll
      for (int qt = 0; qt < 2; ++qt) {
        f32x4 s = {};
        s = __builtin_amdgcn_mfma_f32_16x16x32_bf16(ka0, qf[qt][0], s, 0, 0, 0);
        s = __builtin_amdgcn_mfma_f32_16x16x32_bf16(ka1, qf[qt][1], s, 0, 0, 0);
        sc[kt4][qt] = s;
      }
    }
    // ---- softmax + P write, half 0 (keys 0..31) ----
#pragma unroll
    for (int k2 = 0; k2 < 2; ++k2) {
      const int baseb = k2 * 16 + quad * 4;
#pragma unroll
      for (int qt = 0; qt < 2; ++qt) {
        float p[4];
#pragma unroll
        for (int r = 0; r < 4; ++r) {
          bool keep = (wmCur[qt] >> (baseb + r)) & 1ull;
          p[r] = exp2f(keep ? sc[k2][qt][r] : -1e9f);
        }
        l_lane[qt] += (p[0] + p[1]) + (p[2] + p[3]);
        u32x2 pk = {packtrunc(p[0], p[1]), packtrunc(p[2], p[3])};
        *(u32x2*)(myP + (qt * 16 + l16) * 40 + k2 * 16 + quad * 4) = pk;
      }
    }
    __syncthreads();                          // B: all waves done with sK
    if (it + 1 < 16) stageK(it + 1);
    const u16* bV = sV[it & 1];

    // ---- PV half 0 ----
    {
      bf16x8 pa[2];
#pragma unroll
      for (int qt = 0; qt < 2; ++qt)
        pa[qt] = *(const bf16x8*)(myP + (qt * 16 + l16) * 40 + quad * 8);
#pragma unroll
      for (int nt = 0; nt < 4; ++nt) {
        bf16x8 vf = *(const bf16x8*)(bV + (nt * 16 + l16) * 64 + ((quad ^ sw) * 8));
#pragma unroll
        for (int qt = 0; qt < 2; ++qt)
          accO[qt][nt] = __builtin_amdgcn_mfma_f32_16x16x32_bf16(pa[qt], vf, accO[qt][nt], 0, 0, 0);
      }
    }
    // ---- softmax + P write, half 1 (keys 32..63; same sP slots, same-wave order) ----
#pragma unroll
    for (int k2 = 0; k2 < 2; ++k2) {
      const int baseb = 32 + k2 * 16 + quad * 4;
#pragma unroll
      for (int qt = 0; qt < 2; ++qt) {
        float p[4];
#pragma unroll
        for (int r = 0; r < 4; ++r) {
          bool keep = (wmCur[qt] >> (baseb + r)) & 1ull;
          p[r] = exp2f(keep ? sc[2 + k2][qt][r] : -1e9f);
        }
        l_lane[qt] += (p[0] + p[1]) + (p[2] + p[3]);
        u32x2 pk = {packtrunc(p[0], p[1]), packtrunc(p[2], p[3])};
        *(u32x2*)(myP + (qt * 16 + l16) * 40 + k2 * 16 + quad * 4) = pk;
      }
    }
    // ---- PV half 1 ----
    {
      bf16x8 pa[2];
#pragma unroll
      for (int qt = 0; qt < 2; ++qt)
        pa[qt] = *(const bf16x8*)(myP + (qt * 16 + l16) * 40 + quad * 8);
#pragma unroll
      for (int nt = 0; nt < 4; ++nt) {
        bf16x8 vf = *(const bf16x8*)(bV + (nt * 16 + l16) * 64 + (((4 + quad) ^ sw) * 8));
#pragma unroll
        for (int qt = 0; qt < 2; ++qt)
          accO[qt][nt] = __builtin_amdgcn_mfma_f32_16x16x32_bf16(pa[qt], vf, accO[qt][nt], 0, 0, 0);
      }
    }
    wmCur[0] = wmNext[0];
    wmCur[1] = wmNext[1];
  }

  // l: sum the 4 quads of each q (q = l16 in the softmax layout)
#pragma unroll
  for (int qt = 0; qt < 2; ++qt) {
    float s = l_lane[qt];
    s += __shfl_xor(s, 16);
    s += __shfl_xor(s, 32);
    l_lane[qt] = s;
  }
  float* Op = io.O[chunk];
#pragma unroll
  for (int qt = 0; qt < 2; ++qt)
#pragma unroll
    for (int nt = 0; nt < 4; ++nt)
#pragma unroll
      for (int r = 0; r < 4; ++r) {
        int row = q0w + qt * 16 + quad * 4 + r;
        Op[((size_t)h * S + row) * 64 + nt * 16 + l16] = accO[qt][nt][r];
      }
  if (quad == 0)
#pragma unroll
    for (int qt = 0; qt < 2; ++qt)
      io.lp[((size_t)h * 4 + chunk) * S + q0w + qt * 16 + l16] = l_lane[qt];
}

// ---------------- combine 4 split-K partials -> ctx (bf16) ----------------
__global__ __launch_bounds__(256) void attn_combine(AttnIO io, u16* __restrict__ ctx) {
  const int S = 4096;
  int i = (blockIdx.x * 256 + threadIdx.x);
  int row = i >> 7;
  int col4 = (i & 127) * 4;
  int h = col4 >> 6, c = col4 & 63;
  size_t ob = ((size_t)h * S + row) * 64 + c;
  f32x4 o = {0.f, 0.f, 0.f, 0.f};
  float l = 0.f;
#pragma unroll
  for (int p = 0; p < 4; ++p) {
    o += *(const f32x4*)(io.O[p] + ob);
    l += io.lp[((size_t)h * 4 + p) * S + row];
  }
  float rl = 1.f / l;
  u16x4 out;
#pragma unroll
  for (int j = 0; j < 4; ++j) out[j] = f2bf(o[j] * rl);
  *(u16x4*)(ctx + (size_t)row * 512 + col4) = out;
}

// ---------------- residual + layernorm (rows of 512) ----------------
__global__ __launch_bounds__(256) void resid_ln(const float* __restrict__ X,
                                                const float* __restrict__ Y,
                                                const float* __restrict__ g,
                                                const float* __restrict__ b,
                                                float* __restrict__ outF,
                                                u16* __restrict__ outH) {
  int row = blockIdx.x * 4 + (int)(threadIdx.x >> 6);
  int lane = threadIdx.x & 63;
  const float* x0 = X + (size_t)row * 512;
  const float* y0 = Y + (size_t)row * 512;
  int c0 = lane * 4, c1 = 256 + lane * 4;
  f32x4 v0 = *(const f32x4*)(x0 + c0) + *(const f32x4*)(y0 + c0);
  f32x4 v1 = *(const f32x4*)(x0 + c1) + *(const f32x4*)(y0 + c1);
  float s = 0.f, s2 = 0.f;
#pragma unroll
  for (int j = 0; j < 4; ++j) {
    s += v0[j] + v1[j];
    s2 += v0[j] * v0[j] + v1[j] * v1[j];
  }
#pragma unroll
  for (int m = 1; m < 64; m <<= 1) {
    s += __shfl_xor(s, m);
    s2 += __shfl_xor(s2, m);
  }
  float mean = s * (1.f / 512.f);
  float var = s2 * (1.f / 512.f) - mean * mean;
  float rs = rsqrtf(var + 1e-5f);
  f32x4 o0, o1;
#pragma unroll
  for (int j = 0; j < 4; ++j) {
    o0[j] = (v0[j] - mean) * rs * g[c0 + j] + b[c0 + j];
    o1[j] = (v1[j] - mean) * rs * g[c1 + j] + b[c1 + j];
  }
  if (outF) {
    *(f32x4*)(outF + (size_t)row * 512 + c0) = o0;
    *(f32x4*)(outF + (size_t)row * 512 + c1) = o1;
  }
  if (outH) {
    u16x4 h0, h1;
#pragma unroll
    for (int j = 0; j < 4; ++j) { h0[j] = f2bf(o0[j]); h1[j] = f2bf(o1[j]); }
    *(u16x4*)(outH + (size_t)row * 512 + c0) = h0;
    *(u16x4*)(outH + (size_t)row * 512 + c1) = h1;
  }
}

extern "C" void kernel_launch(void* const* d_in, const int* in_sizes, int n_in,
                              void* d_out, int out_size, void* d_ws, size_t ws_size,
                              hipStream_t stream) {
  (void)in_sizes; (void)n_in; (void)out_size; (void)ws_size;
  const float* x   = (const float*)d_in[0];
  const int*   mask= (const int*)d_in[1];
  const float* wq  = (const float*)d_in[2];
  const float* bq  = (const float*)d_in[3];
  const float* wk  = (const float*)d_in[4];
  const float* bk  = (const float*)d_in[5];
  const float* wv  = (const float*)d_in[6];
  const float* bv  = (const float*)d_in[7];
  const float* wo  = (const float*)d_in[8];
  const float* bo  = (const float*)d_in[9];
  const float* w1  = (const float*)d_in[10];
  const float* b1  = (const float*)d_in[11];
  const float* w2  = (const float*)d_in[12];
  const float* b2  = (const float*)d_in[13];
  const float* g1  = (const float*)d_in[14];
  const float* be1 = (const float*)d_in[15];
  const float* g2  = (const float*)d_in[16];
  const float* be2 = (const float*)d_in[17];

  const int S = 4096, D = 512, F = 2048;
  char* ws = (char*)d_ws;
  size_t cur = 0;
  auto alloc = [&](size_t bytes) {
    char* p = ws + cur;
    cur += (bytes + 255) & ~(size_t)255;
    return p;
  };
  u16* wqT = (u16*)alloc((size_t)D * D * 2);
  u16* wkT = (u16*)alloc((size_t)D * D * 2);
  u16* wvT = (u16*)alloc((size_t)D * D * 2);
  u16* woT = (u16*)alloc((size_t)D * D * 2);
  u16* w1T = (u16*)alloc((size_t)D * F * 2);
  u16* w2T = (u16*)alloc((size_t)D * F * 2);
  u32* mbits = (u32*)alloc((size_t)S * S / 8);
  u16* xh = (u16*)alloc((size_t)S * D * 2);
  u16* xl = (u16*)alloc((size_t)S * D * 2);
  // Qh,Kh,Vt,hx contiguous (16MB): FF1's hbuf spans them
  u16* Qh = (u16*)alloc((size_t)S * D * 2);
  u16* Kh = (u16*)alloc((size_t)S * D * 2);
  u16* Vt = (u16*)alloc((size_t)S * D * 2);
  u16* hx = (u16*)alloc((size_t)S * D * 2); (void)hx;
  u16* ctx = (u16*)alloc((size_t)S * D * 2);
  float* x1 = (float*)alloc((size_t)S * D * 4);
  u16* x1h = (u16*)alloc((size_t)S * D * 2);
  float* Oex = (float*)alloc((size_t)2 * S * D * 4);   // O2,O3 (16MB fresh)
  // aliases (lifetimes disjoint by stream order):
  AttnIO io;
  io.O[0] = (float*)xh;            // 8MB over xh+xl (dead after QKV gemm)
  io.O[1] = x1;                    // 8MB (x1 written later by resid_ln, after combine)
  io.O[2] = Oex;
  io.O[3] = Oex + (size_t)S * D;
  io.lp = (float*)x1h;             // 512KB (x1h written later by resid_ln)
  float* proj = (float*)xh;        // OP output (after combine read O[0])
  u16* hbuf = Qh;                  // FF1 output (16MB over Qh,Kh,Vt,hx), after attn
  float* ff2 = Oex;                // FF2 output (after combine read O[2]/O[3])

  PrepArgs pa;
  pa.x = x; pa.xh = xh; pa.xl = xl;
  pa.mask = mask; pa.mbits = (unsigned long long*)mbits;
  pa.pw[0] = {wq, wqT, nullptr, D, D, 15, 4};
  pa.pw[1] = {wk, wkT, nullptr, D, D, 15, 4};
  pa.pw[2] = {wv, wvT, nullptr, D, D, 15, 4};
  pa.pw[3] = {wo, woT, nullptr, D, D, 15, 4};
  pa.pw[4] = {w1, w1T, nullptr, D, F, 63, 6};
  pa.pw[5] = {w2, w2T, nullptr, F, D, 15, 4};

  QkvArgs qa;
  qa.Ah = xh; qa.Al = xl;
  qa.Bh[0] = wqT; qa.Bh[1] = wkT; qa.Bh[2] = wvT;
  qa.bias[0] = bq; qa.bias[1] = bk; qa.bias[2] = bv;
  qa.Qh = Qh; qa.Kh = Kh; qa.Vt = Vt;

  // 1. fused prep
  prep<<<70656, 256, 0, stream>>>(pa);
  // 2. QKV projection (x hi/lo, w bf16; Q prescaled; V transposed)
  gemm_qkv<<<dim3(4, 32, 3), 256, 0, stream>>>(qa);
  // 3. flash attention (split-phase pipeline, split-K x4) + combine
  attn<<<dim3(32, 32), 256, 0, stream>>>(Qh, Kh, Vt, (const u64*)mbits, io);
  attn_combine<<<(S * D / 4) / 256, 256, 0, stream>>>(io, ctx);
  // 4. output projection -> proj fp32
  gemm_bt<0, 0><<<dim3(4, 32), 256, 0, stream>>>(ctx, woT, bo, proj, nullptr, D, D);
  // 5. residual + LN1
  resid_ln<<<S / 4, 256, 0, stream>>>(x, proj, g1, be1, x1, x1h);
  // 6. FFN
  gemm_bt<1, 1><<<dim3(16, 32), 256, 0, stream>>>(x1h, w1T, b1, nullptr, hbuf, F, D);
  gemm_bt<0, 0><<<dim3(4, 32), 256, 0, stream>>>(hbuf, w2T, b2, ff2, nullptr, D, F);
  // 7. residual + LN2 -> final fp32 output
  resid_ln<<<S / 4, 256, 0, stream>>>(x1, ff2, g2, be2, (float*)d_out, nullptr);
}

// Round 11
// 322.716 us; speedup vs baseline: 1.9915x; 1.0552x over previous
//
#include <hip/hip_runtime.h>

typedef unsigned short u16;
typedef unsigned int u32;
typedef unsigned long long u64;
typedef __attribute__((ext_vector_type(4))) float f32x4;
typedef __attribute__((ext_vector_type(8))) short bf16x8;   // 8 bf16 (4 VGPRs)
typedef __attribute__((ext_vector_type(4))) u16 u16x4;
typedef __attribute__((ext_vector_type(2))) u32 u32x2;

#define DEV __device__ __forceinline__

DEV u16 f2bf(float f) {               // RNE fp32 -> bf16
  union { float f; u32 u; } c; c.f = f;
  u32 u = c.u;
  u += 0x7fffu + ((u >> 16) & 1u);
  return (u16)(u >> 16);
}
DEV float bf2f(u16 h) {
  union { u32 u; float f; } c; c.u = ((u32)h) << 16;
  return c.f;
}
DEV u32 fbits(float f) { union { float f; u32 u; } c; c.f = f; return c.u; }
// pack two fp32 -> two truncated bf16 in one u32 (a = low, b = high)
DEV u32 packtrunc(float a, float b) {
  return (fbits(b) & 0xFFFF0000u) | (fbits(a) >> 16);
}

// async global->LDS, 16B per lane. Dest is WAVE-UNIFORM base + lane*16 (m104/m108).
DEV void gload_lds16(const void* g, void* l) {
  __builtin_amdgcn_global_load_lds(
      (const __attribute__((address_space(1))) u32*)(u64)g,
      (__attribute__((address_space(3))) u32*)(u32)(u64)l,   // low 32 bits = LDS offset
      16, 0, 0);
}

// ---------------- fused prep: x split + 6 weight transposes (hi only) + mask pack -----
struct PrepW { const float* w; u16* th; u16* tl; int R, C, gxmask, gxshift; };
struct PrepArgs {
  const float* x; u16* xh; u16* xl;
  const int* mask; unsigned long long* mbits;
  PrepW pw[6];
};

__global__ __launch_bounds__(256) void prep(PrepArgs a) {
  __shared__ float t[32][33];
  int b = blockIdx.x, tid = threadIdx.x;
  if (b < 2048) {                       // x -> bf16 hi/lo
    int i = (b * 256 + tid) * 4;
    f32x4 v = *(const f32x4*)(a.x + i);
    u16x4 h, l;
#pragma unroll
    for (int j = 0; j < 4; ++j) { h[j] = f2bf(v[j]); l[j] = f2bf(v[j] - bf2f(h[j])); }
    *(u16x4*)(a.xh + i) = h;
    *(u16x4*)(a.xl + i) = l;
    return;
  }
  b -= 2048;
  if (b < 3072) {                       // weight (R,C) -> transposed (C,R)
    int wi, base;
    if (b < 1024) { wi = b >> 8; base = b & 255; }
    else if (b < 2048) { wi = 4; base = b - 1024; }
    else { wi = 5; base = b - 2048; }
    PrepW p = a.pw[wi];
    int c0 = (base & p.gxmask) * 32, r0 = (base >> p.gxshift) * 32;
    int tx = tid & 31, ty = tid >> 5;
#pragma unroll
    for (int i = 0; i < 4; ++i)
      t[ty + 8 * i][tx] = p.w[(size_t)(r0 + ty + 8 * i) * p.C + c0 + tx];
    __syncthreads();
#pragma unroll
    for (int i = 0; i < 4; ++i) {
      float v = t[tx][ty + 8 * i];
      u16 h = f2bf(v);
      size_t o = (size_t)(c0 + ty + 8 * i) * p.R + r0 + tx;
      p.th[o] = h;
      if (p.tl) p.tl[o] = f2bf(v - bf2f(h));
    }
    return;
  }
  b -= 3072;                            // mask -> bitmask
  size_t i = (size_t)b * 256 + tid;
  unsigned long long bb = __ballot(a.mask[i] != 0);
  if ((tid & 63) == 0) a.mbits[i >> 6] = bb;
}

// ---------------- QKV GEMM: double-buffered, x hi/lo (2 MFMA), w single bf16 ---------
// z=0 -> Qh (prescaled by log2e), z=1 -> Kh, z=2 -> Vt (transposed bf16).
struct QkvArgs {
  const u16 *Ah, *Al;
  const u16 *Bh[3];
  const float* bias[3];
  u16 *Qh, *Kh, *Vt;
};

__global__ __launch_bounds__(256) void gemm_qkv(QkvArgs a) {
  const int K = 512;
  const float L2E = 1.44269504088896340736f;
  const int z = blockIdx.z;
  const u16* __restrict__ Bh = a.Bh[z];
  const float* __restrict__ bias = a.bias[z];
  const int bn = blockIdx.x * 128, bm = blockIdx.y * 128;
  const int tid = threadIdx.x;
  const int wave = tid >> 6, lane = tid & 63;
  const int l16 = lane & 15, quad = lane >> 4;
  const int wm = (wave >> 1) * 64, wn = (wave & 1) * 64;

  __shared__ u16 sA[2][128 * 32];
  __shared__ u16 sAl[2][128 * 32];
  __shared__ u16 sB[2][128 * 32];

  const int srow = wave * 32 + (lane >> 2);
  const int scol = (lane & 3) * 8;
  const u16* srcA0 = a.Ah + (size_t)(bm + srow) * K + scol;
  const u16* srcAl0 = a.Al + (size_t)(bm + srow) * K + scol;
  const u16* srcB0 = Bh + (size_t)(bn + srow) * K + scol;
  const size_t half_off = (size_t)16 * K;

  auto prefetchG = [&](int kt, int buf) {
    u16* dA = sA[buf] + wave * 1024;
    u16* dAl = sAl[buf] + wave * 1024;
    u16* dB = sB[buf] + wave * 1024;
    gload_lds16(srcA0 + kt, dA);
    gload_lds16(srcA0 + half_off + kt, dA + 512);
    gload_lds16(srcAl0 + kt, dAl);
    gload_lds16(srcAl0 + half_off + kt, dAl + 512);
    gload_lds16(srcB0 + kt, dB);
    gload_lds16(srcB0 + half_off + kt, dB + 512);
  };

  f32x4 acc[4][4] = {};
  prefetchG(0, 0);

  for (int i = 0; i < 16; ++i) {
    __syncthreads();
    if (i + 1 < 16) prefetchG((i + 1) << 5, (i + 1) & 1);
    const u16* bufA = sA[i & 1];
    const u16* bufAl = sAl[i & 1];
    const u16* bufB = sB[i & 1];

    bf16x8 a_h[4], a_l[4], b_h[4];
#pragma unroll
    for (int mt = 0; mt < 4; ++mt) {
      a_h[mt] = *(const bf16x8*)(bufA + (wm + mt * 16 + l16) * 32 + quad * 8);
      a_l[mt] = *(const bf16x8*)(bufAl + (wm + mt * 16 + l16) * 32 + quad * 8);
    }
#pragma unroll
    for (int nt = 0; nt < 4; ++nt)
      b_h[nt] = *(const bf16x8*)(bufB + (wn + nt * 16 + l16) * 32 + quad * 8);
#pragma unroll
    for (int mt = 0; mt < 4; ++mt)
#pragma unroll
      for (int nt = 0; nt < 4; ++nt) {
        acc[mt][nt] = __builtin_amdgcn_mfma_f32_16x16x32_bf16(a_h[mt], b_h[nt], acc[mt][nt], 0, 0, 0);
        acc[mt][nt] = __builtin_amdgcn_mfma_f32_16x16x32_bf16(a_l[mt], b_h[nt], acc[mt][nt], 0, 0, 0);
      }
  }

  if (z == 2) {
    // V: write transposed bf16 Vt[dim][seq]; r-regs are seq-contiguous -> 8B stores
#pragma unroll
    for (int nt = 0; nt < 4; ++nt) {
      int col = bn + wn + nt * 16 + l16;
      float bv = bias[col];
#pragma unroll
      for (int mt = 0; mt < 4; ++mt) {
        int row0 = bm + wm + mt * 16 + quad * 4;
        u16x4 o;
#pragma unroll
        for (int r = 0; r < 4; ++r) o[r] = f2bf(acc[mt][nt][r] + bv);
        *(u16x4*)(a.Vt + (size_t)col * 4096 + row0) = o;
      }
    }
  } else {
    u16* __restrict__ C = (z == 0) ? a.Qh : a.Kh;
    float scale = (z == 0) ? L2E : 1.f;
#pragma unroll
    for (int mt = 0; mt < 4; ++mt)
#pragma unroll
      for (int nt = 0; nt < 4; ++nt) {
        int col = bn + wn + nt * 16 + l16;
        float bv = bias[col];
#pragma unroll
        for (int r = 0; r < 4; ++r) {
          int row = bm + wm + mt * 16 + quad * 4 + r;
          C[(size_t)row * 512 + col] = f2bf((acc[mt][nt][r] + bv) * scale);
        }
      }
  }
}

// ---------------- generic staged GEMM, double-buffered, optional split-K x2 ----------
// NSPLIT=2: z=0 -> Cf (with bias), z=1 -> Cf2 (no bias); consumer sums partials
// (resid_ln 3-input). No atomics, no zeroing.
template <int RELU, int BF16OUT, int NSPLIT>
__global__ __launch_bounds__(256) void gemm_bt(const u16* __restrict__ Ah,
                                               const u16* __restrict__ Bh,
                                               const float* __restrict__ bias,
                                               float* __restrict__ Cf,
                                               float* __restrict__ Cf2,
                                               u16* __restrict__ Ch,
                                               int N, int K) {
  const int z = (NSPLIT > 1) ? blockIdx.z : 0;
  const int Ksub = K / NSPLIT;
  const int kbeg = z * Ksub;
  const int bn = blockIdx.x * 128, bm = blockIdx.y * 128;
  const int tid = threadIdx.x;
  const int wave = tid >> 6, lane = tid & 63;
  const int l16 = lane & 15, quad = lane >> 4;
  const int wm = (wave >> 1) * 64, wn = (wave & 1) * 64;

  __shared__ u16 sA[2][128 * 32];
  __shared__ u16 sB[2][128 * 32];

  const int srow = wave * 32 + (lane >> 2);
  const int scol = (lane & 3) * 8;
  const u16* srcA0 = Ah + (size_t)(bm + srow) * K + kbeg + scol;
  const u16* srcB0 = Bh + (size_t)(bn + srow) * K + kbeg + scol;
  const size_t half_off = (size_t)16 * K;

  auto prefetchG = [&](int kt, int buf) {
    u16* dA = sA[buf] + wave * 1024;
    u16* dB = sB[buf] + wave * 1024;
    gload_lds16(srcA0 + kt, dA);
    gload_lds16(srcA0 + half_off + kt, dA + 512);
    gload_lds16(srcB0 + kt, dB);
    gload_lds16(srcB0 + half_off + kt, dB + 512);
  };

  f32x4 acc[4][4] = {};
  prefetchG(0, 0);

  const int steps = Ksub >> 5;
  for (int i = 0; i < steps; ++i) {
    __syncthreads();
    if (i + 1 < steps) prefetchG((i + 1) << 5, (i + 1) & 1);
    const u16* bufA = sA[i & 1];
    const u16* bufB = sB[i & 1];

    bf16x8 a_h[4], b_h[4];
#pragma unroll
    for (int mt = 0; mt < 4; ++mt)
      a_h[mt] = *(const bf16x8*)(bufA + (wm + mt * 16 + l16) * 32 + quad * 8);
#pragma unroll
    for (int nt = 0; nt < 4; ++nt)
      b_h[nt] = *(const bf16x8*)(bufB + (wn + nt * 16 + l16) * 32 + quad * 8);
#pragma unroll
    for (int mt = 0; mt < 4; ++mt)
#pragma unroll
      for (int nt = 0; nt < 4; ++nt)
        acc[mt][nt] = __builtin_amdgcn_mfma_f32_16x16x32_bf16(a_h[mt], b_h[nt], acc[mt][nt], 0, 0, 0);
  }

  float* __restrict__ Co = (NSPLIT > 1 && z == 1) ? Cf2 : Cf;
#pragma unroll
  for (int mt = 0; mt < 4; ++mt)
#pragma unroll
    for (int nt = 0; nt < 4; ++nt) {
      int col = bn + wn + nt * 16 + l16;
      float bv = (bias && z == 0) ? bias[col] : 0.f;
#pragma unroll
      for (int r = 0; r < 4; ++r) {
        int row = bm + wm + mt * 16 + quad * 4 + r;
        float v = acc[mt][nt][r] + bv;
        if (RELU) v = fmaxf(v, 0.f);
        size_t oidx = (size_t)row * N + col;
        if (BF16OUT) Ch[oidx] = f2bf(v);
        else Co[oidx] = v;
      }
    }
}

// ---------------- flash attention v7: split-phase pipeline + hoisted mask shifts -----
// Grid (32 = 8h x 4chunk, 32 qb) = 1024 blocks (exactly 4/CU; VGPR=108 caps 4
// blocks anyway). Per 64-key iter:
//   [A] -> issue V(it+1) (dbuf) -> QK + softmax/P half0
//   [B] -> issue K(it+1)        -> PV half0, softmax half1, PV half1
// Mask: per-iter 2x 64-bit shifts hoist the lane-dependent (quad*4) part, so
// per-element tests become constant-shift bfe (r10 used variable u64 shifts
// per element -- the main VALU consumer at VALUBusy=67%).
struct AttnIO { float* O[4]; float* lp; };

__global__ __launch_bounds__(256) void attn(const u16* __restrict__ Qh,
                                            const u16* __restrict__ Kh,
                                            const u16* __restrict__ Vt,
                                            const u64* __restrict__ mb64,
                                            AttnIO io) {
  const int S = 4096, D = 512;
  const int h = blockIdx.x >> 2, chunk = blockIdx.x & 3;
  const int tid = threadIdx.x, wave = tid >> 6, lane = tid & 63;
  const int l16 = lane & 15, quad = lane >> 4;
  const int q0w = blockIdx.y * 128 + wave * 32;
  const int kbeg = chunk * 1024;
  const int sw = l16 & 7;                       // bank-swizzle key

  __shared__ u16 sK[64 * 64];                   // [key][dim]        8 KB
  __shared__ u16 sV[2][64 * 64];                // [dim][key] dbuf  16 KB
  __shared__ u16 sP[4][32 * 40];                // per-wave P       10 KB
  u16* myP = &sP[wave][0];

  const int skey = lane >> 3;
  const int sch  = lane & 7;
  const u16* srcK = Kh + (size_t)(kbeg + wave * 8 + skey) * D + h * 64 + ((sch ^ skey) * 8);
  const u16* srcV = Vt + (size_t)(h * 64 + wave * 8 + skey) * S + kbeg + ((sch ^ skey) * 8);
  u16* dstK = sK + wave * 512;

  auto stageK = [&](int it) {
    const u16* p = srcK + (size_t)it * 64 * D;
    gload_lds16(p, dstK);
    gload_lds16(p + (size_t)32 * D, dstK + 32 * 64);
  };
  auto stageV = [&](int it) {
    const u16* p = srcV + it * 64;
    u16* d = sV[it & 1] + wave * 512;
    gload_lds16(p, d);
    gload_lds16(p + (size_t)32 * S, d + 32 * 64);
  };

  // Q prefetch: B-frags (n=l16 -> q, k=quad*8 dims), single bf16 prescaled
  bf16x8 qf[2][2];
#pragma unroll
  for (int qt = 0; qt < 2; ++qt)
#pragma unroll
    for (int kd = 0; kd < 2; ++kd)
      qf[qt][kd] = *(const bf16x8*)(Qh + (size_t)(q0w + qt * 16 + l16) * D + h * 64 + kd * 32 + quad * 8);

  f32x4 accO[2][4] = {};
  float l_lane[2] = {0.f, 0.f};
  const int wbase = kbeg >> 6;

  stageV(0);
  stageK(0);
  u64 wmCur[2];
#pragma unroll
  for (int qt = 0; qt < 2; ++qt)
    wmCur[qt] = mb64[(size_t)(q0w + qt * 16 + l16) * 64 + wbase];

  for (int it = 0; it < 16; ++it) {
    __syncthreads();                          // A: V(it)/K(it) staged (issued a phase ago)
    if (it + 1 < 16) stageV(it + 1);          // into the other V buffer
    u64 wmNext[2] = {0, 0};
    if (it + 1 < 16) {
#pragma unroll
      for (int qt = 0; qt < 2; ++qt)
        wmNext[qt] = mb64[(size_t)(q0w + qt * 16 + l16) * 64 + wbase + it + 1];
    }
    // hoist lane-dependent mask shift: bit (k2*16+r) of wlo/whi
    u32 wlo[2], whi[2];
#pragma unroll
    for (int qt = 0; qt < 2; ++qt) {
      wlo[qt] = (u32)(wmCur[qt] >> (quad * 4));
      whi[qt] = (u32)(wmCur[qt] >> (quad * 4 + 32));
    }

    // ---- QK phase: the ONLY sK reads ----
    f32x4 sc[4][2];
#pragma unroll
    for (int kt4 = 0; kt4 < 4; ++kt4) {
      const u16* arow = sK + (kt4 * 16 + l16) * 64;
      bf16x8 ka0 = *(const bf16x8*)(arow + ((quad ^ sw) * 8));
      bf16x8 ka1 = *(const bf16x8*)(arow + (((4 + quad) ^ sw) * 8));
#pragma unroll
      for (int qt = 0; qt < 2; ++qt) {
        f32x4 s = {};
        s = __builtin_amdgcn_mfma_f32_16x16x32_bf16(ka0, qf[qt][0], s, 0, 0, 0);
        s = __builtin_amdgcn_mfma_f32_16x16x32_bf16(ka1, qf[qt][1], s, 0, 0, 0);
        sc[kt4][qt] = s;
      }
    }
    // ---- softmax + P write, half 0 (keys 0..31) ----
#pragma unroll
    for (int k2 = 0; k2 < 2; ++k2) {
#pragma unroll
      for (int qt = 0; qt < 2; ++qt) {
        float p[4];
#pragma unroll
        for (int r = 0; r < 4; ++r) {
          bool keep = (wlo[qt] >> (k2 * 16 + r)) & 1u;
          p[r] = exp2f(keep ? sc[k2][qt][r] : -1e9f);
        }
        l_lane[qt] += (p[0] + p[1]) + (p[2] + p[3]);
        u32x2 pk = {packtrunc(p[0], p[1]), packtrunc(p[2], p[3])};
        *(u32x2*)(myP + (qt * 16 + l16) * 40 + k2 * 16 + quad * 4) = pk;
      }
    }
    __syncthreads();                          // B: all waves done with sK
    if (it + 1 < 16) stageK(it + 1);
    const u16* bV = sV[it & 1];

    // ---- PV half 0 ----
    {
      bf16x8 pa[2];
#pragma unroll
      for (int qt = 0; qt < 2; ++qt)
        pa[qt] = *(const bf16x8*)(myP + (qt * 16 + l16) * 40 + quad * 8);
#pragma unroll
      for (int nt = 0; nt < 4; ++nt) {
        bf16x8 vf = *(const bf16x8*)(bV + (nt * 16 + l16) * 64 + ((quad ^ sw) * 8));
#pragma unroll
        for (int qt = 0; qt < 2; ++qt)
          accO[qt][nt] = __builtin_amdgcn_mfma_f32_16x16x32_bf16(pa[qt], vf, accO[qt][nt], 0, 0, 0);
      }
    }
    // ---- softmax + P write, half 1 (keys 32..63; same sP slots, same-wave order) ----
#pragma unroll
    for (int k2 = 0; k2 < 2; ++k2) {
#pragma unroll
      for (int qt = 0; qt < 2; ++qt) {
        float p[4];
#pragma unroll
        for (int r = 0; r < 4; ++r) {
          bool keep = (whi[qt] >> (k2 * 16 + r)) & 1u;
          p[r] = exp2f(keep ? sc[2 + k2][qt][r] : -1e9f);
        }
        l_lane[qt] += (p[0] + p[1]) + (p[2] + p[3]);
        u32x2 pk = {packtrunc(p[0], p[1]), packtrunc(p[2], p[3])};
        *(u32x2*)(myP + (qt * 16 + l16) * 40 + k2 * 16 + quad * 4) = pk;
      }
    }
    // ---- PV half 1 ----
    {
      bf16x8 pa[2];
#pragma unroll
      for (int qt = 0; qt < 2; ++qt)
        pa[qt] = *(const bf16x8*)(myP + (qt * 16 + l16) * 40 + quad * 8);
#pragma unroll
      for (int nt = 0; nt < 4; ++nt) {
        bf16x8 vf = *(const bf16x8*)(bV + (nt * 16 + l16) * 64 + (((4 + quad) ^ sw) * 8));
#pragma unroll
        for (int qt = 0; qt < 2; ++qt)
          accO[qt][nt] = __builtin_amdgcn_mfma_f32_16x16x32_bf16(pa[qt], vf, accO[qt][nt], 0, 0, 0);
      }
    }
    wmCur[0] = wmNext[0];
    wmCur[1] = wmNext[1];
  }

  // l: sum the 4 quads of each q (q = l16 in the softmax layout)
#pragma unroll
  for (int qt = 0; qt < 2; ++qt) {
    float s = l_lane[qt];
    s += __shfl_xor(s, 16);
    s += __shfl_xor(s, 32);
    l_lane[qt] = s;
  }
  float* Op = io.O[chunk];
#pragma unroll
  for (int qt = 0; qt < 2; ++qt)
#pragma unroll
    for (int nt = 0; nt < 4; ++nt)
#pragma unroll
      for (int r = 0; r < 4; ++r) {
        int row = q0w + qt * 16 + quad * 4 + r;
        Op[((size_t)h * S + row) * 64 + nt * 16 + l16] = accO[qt][nt][r];
      }
  if (quad == 0)
#pragma unroll
    for (int qt = 0; qt < 2; ++qt)
      io.lp[((size_t)h * 4 + chunk) * S + q0w + qt * 16 + l16] = l_lane[qt];
}

// ---------------- combine 4 split-K partials -> ctx (bf16) ----------------
__global__ __launch_bounds__(256) void attn_combine(AttnIO io, u16* __restrict__ ctx) {
  const int S = 4096;
  int i = (blockIdx.x * 256 + threadIdx.x);
  int row = i >> 7;
  int col4 = (i & 127) * 4;
  int h = col4 >> 6, c = col4 & 63;
  size_t ob = ((size_t)h * S + row) * 64 + c;
  f32x4 o = {0.f, 0.f, 0.f, 0.f};
  float l = 0.f;
#pragma unroll
  for (int p = 0; p < 4; ++p) {
    o += *(const f32x4*)(io.O[p] + ob);
    l += io.lp[((size_t)h * 4 + p) * S + row];
  }
  float rl = 1.f / l;
  u16x4 out;
#pragma unroll
  for (int j = 0; j < 4; ++j) out[j] = f2bf(o[j] * rl);
  *(u16x4*)(ctx + (size_t)row * 512 + col4) = out;
}

// ---------------- residual + layernorm (rows of 512), optional 3rd input ----------
__global__ __launch_bounds__(256) void resid_ln(const float* __restrict__ X,
                                                const float* __restrict__ Y,
                                                const float* __restrict__ Y2,
                                                const float* __restrict__ g,
                                                const float* __restrict__ b,
                                                float* __restrict__ outF,
                                                u16* __restrict__ outH) {
  int row = blockIdx.x * 4 + (int)(threadIdx.x >> 6);
  int lane = threadIdx.x & 63;
  const float* x0 = X + (size_t)row * 512;
  const float* y0 = Y + (size_t)row * 512;
  int c0 = lane * 4, c1 = 256 + lane * 4;
  f32x4 v0 = *(const f32x4*)(x0 + c0) + *(const f32x4*)(y0 + c0);
  f32x4 v1 = *(const f32x4*)(x0 + c1) + *(const f32x4*)(y0 + c1);
  if (Y2) {
    const float* y2 = Y2 + (size_t)row * 512;
    v0 += *(const f32x4*)(y2 + c0);
    v1 += *(const f32x4*)(y2 + c1);
  }
  float s = 0.f, s2 = 0.f;
#pragma unroll
  for (int j = 0; j < 4; ++j) {
    s += v0[j] + v1[j];
    s2 += v0[j] * v0[j] + v1[j] * v1[j];
  }
#pragma unroll
  for (int m = 1; m < 64; m <<= 1) {
    s += __shfl_xor(s, m);
    s2 += __shfl_xor(s2, m);
  }
  float mean = s * (1.f / 512.f);
  float var = s2 * (1.f / 512.f) - mean * mean;
  float rs = rsqrtf(var + 1e-5f);
  f32x4 o0, o1;
#pragma unroll
  for (int j = 0; j < 4; ++j) {
    o0[j] = (v0[j] - mean) * rs * g[c0 + j] + b[c0 + j];
    o1[j] = (v1[j] - mean) * rs * g[c1 + j] + b[c1 + j];
  }
  if (outF) {
    *(f32x4*)(outF + (size_t)row * 512 + c0) = o0;
    *(f32x4*)(outF + (size_t)row * 512 + c1) = o1;
  }
  if (outH) {
    u16x4 h0, h1;
#pragma unroll
    for (int j = 0; j < 4; ++j) { h0[j] = f2bf(o0[j]); h1[j] = f2bf(o1[j]); }
    *(u16x4*)(outH + (size_t)row * 512 + c0) = h0;
    *(u16x4*)(outH + (size_t)row * 512 + c1) = h1;
  }
}

extern "C" void kernel_launch(void* const* d_in, const int* in_sizes, int n_in,
                              void* d_out, int out_size, void* d_ws, size_t ws_size,
                              hipStream_t stream) {
  (void)in_sizes; (void)n_in; (void)out_size; (void)ws_size;
  const float* x   = (const float*)d_in[0];
  const int*   mask= (const int*)d_in[1];
  const float* wq  = (const float*)d_in[2];
  const float* bq  = (const float*)d_in[3];
  const float* wk  = (const float*)d_in[4];
  const float* bk  = (const float*)d_in[5];
  const float* wv  = (const float*)d_in[6];
  const float* bv  = (const float*)d_in[7];
  const float* wo  = (const float*)d_in[8];
  const float* bo  = (const float*)d_in[9];
  const float* w1  = (const float*)d_in[10];
  const float* b1  = (const float*)d_in[11];
  const float* w2  = (const float*)d_in[12];
  const float* b2  = (const float*)d_in[13];
  const float* g1  = (const float*)d_in[14];
  const float* be1 = (const float*)d_in[15];
  const float* g2  = (const float*)d_in[16];
  const float* be2 = (const float*)d_in[17];

  const int S = 4096, D = 512, F = 2048;
  char* ws = (char*)d_ws;
  size_t cur = 0;
  auto alloc = [&](size_t bytes) {
    char* p = ws + cur;
    cur += (bytes + 255) & ~(size_t)255;
    return p;
  };
  u16* wqT = (u16*)alloc((size_t)D * D * 2);
  u16* wkT = (u16*)alloc((size_t)D * D * 2);
  u16* wvT = (u16*)alloc((size_t)D * D * 2);
  u16* woT = (u16*)alloc((size_t)D * D * 2);
  u16* w1T = (u16*)alloc((size_t)D * F * 2);
  u16* w2T = (u16*)alloc((size_t)D * F * 2);
  u32* mbits = (u32*)alloc((size_t)S * S / 8);
  u16* xh = (u16*)alloc((size_t)S * D * 2);
  u16* xl = (u16*)alloc((size_t)S * D * 2);
  // Qh,Kh,Vt,hx contiguous (16MB): FF1's hbuf spans them
  u16* Qh = (u16*)alloc((size_t)S * D * 2);
  u16* Kh = (u16*)alloc((size_t)S * D * 2);
  u16* Vt = (u16*)alloc((size_t)S * D * 2);
  u16* hx = (u16*)alloc((size_t)S * D * 2); (void)hx;
  u16* ctx = (u16*)alloc((size_t)S * D * 2);
  float* x1 = (float*)alloc((size_t)S * D * 4);
  u16* x1h = (u16*)alloc((size_t)S * D * 2);
  float* Oex = (float*)alloc((size_t)2 * S * D * 4);   // O2,O3 (16MB fresh)
  // aliases (lifetimes disjoint by stream order):
  AttnIO io;
  io.O[0] = (float*)xh;            // 8MB over xh+xl (dead after QKV gemm)
  io.O[1] = x1;                    // 8MB (x1 written later by resid_ln, after combine)
  io.O[2] = Oex;
  io.O[3] = Oex + (size_t)S * D;
  io.lp = (float*)x1h;             // 512KB (x1h written later by resid_ln)
  float* proj = (float*)xh;        // OP partial 0 (after combine read O[0])
  float* projB = Oex + (size_t)S * D;  // OP partial 1 (O[3] region, after combine read)
  u16* hbuf = Qh;                  // FF1 output (16MB over Qh,Kh,Vt,hx), after attn
  float* ff2 = Oex;                // FF2 partial 0 (O[2] region, after combine read)
  float* ff2B = Oex + (size_t)S * D;   // FF2 partial 1 (O[3]; OP partial 1 dead after LN1)

  PrepArgs pa;
  pa.x = x; pa.xh = xh; pa.xl = xl;
  pa.mask = mask; pa.mbits = (unsigned long long*)mbits;
  pa.pw[0] = {wq, wqT, nullptr, D, D, 15, 4};
  pa.pw[1] = {wk, wkT, nullptr, D, D, 15, 4};
  pa.pw[2] = {wv, wvT, nullptr, D, D, 15, 4};
  pa.pw[3] = {wo, woT, nullptr, D, D, 15, 4};
  pa.pw[4] = {w1, w1T, nullptr, D, F, 63, 6};
  pa.pw[5] = {w2, w2T, nullptr, F, D, 15, 4};

  QkvArgs qa;
  qa.Ah = xh; qa.Al = xl;
  qa.Bh[0] = wqT; qa.Bh[1] = wkT; qa.Bh[2] = wvT;
  qa.bias[0] = bq; qa.bias[1] = bk; qa.bias[2] = bv;
  qa.Qh = Qh; qa.Kh = Kh; qa.Vt = Vt;

  // 1. fused prep
  prep<<<70656, 256, 0, stream>>>(pa);
  // 2. QKV projection (x hi/lo, w bf16; Q prescaled; V transposed)
  gemm_qkv<<<dim3(4, 32, 3), 256, 0, stream>>>(qa);
  // 3. flash attention (split-phase pipeline, split-K x4) + combine
  attn<<<dim3(32, 32), 256, 0, stream>>>(Qh, Kh, Vt, (const u64*)mbits, io);
  attn_combine<<<(S * D / 4) / 256, 256, 0, stream>>>(io, ctx);
  // 4. output projection, split-K x2 -> two partial buffers (256 blocks)
  gemm_bt<0, 0, 2><<<dim3(4, 32, 2), 256, 0, stream>>>(ctx, woT, bo, proj, projB, nullptr, D, D);
  // 5. residual + LN1 (x + proj0 + proj1)
  resid_ln<<<S / 4, 256, 0, stream>>>(x, proj, projB, g1, be1, x1, x1h);
  // 6. FFN: FF1 direct (512 blocks); FF2 split-K x2 (256 blocks)
  gemm_bt<1, 1, 1><<<dim3(16, 32), 256, 0, stream>>>(x1h, w1T, b1, nullptr, nullptr, hbuf, F, D);
  gemm_bt<0, 0, 2><<<dim3(4, 32, 2), 256, 0, stream>>>(hbuf, w2T, b2, ff2, ff2B, nullptr, D, F);
  // 7. residual + LN2 (x1 + ff2a + ff2b) -> final fp32 output
  resid_ln<<<S / 4, 256, 0, stream>>>(x1, ff2, ff2B, g2, be2, (float*)d_out, nullptr);
}

// Round 12
// 309.534 us; speedup vs baseline: 2.0763x; 1.0426x over previous
//
#include <hip/hip_runtime.h>

typedef unsigned short u16;
typedef unsigned int u32;
typedef unsigned long long u64;
typedef __attribute__((ext_vector_type(4))) float f32x4;
typedef __attribute__((ext_vector_type(8))) short bf16x8;   // 8 bf16 (4 VGPRs)
typedef __attribute__((ext_vector_type(4))) u16 u16x4;
typedef __attribute__((ext_vector_type(2))) u32 u32x2;

#define DEV __device__ __forceinline__

DEV u16 f2bf(float f) {               // RNE fp32 -> bf16
  union { float f; u32 u; } c; c.f = f;
  u32 u = c.u;
  u += 0x7fffu + ((u >> 16) & 1u);
  return (u16)(u >> 16);
}
DEV float bf2f(u16 h) {
  union { u32 u; float f; } c; c.u = ((u32)h) << 16;
  return c.f;
}
DEV u32 fbits(float f) { union { float f; u32 u; } c; c.f = f; return c.u; }
// pack two fp32 -> two truncated bf16 in one u32 (a = low, b = high):
// single v_perm_b32 byte shuffle (D.b01 = a.b23, D.b23 = b.b23)
DEV u32 packtrunc(float a, float b) {
  return __builtin_amdgcn_perm(fbits(b), fbits(a), 0x07060302u);
}

// async global->LDS, 16B per lane. Dest is WAVE-UNIFORM base + lane*16 (m104/m108).
DEV void gload_lds16(const void* g, void* l) {
  __builtin_amdgcn_global_load_lds(
      (const __attribute__((address_space(1))) u32*)(u64)g,
      (__attribute__((address_space(3))) u32*)(u32)(u64)l,   // low 32 bits = LDS offset
      16, 0, 0);
}

// ---------------- fused prep: x split + 6 weight transposes (hi only) + mask pack -----
struct PrepW { const float* w; u16* th; u16* tl; int R, C, gxmask, gxshift; };
struct PrepArgs {
  const float* x; u16* xh; u16* xl;
  const int* mask; unsigned long long* mbits;
  PrepW pw[6];
};

__global__ __launch_bounds__(256) void prep(PrepArgs a) {
  __shared__ float t[32][33];
  int b = blockIdx.x, tid = threadIdx.x;
  if (b < 2048) {                       // x -> bf16 hi/lo
    int i = (b * 256 + tid) * 4;
    f32x4 v = *(const f32x4*)(a.x + i);
    u16x4 h, l;
#pragma unroll
    for (int j = 0; j < 4; ++j) { h[j] = f2bf(v[j]); l[j] = f2bf(v[j] - bf2f(h[j])); }
    *(u16x4*)(a.xh + i) = h;
    *(u16x4*)(a.xl + i) = l;
    return;
  }
  b -= 2048;
  if (b < 3072) {                       // weight (R,C) -> transposed (C,R)
    int wi, base;
    if (b < 1024) { wi = b >> 8; base = b & 255; }
    else if (b < 2048) { wi = 4; base = b - 1024; }
    else { wi = 5; base = b - 2048; }
    PrepW p = a.pw[wi];
    int c0 = (base & p.gxmask) * 32, r0 = (base >> p.gxshift) * 32;
    int tx = tid & 31, ty = tid >> 5;
#pragma unroll
    for (int i = 0; i < 4; ++i)
      t[ty + 8 * i][tx] = p.w[(size_t)(r0 + ty + 8 * i) * p.C + c0 + tx];
    __syncthreads();
#pragma unroll
    for (int i = 0; i < 4; ++i) {
      float v = t[tx][ty + 8 * i];
      u16 h = f2bf(v);
      size_t o = (size_t)(c0 + ty + 8 * i) * p.R + r0 + tx;
      p.th[o] = h;
      if (p.tl) p.tl[o] = f2bf(v - bf2f(h));
    }
    return;
  }
  b -= 3072;                            // mask -> bitmask
  size_t i = (size_t)b * 256 + tid;
  unsigned long long bb = __ballot(a.mask[i] != 0);
  if ((tid & 63) == 0) a.mbits[i >> 6] = bb;
}

// ---------------- QKV GEMM: double-buffered, x hi/lo (2 MFMA), w single bf16 ---------
// z=0 -> Qh (prescaled by log2e), z=1 -> Kh, z=2 -> Vt (transposed bf16).
struct QkvArgs {
  const u16 *Ah, *Al;
  const u16 *Bh[3];
  const float* bias[3];
  u16 *Qh, *Kh, *Vt;
};

__global__ __launch_bounds__(256) void gemm_qkv(QkvArgs a) {
  const int K = 512;
  const float L2E = 1.44269504088896340736f;
  const int z = blockIdx.z;
  const u16* __restrict__ Bh = a.Bh[z];
  const float* __restrict__ bias = a.bias[z];
  const int bn = blockIdx.x * 128, bm = blockIdx.y * 128;
  const int tid = threadIdx.x;
  const int wave = tid >> 6, lane = tid & 63;
  const int l16 = lane & 15, quad = lane >> 4;
  const int wm = (wave >> 1) * 64, wn = (wave & 1) * 64;

  __shared__ u16 sA[2][128 * 32];
  __shared__ u16 sAl[2][128 * 32];
  __shared__ u16 sB[2][128 * 32];

  const int srow = wave * 32 + (lane >> 2);
  const int scol = (lane & 3) * 8;
  const u16* srcA0 = a.Ah + (size_t)(bm + srow) * K + scol;
  const u16* srcAl0 = a.Al + (size_t)(bm + srow) * K + scol;
  const u16* srcB0 = Bh + (size_t)(bn + srow) * K + scol;
  const size_t half_off = (size_t)16 * K;

  auto prefetchG = [&](int kt, int buf) {
    u16* dA = sA[buf] + wave * 1024;
    u16* dAl = sAl[buf] + wave * 1024;
    u16* dB = sB[buf] + wave * 1024;
    gload_lds16(srcA0 + kt, dA);
    gload_lds16(srcA0 + half_off + kt, dA + 512);
    gload_lds16(srcAl0 + kt, dAl);
    gload_lds16(srcAl0 + half_off + kt, dAl + 512);
    gload_lds16(srcB0 + kt, dB);
    gload_lds16(srcB0 + half_off + kt, dB + 512);
  };

  f32x4 acc[4][4] = {};
  prefetchG(0, 0);

  for (int i = 0; i < 16; ++i) {
    __syncthreads();
    if (i + 1 < 16) prefetchG((i + 1) << 5, (i + 1) & 1);
    const u16* bufA = sA[i & 1];
    const u16* bufAl = sAl[i & 1];
    const u16* bufB = sB[i & 1];

    bf16x8 a_h[4], a_l[4], b_h[4];
#pragma unroll
    for (int mt = 0; mt < 4; ++mt) {
      a_h[mt] = *(const bf16x8*)(bufA + (wm + mt * 16 + l16) * 32 + quad * 8);
      a_l[mt] = *(const bf16x8*)(bufAl + (wm + mt * 16 + l16) * 32 + quad * 8);
    }
#pragma unroll
    for (int nt = 0; nt < 4; ++nt)
      b_h[nt] = *(const bf16x8*)(bufB + (wn + nt * 16 + l16) * 32 + quad * 8);
#pragma unroll
    for (int mt = 0; mt < 4; ++mt)
#pragma unroll
      for (int nt = 0; nt < 4; ++nt) {
        acc[mt][nt] = __builtin_amdgcn_mfma_f32_16x16x32_bf16(a_h[mt], b_h[nt], acc[mt][nt], 0, 0, 0);
        acc[mt][nt] = __builtin_amdgcn_mfma_f32_16x16x32_bf16(a_l[mt], b_h[nt], acc[mt][nt], 0, 0, 0);
      }
  }

  if (z == 2) {
    // V: write transposed bf16 Vt[dim][seq]; r-regs are seq-contiguous -> 8B stores
#pragma unroll
    for (int nt = 0; nt < 4; ++nt) {
      int col = bn + wn + nt * 16 + l16;
      float bv = bias[col];
#pragma unroll
      for (int mt = 0; mt < 4; ++mt) {
        int row0 = bm + wm + mt * 16 + quad * 4;
        u16x4 o;
#pragma unroll
        for (int r = 0; r < 4; ++r) o[r] = f2bf(acc[mt][nt][r] + bv);
        *(u16x4*)(a.Vt + (size_t)col * 4096 + row0) = o;
      }
    }
  } else {
    u16* __restrict__ C = (z == 0) ? a.Qh : a.Kh;
    float scale = (z == 0) ? L2E : 1.f;
#pragma unroll
    for (int mt = 0; mt < 4; ++mt)
#pragma unroll
      for (int nt = 0; nt < 4; ++nt) {
        int col = bn + wn + nt * 16 + l16;
        float bv = bias[col];
#pragma unroll
        for (int r = 0; r < 4; ++r) {
          int row = bm + wm + mt * 16 + quad * 4 + r;
          C[(size_t)row * 512 + col] = f2bf((acc[mt][nt][r] + bv) * scale);
        }
      }
  }
}

// ---------------- generic staged GEMM, double-buffered, optional split-K x2 ----------
// NSPLIT=2: z=0 -> Cf (with bias), z=1 -> Cf2 (no bias); consumer sums partials
// (resid_ln 3-input). No atomics, no zeroing.
template <int RELU, int BF16OUT, int NSPLIT>
__global__ __launch_bounds__(256) void gemm_bt(const u16* __restrict__ Ah,
                                               const u16* __restrict__ Bh,
                                               const float* __restrict__ bias,
                                               float* __restrict__ Cf,
                                               float* __restrict__ Cf2,
                                               u16* __restrict__ Ch,
                                               int N, int K) {
  const int z = (NSPLIT > 1) ? blockIdx.z : 0;
  const int Ksub = K / NSPLIT;
  const int kbeg = z * Ksub;
  const int bn = blockIdx.x * 128, bm = blockIdx.y * 128;
  const int tid = threadIdx.x;
  const int wave = tid >> 6, lane = tid & 63;
  const int l16 = lane & 15, quad = lane >> 4;
  const int wm = (wave >> 1) * 64, wn = (wave & 1) * 64;

  __shared__ u16 sA[2][128 * 32];
  __shared__ u16 sB[2][128 * 32];

  const int srow = wave * 32 + (lane >> 2);
  const int scol = (lane & 3) * 8;
  const u16* srcA0 = Ah + (size_t)(bm + srow) * K + kbeg + scol;
  const u16* srcB0 = Bh + (size_t)(bn + srow) * K + kbeg + scol;
  const size_t half_off = (size_t)16 * K;

  auto prefetchG = [&](int kt, int buf) {
    u16* dA = sA[buf] + wave * 1024;
    u16* dB = sB[buf] + wave * 1024;
    gload_lds16(srcA0 + kt, dA);
    gload_lds16(srcA0 + half_off + kt, dA + 512);
    gload_lds16(srcB0 + kt, dB);
    gload_lds16(srcB0 + half_off + kt, dB + 512);
  };

  f32x4 acc[4][4] = {};
  prefetchG(0, 0);

  const int steps = Ksub >> 5;
  for (int i = 0; i < steps; ++i) {
    __syncthreads();
    if (i + 1 < steps) prefetchG((i + 1) << 5, (i + 1) & 1);
    const u16* bufA = sA[i & 1];
    const u16* bufB = sB[i & 1];

    bf16x8 a_h[4], b_h[4];
#pragma unroll
    for (int mt = 0; mt < 4; ++mt)
      a_h[mt] = *(const bf16x8*)(bufA + (wm + mt * 16 + l16) * 32 + quad * 8);
#pragma unroll
    for (int nt = 0; nt < 4; ++nt)
      b_h[nt] = *(const bf16x8*)(bufB + (wn + nt * 16 + l16) * 32 + quad * 8);
#pragma unroll
    for (int mt = 0; mt < 4; ++mt)
#pragma unroll
      for (int nt = 0; nt < 4; ++nt)
        acc[mt][nt] = __builtin_amdgcn_mfma_f32_16x16x32_bf16(a_h[mt], b_h[nt], acc[mt][nt], 0, 0, 0);
  }

  float* __restrict__ Co = (NSPLIT > 1 && z == 1) ? Cf2 : Cf;
#pragma unroll
  for (int mt = 0; mt < 4; ++mt)
#pragma unroll
    for (int nt = 0; nt < 4; ++nt) {
      int col = bn + wn + nt * 16 + l16;
      float bv = (bias && z == 0) ? bias[col] : 0.f;
#pragma unroll
      for (int r = 0; r < 4; ++r) {
        int row = bm + wm + mt * 16 + quad * 4 + r;
        float v = acc[mt][nt][r] + bv;
        if (RELU) v = fmaxf(v, 0.f);
        size_t oidx = (size_t)row * N + col;
        if (BF16OUT) Ch[oidx] = f2bf(v);
        else Co[oidx] = v;
      }
    }
}

// ---------------- flash attention v8: split-phase pipeline + raw v_exp/v_perm -------
// Grid (32 = 8h x 4chunk, 32 qb) = 1024 blocks. Per 64-key iter:
//   [A] -> issue V(it+1) (dbuf) -> QK + softmax/P half0
//   [B] -> issue K(it+1)        -> PV half0, softmax half1, PV half1
// VALU diet (r11 was VALU-issue-bound at 70% busy): exp2f -> raw v_exp_f32
// (__builtin_amdgcn_exp2f; inputs bounded, -1e9 underflows to exactly 0, so
// libm's 5-op range-guard sequence is unnecessary); bf16-pair pack -> single
// v_perm_b32. ~60% of per-iter VALU ops removed.
struct AttnIO { float* O[4]; float* lp; };

__global__ __launch_bounds__(256) void attn(const u16* __restrict__ Qh,
                                            const u16* __restrict__ Kh,
                                            const u16* __restrict__ Vt,
                                            const u64* __restrict__ mb64,
                                            AttnIO io) {
  const int S = 4096, D = 512;
  const int h = blockIdx.x >> 2, chunk = blockIdx.x & 3;
  const int tid = threadIdx.x, wave = tid >> 6, lane = tid & 63;
  const int l16 = lane & 15, quad = lane >> 4;
  const int q0w = blockIdx.y * 128 + wave * 32;
  const int kbeg = chunk * 1024;
  const int sw = l16 & 7;                       // bank-swizzle key

  __shared__ u16 sK[64 * 64];                   // [key][dim]        8 KB
  __shared__ u16 sV[2][64 * 64];                // [dim][key] dbuf  16 KB
  __shared__ u16 sP[4][32 * 40];                // per-wave P       10 KB
  u16* myP = &sP[wave][0];

  const int skey = lane >> 3;
  const int sch  = lane & 7;
  const u16* srcK = Kh + (size_t)(kbeg + wave * 8 + skey) * D + h * 64 + ((sch ^ skey) * 8);
  const u16* srcV = Vt + (size_t)(h * 64 + wave * 8 + skey) * S + kbeg + ((sch ^ skey) * 8);
  u16* dstK = sK + wave * 512;

  auto stageK = [&](int it) {
    const u16* p = srcK + (size_t)it * 64 * D;
    gload_lds16(p, dstK);
    gload_lds16(p + (size_t)32 * D, dstK + 32 * 64);
  };
  auto stageV = [&](int it) {
    const u16* p = srcV + it * 64;
    u16* d = sV[it & 1] + wave * 512;
    gload_lds16(p, d);
    gload_lds16(p + (size_t)32 * S, d + 32 * 64);
  };

  // Q prefetch: B-frags (n=l16 -> q, k=quad*8 dims), single bf16 prescaled
  bf16x8 qf[2][2];
#pragma unroll
  for (int qt = 0; qt < 2; ++qt)
#pragma unroll
    for (int kd = 0; kd < 2; ++kd)
      qf[qt][kd] = *(const bf16x8*)(Qh + (size_t)(q0w + qt * 16 + l16) * D + h * 64 + kd * 32 + quad * 8);

  f32x4 accO[2][4] = {};
  float l_lane[2] = {0.f, 0.f};
  const int wbase = kbeg >> 6;

  stageV(0);
  stageK(0);
  u64 wmCur[2];
#pragma unroll
  for (int qt = 0; qt < 2; ++qt)
    wmCur[qt] = mb64[(size_t)(q0w + qt * 16 + l16) * 64 + wbase];

  for (int it = 0; it < 16; ++it) {
    __syncthreads();                          // A: V(it)/K(it) staged (issued a phase ago)
    if (it + 1 < 16) stageV(it + 1);          // into the other V buffer
    u64 wmNext[2] = {0, 0};
    if (it + 1 < 16) {
#pragma unroll
      for (int qt = 0; qt < 2; ++qt)
        wmNext[qt] = mb64[(size_t)(q0w + qt * 16 + l16) * 64 + wbase + it + 1];
    }
    // hoist lane-dependent mask shift: bit (k2*16+r) of wlo/whi
    u32 wlo[2], whi[2];
#pragma unroll
    for (int qt = 0; qt < 2; ++qt) {
      wlo[qt] = (u32)(wmCur[qt] >> (quad * 4));
      whi[qt] = (u32)(wmCur[qt] >> (quad * 4 + 32));
    }

    // ---- QK phase: the ONLY sK reads ----
    f32x4 sc[4][2];
#pragma unroll
    for (int kt4 = 0; kt4 < 4; ++kt4) {
      const u16* arow = sK + (kt4 * 16 + l16) * 64;
      bf16x8 ka0 = *(const bf16x8*)(arow + ((quad ^ sw) * 8));
      bf16x8 ka1 = *(const bf16x8*)(arow + (((4 + quad) ^ sw) * 8));
#pragma unroll
      for (int qt = 0; qt < 2; ++qt) {
        f32x4 s = {};
        s = __builtin_amdgcn_mfma_f32_16x16x32_bf16(ka0, qf[qt][0], s, 0, 0, 0);
        s = __builtin_amdgcn_mfma_f32_16x16x32_bf16(ka1, qf[qt][1], s, 0, 0, 0);
        sc[kt4][qt] = s;
      }
    }
    // ---- softmax + P write, half 0 (keys 0..31) ----
#pragma unroll
    for (int k2 = 0; k2 < 2; ++k2) {
#pragma unroll
      for (int qt = 0; qt < 2; ++qt) {
        float p[4];
#pragma unroll
        for (int r = 0; r < 4; ++r) {
          bool keep = (wlo[qt] >> (k2 * 16 + r)) & 1u;
          p[r] = __builtin_amdgcn_exp2f(keep ? sc[k2][qt][r] : -1e9f);
        }
        l_lane[qt] += (p[0] + p[1]) + (p[2] + p[3]);
        u32x2 pk = {packtrunc(p[0], p[1]), packtrunc(p[2], p[3])};
        *(u32x2*)(myP + (qt * 16 + l16) * 40 + k2 * 16 + quad * 4) = pk;
      }
    }
    __syncthreads();                          // B: all waves done with sK
    if (it + 1 < 16) stageK(it + 1);
    const u16* bV = sV[it & 1];

    // ---- PV half 0 ----
    {
      bf16x8 pa[2];
#pragma unroll
      for (int qt = 0; qt < 2; ++qt)
        pa[qt] = *(const bf16x8*)(myP + (qt * 16 + l16) * 40 + quad * 8);
#pragma unroll
      for (int nt = 0; nt < 4; ++nt) {
        bf16x8 vf = *(const bf16x8*)(bV + (nt * 16 + l16) * 64 + ((quad ^ sw) * 8));
#pragma unroll
        for (int qt = 0; qt < 2; ++qt)
          accO[qt][nt] = __builtin_amdgcn_mfma_f32_16x16x32_bf16(pa[qt], vf, accO[qt][nt], 0, 0, 0);
      }
    }
    // ---- softmax + P write, half 1 (keys 32..63; same sP slots, same-wave order) ----
#pragma unroll
    for (int k2 = 0; k2 < 2; ++k2) {
#pragma unroll
      for (int qt = 0; qt < 2; ++qt) {
        float p[4];
#pragma unroll
        for (int r = 0; r < 4; ++r) {
          bool keep = (whi[qt] >> (k2 * 16 + r)) & 1u;
          p[r] = __builtin_amdgcn_exp2f(keep ? sc[2 + k2][qt][r] : -1e9f);
        }
        l_lane[qt] += (p[0] + p[1]) + (p[2] + p[3]);
        u32x2 pk = {packtrunc(p[0], p[1]), packtrunc(p[2], p[3])};
        *(u32x2*)(myP + (qt * 16 + l16) * 40 + k2 * 16 + quad * 4) = pk;
      }
    }
    // ---- PV half 1 ----
    {
      bf16x8 pa[2];
#pragma unroll
      for (int qt = 0; qt < 2; ++qt)
        pa[qt] = *(const bf16x8*)(myP + (qt * 16 + l16) * 40 + quad * 8);
#pragma unroll
      for (int nt = 0; nt < 4; ++nt) {
        bf16x8 vf = *(const bf16x8*)(bV + (nt * 16 + l16) * 64 + (((4 + quad) ^ sw) * 8));
#pragma unroll
        for (int qt = 0; qt < 2; ++qt)
          accO[qt][nt] = __builtin_amdgcn_mfma_f32_16x16x32_bf16(pa[qt], vf, accO[qt][nt], 0, 0, 0);
      }
    }
    wmCur[0] = wmNext[0];
    wmCur[1] = wmNext[1];
  }

  // l: sum the 4 quads of each q (q = l16 in the softmax layout)
#pragma unroll
  for (int qt = 0; qt < 2; ++qt) {
    float s = l_lane[qt];
    s += __shfl_xor(s, 16);
    s += __shfl_xor(s, 32);
    l_lane[qt] = s;
  }
  float* Op = io.O[chunk];
#pragma unroll
  for (int qt = 0; qt < 2; ++qt)
#pragma unroll
    for (int nt = 0; nt < 4; ++nt)
#pragma unroll
      for (int r = 0; r < 4; ++r) {
        int row = q0w + qt * 16 + quad * 4 + r;
        Op[((size_t)h * S + row) * 64 + nt * 16 + l16] = accO[qt][nt][r];
      }
  if (quad == 0)
#pragma unroll
    for (int qt = 0; qt < 2; ++qt)
      io.lp[((size_t)h * 4 + chunk) * S + q0w + qt * 16 + l16] = l_lane[qt];
}

// ---------------- combine 4 split-K partials -> ctx (bf16) ----------------
__global__ __launch_bounds__(256) void attn_combine(AttnIO io, u16* __restrict__ ctx) {
  const int S = 4096;
  int i = (blockIdx.x * 256 + threadIdx.x);
  int row = i >> 7;
  int col4 = (i & 127) * 4;
  int h = col4 >> 6, c = col4 & 63;
  size_t ob = ((size_t)h * S + row) * 64 + c;
  f32x4 o = {0.f, 0.f, 0.f, 0.f};
  float l = 0.f;
#pragma unroll
  for (int p = 0; p < 4; ++p) {
    o += *(const f32x4*)(io.O[p] + ob);
    l += io.lp[((size_t)h * 4 + p) * S + row];
  }
  float rl = 1.f / l;
  u16x4 out;
#pragma unroll
  for (int j = 0; j < 4; ++j) out[j] = f2bf(o[j] * rl);
  *(u16x4*)(ctx + (size_t)row * 512 + col4) = out;
}

// ---------------- residual + layernorm (rows of 512), optional 3rd input ----------
__global__ __launch_bounds__(256) void resid_ln(const float* __restrict__ X,
                                                const float* __restrict__ Y,
                                                const float* __restrict__ Y2,
                                                const float* __restrict__ g,
                                                const float* __restrict__ b,
                                                float* __restrict__ outF,
                                                u16* __restrict__ outH) {
  int row = blockIdx.x * 4 + (int)(threadIdx.x >> 6);
  int lane = threadIdx.x & 63;
  const float* x0 = X + (size_t)row * 512;
  const float* y0 = Y + (size_t)row * 512;
  int c0 = lane * 4, c1 = 256 + lane * 4;
  f32x4 v0 = *(const f32x4*)(x0 + c0) + *(const f32x4*)(y0 + c0);
  f32x4 v1 = *(const f32x4*)(x0 + c1) + *(const f32x4*)(y0 + c1);
  if (Y2) {
    const float* y2 = Y2 + (size_t)row * 512;
    v0 += *(const f32x4*)(y2 + c0);
    v1 += *(const f32x4*)(y2 + c1);
  }
  float s = 0.f, s2 = 0.f;
#pragma unroll
  for (int j = 0; j < 4; ++j) {
    s += v0[j] + v1[j];
    s2 += v0[j] * v0[j] + v1[j] * v1[j];
  }
#pragma unroll
  for (int m = 1; m < 64; m <<= 1) {
    s += __shfl_xor(s, m);
    s2 += __shfl_xor(s2, m);
  }
  float mean = s * (1.f / 512.f);
  float var = s2 * (1.f / 512.f) - mean * mean;
  float rs = rsqrtf(var + 1e-5f);
  f32x4 o0, o1;
#pragma unroll
  for (int j = 0; j < 4; ++j) {
    o0[j] = (v0[j] - mean) * rs * g[c0 + j] + b[c0 + j];
    o1[j] = (v1[j] - mean) * rs * g[c1 + j] + b[c1 + j];
  }
  if (outF) {
    *(f32x4*)(outF + (size_t)row * 512 + c0) = o0;
    *(f32x4*)(outF + (size_t)row * 512 + c1) = o1;
  }
  if (outH) {
    u16x4 h0, h1;
#pragma unroll
    for (int j = 0; j < 4; ++j) { h0[j] = f2bf(o0[j]); h1[j] = f2bf(o1[j]); }
    *(u16x4*)(outH + (size_t)row * 512 + c0) = h0;
    *(u16x4*)(outH + (size_t)row * 512 + c1) = h1;
  }
}

extern "C" void kernel_launch(void* const* d_in, const int* in_sizes, int n_in,
                              void* d_out, int out_size, void* d_ws, size_t ws_size,
                              hipStream_t stream) {
  (void)in_sizes; (void)n_in; (void)out_size; (void)ws_size;
  const float* x   = (const float*)d_in[0];
  const int*   mask= (const int*)d_in[1];
  const float* wq  = (const float*)d_in[2];
  const float* bq  = (const float*)d_in[3];
  const float* wk  = (const float*)d_in[4];
  const float* bk  = (const float*)d_in[5];
  const float* wv  = (const float*)d_in[6];
  const float* bv  = (const float*)d_in[7];
  const float* wo  = (const float*)d_in[8];
  const float* bo  = (const float*)d_in[9];
  const float* w1  = (const float*)d_in[10];
  const float* b1  = (const float*)d_in[11];
  const float* w2  = (const float*)d_in[12];
  const float* b2  = (const float*)d_in[13];
  const float* g1  = (const float*)d_in[14];
  const float* be1 = (const float*)d_in[15];
  const float* g2  = (const float*)d_in[16];
  const float* be2 = (const float*)d_in[17];

  const int S = 4096, D = 512, F = 2048;
  char* ws = (char*)d_ws;
  size_t cur = 0;
  auto alloc = [&](size_t bytes) {
    char* p = ws + cur;
    cur += (bytes + 255) & ~(size_t)255;
    return p;
  };
  u16* wqT = (u16*)alloc((size_t)D * D * 2);
  u16* wkT = (u16*)alloc((size_t)D * D * 2);
  u16* wvT = (u16*)alloc((size_t)D * D * 2);
  u16* woT = (u16*)alloc((size_t)D * D * 2);
  u16* w1T = (u16*)alloc((size_t)D * F * 2);
  u16* w2T = (u16*)alloc((size_t)D * F * 2);
  u32* mbits = (u32*)alloc((size_t)S * S / 8);
  u16* xh = (u16*)alloc((size_t)S * D * 2);
  u16* xl = (u16*)alloc((size_t)S * D * 2);
  // Qh,Kh,Vt,hx contiguous (16MB): FF1's hbuf spans them
  u16* Qh = (u16*)alloc((size_t)S * D * 2);
  u16* Kh = (u16*)alloc((size_t)S * D * 2);
  u16* Vt = (u16*)alloc((size_t)S * D * 2);
  u16* hx = (u16*)alloc((size_t)S * D * 2); (void)hx;
  u16* ctx = (u16*)alloc((size_t)S * D * 2);
  float* x1 = (float*)alloc((size_t)S * D * 4);
  u16* x1h = (u16*)alloc((size_t)S * D * 2);
  float* Oex = (float*)alloc((size_t)2 * S * D * 4);   // O2,O3 (16MB fresh)
  // aliases (lifetimes disjoint by stream order):
  AttnIO io;
  io.O[0] = (float*)xh;            // 8MB over xh+xl (dead after QKV gemm)
  io.O[1] = x1;                    // 8MB (x1 written later by resid_ln, after combine)
  io.O[2] = Oex;
  io.O[3] = Oex + (size_t)S * D;
  io.lp = (float*)x1h;             // 512KB (x1h written later by resid_ln)
  float* proj = (float*)xh;        // OP partial 0 (after combine read O[0])
  float* projB = Oex + (size_t)S * D;  // OP partial 1 (O[3] region, after combine read)
  u16* hbuf = Qh;                  // FF1 output (16MB over Qh,Kh,Vt,hx), after attn
  float* ff2 = Oex;                // FF2 partial 0 (O[2] region, after combine read)
  float* ff2B = Oex + (size_t)S * D;   // FF2 partial 1 (O[3]; OP partial 1 dead after LN1)

  PrepArgs pa;
  pa.x = x; pa.xh = xh; pa.xl = xl;
  pa.mask = mask; pa.mbits = (unsigned long long*)mbits;
  pa.pw[0] = {wq, wqT, nullptr, D, D, 15, 4};
  pa.pw[1] = {wk, wkT, nullptr, D, D, 15, 4};
  pa.pw[2] = {wv, wvT, nullptr, D, D, 15, 4};
  pa.pw[3] = {wo, woT, nullptr, D, D, 15, 4};
  pa.pw[4] = {w1, w1T, nullptr, D, F, 63, 6};
  pa.pw[5] = {w2, w2T, nullptr, F, D, 15, 4};

  QkvArgs qa;
  qa.Ah = xh; qa.Al = xl;
  qa.Bh[0] = wqT; qa.Bh[1] = wkT; qa.Bh[2] = wvT;
  qa.bias[0] = bq; qa.bias[1] = bk; qa.bias[2] = bv;
  qa.Qh = Qh; qa.Kh = Kh; qa.Vt = Vt;

  // 1. fused prep
  prep<<<70656, 256, 0, stream>>>(pa);
  // 2. QKV projection (x hi/lo, w bf16; Q prescaled; V transposed)
  gemm_qkv<<<dim3(4, 32, 3), 256, 0, stream>>>(qa);
  // 3. flash attention (split-phase pipeline, split-K x4) + combine
  attn<<<dim3(32, 32), 256, 0, stream>>>(Qh, Kh, Vt, (const u64*)mbits, io);
  attn_combine<<<(S * D / 4) / 256, 256, 0, stream>>>(io, ctx);
  // 4. output projection, split-K x2 -> two partial buffers (256 blocks)
  gemm_bt<0, 0, 2><<<dim3(4, 32, 2), 256, 0, stream>>>(ctx, woT, bo, proj, projB, nullptr, D, D);
  // 5. residual + LN1 (x + proj0 + proj1)
  resid_ln<<<S / 4, 256, 0, stream>>>(x, proj, projB, g1, be1, x1, x1h);
  // 6. FFN: FF1 direct (512 blocks); FF2 split-K x2 (256 blocks)
  gemm_bt<1, 1, 1><<<dim3(16, 32), 256, 0, stream>>>(x1h, w1T, b1, nullptr, nullptr, hbuf, F, D);
  gemm_bt<0, 0, 2><<<dim3(4, 32, 2), 256, 0, stream>>>(hbuf, w2T, b2, ff2, ff2B, nullptr, D, F);
  // 7. residual + LN2 (x1 + ff2a + ff2b) -> final fp32 output
  resid_ln<<<S / 4, 256, 0, stream>>>(x1, ff2, ff2B, g2, be2, (float*)d_out, nullptr);
}

// Round 13
// 308.930 us; speedup vs baseline: 2.0803x; 1.0020x over previous
//
#include <hip/hip_runtime.h>

typedef unsigned short u16;
typedef unsigned int u32;
typedef unsigned long long u64;
typedef __attribute__((ext_vector_type(4))) float f32x4;
typedef __attribute__((ext_vector_type(8))) short bf16x8;   // 8 bf16 (4 VGPRs)
typedef __attribute__((ext_vector_type(4))) u16 u16x4;
typedef __attribute__((ext_vector_type(2))) u32 u32x2;

#define DEV __device__ __forceinline__

DEV u16 f2bf(float f) {               // RNE fp32 -> bf16
  union { float f; u32 u; } c; c.f = f;
  u32 u = c.u;
  u += 0x7fffu + ((u >> 16) & 1u);
  return (u16)(u >> 16);
}
DEV float bf2f(u16 h) {
  union { u32 u; float f; } c; c.u = ((u32)h) << 16;
  return c.f;
}
DEV u32 fbits(float f) { union { float f; u32 u; } c; c.f = f; return c.u; }
// pack two truncated-bf16 (given as fp32 bit patterns) into one u32: 1x v_perm_b32
DEV u32 packbits(u32 a, u32 b) {
  return __builtin_amdgcn_perm(b, a, 0x07060302u);
}

// async global->LDS, 16B per lane. Dest is WAVE-UNIFORM base + lane*16 (m104/m108).
DEV void gload_lds16(const void* g, void* l) {
  __builtin_amdgcn_global_load_lds(
      (const __attribute__((address_space(1))) u32*)(u64)g,
      (__attribute__((address_space(3))) u32*)(u32)(u64)l,   // low 32 bits = LDS offset
      16, 0, 0);
}

// ---------------- fused prep: x split + 6 weight transposes (hi only) + mask pack -----
struct PrepW { const float* w; u16* th; u16* tl; int R, C, gxmask, gxshift; };
struct PrepArgs {
  const float* x; u16* xh; u16* xl;
  const int* mask; unsigned long long* mbits;
  PrepW pw[6];
};

__global__ __launch_bounds__(256) void prep(PrepArgs a) {
  __shared__ float t[32][33];
  int b = blockIdx.x, tid = threadIdx.x;
  if (b < 2048) {                       // x -> bf16 hi/lo
    int i = (b * 256 + tid) * 4;
    f32x4 v = *(const f32x4*)(a.x + i);
    u16x4 h, l;
#pragma unroll
    for (int j = 0; j < 4; ++j) { h[j] = f2bf(v[j]); l[j] = f2bf(v[j] - bf2f(h[j])); }
    *(u16x4*)(a.xh + i) = h;
    *(u16x4*)(a.xl + i) = l;
    return;
  }
  b -= 2048;
  if (b < 3072) {                       // weight (R,C) -> transposed (C,R)
    int wi, base;
    if (b < 1024) { wi = b >> 8; base = b & 255; }
    else if (b < 2048) { wi = 4; base = b - 1024; }
    else { wi = 5; base = b - 2048; }
    PrepW p = a.pw[wi];
    int c0 = (base & p.gxmask) * 32, r0 = (base >> p.gxshift) * 32;
    int tx = tid & 31, ty = tid >> 5;
#pragma unroll
    for (int i = 0; i < 4; ++i)
      t[ty + 8 * i][tx] = p.w[(size_t)(r0 + ty + 8 * i) * p.C + c0 + tx];
    __syncthreads();
#pragma unroll
    for (int i = 0; i < 4; ++i) {
      float v = t[tx][ty + 8 * i];
      u16 h = f2bf(v);
      size_t o = (size_t)(c0 + ty + 8 * i) * p.R + r0 + tx;
      p.th[o] = h;
      if (p.tl) p.tl[o] = f2bf(v - bf2f(h));
    }
    return;
  }
  b -= 3072;                            // mask -> bitmask
  size_t i = (size_t)b * 256 + tid;
  unsigned long long bb = __ballot(a.mask[i] != 0);
  if ((tid & 63) == 0) a.mbits[i >> 6] = bb;
}

// ---------------- QKV GEMM: double-buffered, x hi/lo (2 MFMA), w single bf16 ---------
// z=0 -> Qh (prescaled by log2e), z=1 -> Kh, z=2 -> Vt (transposed bf16).
struct QkvArgs {
  const u16 *Ah, *Al;
  const u16 *Bh[3];
  const float* bias[3];
  u16 *Qh, *Kh, *Vt;
};

__global__ __launch_bounds__(256) void gemm_qkv(QkvArgs a) {
  const int K = 512;
  const float L2E = 1.44269504088896340736f;
  const int z = blockIdx.z;
  const u16* __restrict__ Bh = a.Bh[z];
  const float* __restrict__ bias = a.bias[z];
  const int bn = blockIdx.x * 128, bm = blockIdx.y * 128;
  const int tid = threadIdx.x;
  const int wave = tid >> 6, lane = tid & 63;
  const int l16 = lane & 15, quad = lane >> 4;
  const int wm = (wave >> 1) * 64, wn = (wave & 1) * 64;

  __shared__ u16 sA[2][128 * 32];
  __shared__ u16 sAl[2][128 * 32];
  __shared__ u16 sB[2][128 * 32];

  const int srow = wave * 32 + (lane >> 2);
  const int scol = (lane & 3) * 8;
  const u16* srcA0 = a.Ah + (size_t)(bm + srow) * K + scol;
  const u16* srcAl0 = a.Al + (size_t)(bm + srow) * K + scol;
  const u16* srcB0 = Bh + (size_t)(bn + srow) * K + scol;
  const size_t half_off = (size_t)16 * K;

  auto prefetchG = [&](int kt, int buf) {
    u16* dA = sA[buf] + wave * 1024;
    u16* dAl = sAl[buf] + wave * 1024;
    u16* dB = sB[buf] + wave * 1024;
    gload_lds16(srcA0 + kt, dA);
    gload_lds16(srcA0 + half_off + kt, dA + 512);
    gload_lds16(srcAl0 + kt, dAl);
    gload_lds16(srcAl0 + half_off + kt, dAl + 512);
    gload_lds16(srcB0 + kt, dB);
    gload_lds16(srcB0 + half_off + kt, dB + 512);
  };

  f32x4 acc[4][4] = {};
  prefetchG(0, 0);

  for (int i = 0; i < 16; ++i) {
    __syncthreads();
    if (i + 1 < 16) prefetchG((i + 1) << 5, (i + 1) & 1);
    const u16* bufA = sA[i & 1];
    const u16* bufAl = sAl[i & 1];
    const u16* bufB = sB[i & 1];

    bf16x8 a_h[4], a_l[4], b_h[4];
#pragma unroll
    for (int mt = 0; mt < 4; ++mt) {
      a_h[mt] = *(const bf16x8*)(bufA + (wm + mt * 16 + l16) * 32 + quad * 8);
      a_l[mt] = *(const bf16x8*)(bufAl + (wm + mt * 16 + l16) * 32 + quad * 8);
    }
#pragma unroll
    for (int nt = 0; nt < 4; ++nt)
      b_h[nt] = *(const bf16x8*)(bufB + (wn + nt * 16 + l16) * 32 + quad * 8);
#pragma unroll
    for (int mt = 0; mt < 4; ++mt)
#pragma unroll
      for (int nt = 0; nt < 4; ++nt) {
        acc[mt][nt] = __builtin_amdgcn_mfma_f32_16x16x32_bf16(a_h[mt], b_h[nt], acc[mt][nt], 0, 0, 0);
        acc[mt][nt] = __builtin_amdgcn_mfma_f32_16x16x32_bf16(a_l[mt], b_h[nt], acc[mt][nt], 0, 0, 0);
      }
  }

  if (z == 2) {
    // V: write transposed bf16 Vt[dim][seq]; r-regs are seq-contiguous -> 8B stores
#pragma unroll
    for (int nt = 0; nt < 4; ++nt) {
      int col = bn + wn + nt * 16 + l16;
      float bv = bias[col];
#pragma unroll
      for (int mt = 0; mt < 4; ++mt) {
        int row0 = bm + wm + mt * 16 + quad * 4;
        u16x4 o;
#pragma unroll
        for (int r = 0; r < 4; ++r) o[r] = f2bf(acc[mt][nt][r] + bv);
        *(u16x4*)(a.Vt + (size_t)col * 4096 + row0) = o;
      }
    }
  } else {
    u16* __restrict__ C = (z == 0) ? a.Qh : a.Kh;
    float scale = (z == 0) ? L2E : 1.f;
#pragma unroll
    for (int mt = 0; mt < 4; ++mt)
#pragma unroll
      for (int nt = 0; nt < 4; ++nt) {
        int col = bn + wn + nt * 16 + l16;
        float bv = bias[col];
#pragma unroll
        for (int r = 0; r < 4; ++r) {
          int row = bm + wm + mt * 16 + quad * 4 + r;
          C[(size_t)row * 512 + col] = f2bf((acc[mt][nt][r] + bv) * scale);
        }
      }
  }
}

// ---------------- generic staged GEMM, double-buffered, optional split-K x2 ----------
// NSPLIT=2: z=0 -> Cf (with bias), z=1 -> Cf2 (no bias); consumer sums partials
// (resid_ln 3-input). No atomics, no zeroing.
template <int RELU, int BF16OUT, int NSPLIT>
__global__ __launch_bounds__(256) void gemm_bt(const u16* __restrict__ Ah,
                                               const u16* __restrict__ Bh,
                                               const float* __restrict__ bias,
                                               float* __restrict__ Cf,
                                               float* __restrict__ Cf2,
                                               u16* __restrict__ Ch,
                                               int N, int K) {
  const int z = (NSPLIT > 1) ? blockIdx.z : 0;
  const int Ksub = K / NSPLIT;
  const int kbeg = z * Ksub;
  const int bn = blockIdx.x * 128, bm = blockIdx.y * 128;
  const int tid = threadIdx.x;
  const int wave = tid >> 6, lane = tid & 63;
  const int l16 = lane & 15, quad = lane >> 4;
  const int wm = (wave >> 1) * 64, wn = (wave & 1) * 64;

  __shared__ u16 sA[2][128 * 32];
  __shared__ u16 sB[2][128 * 32];

  const int srow = wave * 32 + (lane >> 2);
  const int scol = (lane & 3) * 8;
  const u16* srcA0 = Ah + (size_t)(bm + srow) * K + kbeg + scol;
  const u16* srcB0 = Bh + (size_t)(bn + srow) * K + kbeg + scol;
  const size_t half_off = (size_t)16 * K;

  auto prefetchG = [&](int kt, int buf) {
    u16* dA = sA[buf] + wave * 1024;
    u16* dB = sB[buf] + wave * 1024;
    gload_lds16(srcA0 + kt, dA);
    gload_lds16(srcA0 + half_off + kt, dA + 512);
    gload_lds16(srcB0 + kt, dB);
    gload_lds16(srcB0 + half_off + kt, dB + 512);
  };

  f32x4 acc[4][4] = {};
  prefetchG(0, 0);

  const int steps = Ksub >> 5;
  for (int i = 0; i < steps; ++i) {
    __syncthreads();
    if (i + 1 < steps) prefetchG((i + 1) << 5, (i + 1) & 1);
    const u16* bufA = sA[i & 1];
    const u16* bufB = sB[i & 1];

    bf16x8 a_h[4], b_h[4];
#pragma unroll
    for (int mt = 0; mt < 4; ++mt)
      a_h[mt] = *(const bf16x8*)(bufA + (wm + mt * 16 + l16) * 32 + quad * 8);
#pragma unroll
    for (int nt = 0; nt < 4; ++nt)
      b_h[nt] = *(const bf16x8*)(bufB + (wn + nt * 16 + l16) * 32 + quad * 8);
#pragma unroll
    for (int mt = 0; mt < 4; ++mt)
#pragma unroll
      for (int nt = 0; nt < 4; ++nt)
        acc[mt][nt] = __builtin_amdgcn_mfma_f32_16x16x32_bf16(a_h[mt], b_h[nt], acc[mt][nt], 0, 0, 0);
  }

  float* __restrict__ Co = (NSPLIT > 1 && z == 1) ? Cf2 : Cf;
#pragma unroll
  for (int mt = 0; mt < 4; ++mt)
#pragma unroll
    for (int nt = 0; nt < 4; ++nt) {
      int col = bn + wn + nt * 16 + l16;
      float bv = (bias && z == 0) ? bias[col] : 0.f;
#pragma unroll
      for (int r = 0; r < 4; ++r) {
        int row = bm + wm + mt * 16 + quad * 4 + r;
        float v = acc[mt][nt][r] + bv;
        if (RELU) v = fmaxf(v, 0.f);
        size_t oidx = (size_t)row * N + col;
        if (BF16OUT) Ch[oidx] = f2bf(v);
        else Co[oidx] = v;
      }
    }
}

// ---------------- flash attention v9: split-phase pipeline, mask-AND, MFMA-l --------
// Grid (32 = 8h x 4chunk, 32 qb) = 1024 blocks. Per 64-key iter:
//   [A] -> issue V(it+1) (dbuf) -> QK + softmax/P half0
//   [B] -> issue K(it+1)        -> PV half0, softmax half1, PV half1
// VALU diet #2 (r12 still VALU-limited at 57% busy):
//  - mask: p_bits = fbits(v_exp(sc)) & sext(bit)  (bfe_i32+and; replaces
//    extract+cmp+cndmask and unblocks exp ILP). Masked -> +0.0 exactly.
//  - l via ones-row MFMA: sV row 64 = 1.0, 5th PV n-tile accumulates l=SUM(P)
//    (removes 24 v_add/iter + end shuffles; l sums the SAME truncated P as the
//    numerator, so truncation bias cancels in the ratio).
struct AttnIO { float* O[4]; float* lp; };

__global__ __launch_bounds__(256) void attn(const u16* __restrict__ Qh,
                                            const u16* __restrict__ Kh,
                                            const u16* __restrict__ Vt,
                                            const u64* __restrict__ mb64,
                                            AttnIO io) {
  const int S = 4096, D = 512;
  const int h = blockIdx.x >> 2, chunk = blockIdx.x & 3;
  const int tid = threadIdx.x, wave = tid >> 6, lane = tid & 63;
  const int l16 = lane & 15, quad = lane >> 4;
  const int q0w = blockIdx.y * 128 + wave * 32;
  const int kbeg = chunk * 1024;
  const int sw = l16 & 7;                       // bank-swizzle key

  __shared__ u16 sK[64 * 64];                   // [key][dim]              8 KB
  __shared__ u16 sV[2][80 * 64];                // [dim][key] dbuf, row64=1  20 KB
  __shared__ u16 sP[4][32 * 40];                // per-wave P             10 KB
  u16* myP = &sP[wave][0];

  // ones row (dim 64 -> l column) in both buffers; rows 65..79 garbage (cols unused)
  if (tid < 32) ((u64*)(sV[tid >> 4] + 64 * 64))[tid & 15] = 0x3F803F803F803F80ULL;

  const int skey = lane >> 3;
  const int sch  = lane & 7;
  const u16* srcK = Kh + (size_t)(kbeg + wave * 8 + skey) * D + h * 64 + ((sch ^ skey) * 8);
  const u16* srcV = Vt + (size_t)(h * 64 + wave * 8 + skey) * S + kbeg + ((sch ^ skey) * 8);
  u16* dstK = sK + wave * 512;

  auto stageK = [&](int it) {
    const u16* p = srcK + (size_t)it * 64 * D;
    gload_lds16(p, dstK);
    gload_lds16(p + (size_t)32 * D, dstK + 32 * 64);
  };
  auto stageV = [&](int it) {
    const u16* p = srcV + it * 64;
    u16* d = sV[it & 1] + wave * 512;
    gload_lds16(p, d);
    gload_lds16(p + (size_t)32 * S, d + 32 * 64);
  };

  // Q prefetch: B-frags (n=l16 -> q, k=quad*8 dims), single bf16 prescaled
  bf16x8 qf[2][2];
#pragma unroll
  for (int qt = 0; qt < 2; ++qt)
#pragma unroll
    for (int kd = 0; kd < 2; ++kd)
      qf[qt][kd] = *(const bf16x8*)(Qh + (size_t)(q0w + qt * 16 + l16) * D + h * 64 + kd * 32 + quad * 8);

  f32x4 accO[2][5] = {};
  const int wbase = kbeg >> 6;

  stageV(0);
  stageK(0);
  u64 wmCur[2];
#pragma unroll
  for (int qt = 0; qt < 2; ++qt)
    wmCur[qt] = mb64[(size_t)(q0w + qt * 16 + l16) * 64 + wbase];

  for (int it = 0; it < 16; ++it) {
    __syncthreads();                          // A: V(it)/K(it) staged (issued a phase ago)
    if (it + 1 < 16) stageV(it + 1);          // into the other V buffer
    u64 wmNext[2] = {0, 0};
    if (it + 1 < 16) {
#pragma unroll
      for (int qt = 0; qt < 2; ++qt)
        wmNext[qt] = mb64[(size_t)(q0w + qt * 16 + l16) * 64 + wbase + it + 1];
    }
    // hoist lane-dependent mask shift: bit (k2*16+r) of wlo/whi
    u32 wlo[2], whi[2];
#pragma unroll
    for (int qt = 0; qt < 2; ++qt) {
      wlo[qt] = (u32)(wmCur[qt] >> (quad * 4));
      whi[qt] = (u32)(wmCur[qt] >> (quad * 4 + 32));
    }

    // ---- QK phase: the ONLY sK reads ----
    f32x4 sc[4][2];
#pragma unroll
    for (int kt4 = 0; kt4 < 4; ++kt4) {
      const u16* arow = sK + (kt4 * 16 + l16) * 64;
      bf16x8 ka0 = *(const bf16x8*)(arow + ((quad ^ sw) * 8));
      bf16x8 ka1 = *(const bf16x8*)(arow + (((4 + quad) ^ sw) * 8));
#pragma unroll
      for (int qt = 0; qt < 2; ++qt) {
        f32x4 s = {};
        s = __builtin_amdgcn_mfma_f32_16x16x32_bf16(ka0, qf[qt][0], s, 0, 0, 0);
        s = __builtin_amdgcn_mfma_f32_16x16x32_bf16(ka1, qf[qt][1], s, 0, 0, 0);
        sc[kt4][qt] = s;
      }
    }
    // ---- softmax + P write, half 0 (keys 0..31) ----
#pragma unroll
    for (int k2 = 0; k2 < 2; ++k2) {
#pragma unroll
      for (int qt = 0; qt < 2; ++qt) {
        u32 pb[4];
#pragma unroll
        for (int r = 0; r < 4; ++r) {
          u32 m = (u32)((int)(wlo[qt] << (31 - (k2 * 16 + r))) >> 31);  // sext(bit)
          pb[r] = fbits(__builtin_amdgcn_exp2f(sc[k2][qt][r])) & m;
        }
        u32x2 pk = {packbits(pb[0], pb[1]), packbits(pb[2], pb[3])};
        *(u32x2*)(myP + (qt * 16 + l16) * 40 + k2 * 16 + quad * 4) = pk;
      }
    }
    __syncthreads();                          // B: all waves done with sK
    if (it + 1 < 16) stageK(it + 1);
    const u16* bV = sV[it & 1];

    // ---- PV half 0 (5 n-tiles; nt=4 = ones-row -> l) ----
    {
      bf16x8 pa[2];
#pragma unroll
      for (int qt = 0; qt < 2; ++qt)
        pa[qt] = *(const bf16x8*)(myP + (qt * 16 + l16) * 40 + quad * 8);
#pragma unroll
      for (int nt = 0; nt < 5; ++nt) {
        bf16x8 vf = *(const bf16x8*)(bV + (nt * 16 + l16) * 64 + ((quad ^ sw) * 8));
#pragma unroll
        for (int qt = 0; qt < 2; ++qt)
          accO[qt][nt] = __builtin_amdgcn_mfma_f32_16x16x32_bf16(pa[qt], vf, accO[qt][nt], 0, 0, 0);
      }
    }
    // ---- softmax + P write, half 1 (keys 32..63; same sP slots, same-wave order) ----
#pragma unroll
    for (int k2 = 0; k2 < 2; ++k2) {
#pragma unroll
      for (int qt = 0; qt < 2; ++qt) {
        u32 pb[4];
#pragma unroll
        for (int r = 0; r < 4; ++r) {
          u32 m = (u32)((int)(whi[qt] << (31 - (k2 * 16 + r))) >> 31);
          pb[r] = fbits(__builtin_amdgcn_exp2f(sc[2 + k2][qt][r])) & m;
        }
        u32x2 pk = {packbits(pb[0], pb[1]), packbits(pb[2], pb[3])};
        *(u32x2*)(myP + (qt * 16 + l16) * 40 + k2 * 16 + quad * 4) = pk;
      }
    }
    // ---- PV half 1 ----
    {
      bf16x8 pa[2];
#pragma unroll
      for (int qt = 0; qt < 2; ++qt)
        pa[qt] = *(const bf16x8*)(myP + (qt * 16 + l16) * 40 + quad * 8);
#pragma unroll
      for (int nt = 0; nt < 5; ++nt) {
        bf16x8 vf = *(const bf16x8*)(bV + (nt * 16 + l16) * 64 + (((4 + quad) ^ sw) * 8));
#pragma unroll
        for (int qt = 0; qt < 2; ++qt)
          accO[qt][nt] = __builtin_amdgcn_mfma_f32_16x16x32_bf16(pa[qt], vf, accO[qt][nt], 0, 0, 0);
      }
    }
    wmCur[0] = wmNext[0];
    wmCur[1] = wmNext[1];
  }

  float* Op = io.O[chunk];
#pragma unroll
  for (int qt = 0; qt < 2; ++qt)
#pragma unroll
    for (int nt = 0; nt < 4; ++nt)
#pragma unroll
      for (int r = 0; r < 4; ++r) {
        int row = q0w + qt * 16 + quad * 4 + r;
        Op[((size_t)h * S + row) * 64 + nt * 16 + l16] = accO[qt][nt][r];
      }
  // l lives in accO[qt][4] column 0 (n = 64 + l16 -> l16 == 0), rows quad*4+r
  if (l16 == 0)
#pragma unroll
    for (int qt = 0; qt < 2; ++qt)
#pragma unroll
      for (int r = 0; r < 4; ++r)
        io.lp[((size_t)h * 4 + chunk) * S + q0w + qt * 16 + quad * 4 + r] = accO[qt][4][r];
}

// ---------------- combine 4 split-K partials -> ctx (bf16) ----------------
__global__ __launch_bounds__(256) void attn_combine(AttnIO io, u16* __restrict__ ctx) {
  const int S = 4096;
  int i = (blockIdx.x * 256 + threadIdx.x);
  int row = i >> 7;
  int col4 = (i & 127) * 4;
  int h = col4 >> 6, c = col4 & 63;
  size_t ob = ((size_t)h * S + row) * 64 + c;
  f32x4 o = {0.f, 0.f, 0.f, 0.f};
  float l = 0.f;
#pragma unroll
  for (int p = 0; p < 4; ++p) {
    o += *(const f32x4*)(io.O[p] + ob);
    l += io.lp[((size_t)h * 4 + p) * S + row];
  }
  float rl = 1.f / l;
  u16x4 out;
#pragma unroll
  for (int j = 0; j < 4; ++j) out[j] = f2bf(o[j] * rl);
  *(u16x4*)(ctx + (size_t)row * 512 + col4) = out;
}

// ---------------- residual + layernorm (rows of 512), optional 3rd input ----------
__global__ __launch_bounds__(256) void resid_ln(const float* __restrict__ X,
                                                const float* __restrict__ Y,
                                                const float* __restrict__ Y2,
                                                const float* __restrict__ g,
                                                const float* __restrict__ b,
                                                float* __restrict__ outF,
                                                u16* __restrict__ outH) {
  int row = blockIdx.x * 4 + (int)(threadIdx.x >> 6);
  int lane = threadIdx.x & 63;
  const float* x0 = X + (size_t)row * 512;
  const float* y0 = Y + (size_t)row * 512;
  int c0 = lane * 4, c1 = 256 + lane * 4;
  f32x4 v0 = *(const f32x4*)(x0 + c0) + *(const f32x4*)(y0 + c0);
  f32x4 v1 = *(const f32x4*)(x0 + c1) + *(const f32x4*)(y0 + c1);
  if (Y2) {
    const float* y2 = Y2 + (size_t)row * 512;
    v0 += *(const f32x4*)(y2 + c0);
    v1 += *(const f32x4*)(y2 + c1);
  }
  float s = 0.f, s2 = 0.f;
#pragma unroll
  for (int j = 0; j < 4; ++j) {
    s += v0[j] + v1[j];
    s2 += v0[j] * v0[j] + v1[j] * v1[j];
  }
#pragma unroll
  for (int m = 1; m < 64; m <<= 1) {
    s += __shfl_xor(s, m);
    s2 += __shfl_xor(s2, m);
  }
  float mean = s * (1.f / 512.f);
  float var = s2 * (1.f / 512.f) - mean * mean;
  float rs = rsqrtf(var + 1e-5f);
  f32x4 o0, o1;
#pragma unroll
  for (int j = 0; j < 4; ++j) {
    o0[j] = (v0[j] - mean) * rs * g[c0 + j] + b[c0 + j];
    o1[j] = (v1[j] - mean) * rs * g[c1 + j] + b[c1 + j];
  }
  if (outF) {
    *(f32x4*)(outF + (size_t)row * 512 + c0) = o0;
    *(f32x4*)(outF + (size_t)row * 512 + c1) = o1;
  }
  if (outH) {
    u16x4 h0, h1;
#pragma unroll
    for (int j = 0; j < 4; ++j) { h0[j] = f2bf(o0[j]); h1[j] = f2bf(o1[j]); }
    *(u16x4*)(outH + (size_t)row * 512 + c0) = h0;
    *(u16x4*)(outH + (size_t)row * 512 + c1) = h1;
  }
}

extern "C" void kernel_launch(void* const* d_in, const int* in_sizes, int n_in,
                              void* d_out, int out_size, void* d_ws, size_t ws_size,
                              hipStream_t stream) {
  (void)in_sizes; (void)n_in; (void)out_size; (void)ws_size;
  const float* x   = (const float*)d_in[0];
  const int*   mask= (const int*)d_in[1];
  const float* wq  = (const float*)d_in[2];
  const float* bq  = (const float*)d_in[3];
  const float* wk  = (const float*)d_in[4];
  const float* bk  = (const float*)d_in[5];
  const float* wv  = (const float*)d_in[6];
  const float* bv  = (const float*)d_in[7];
  const float* wo  = (const float*)d_in[8];
  const float* bo  = (const float*)d_in[9];
  const float* w1  = (const float*)d_in[10];
  const float* b1  = (const float*)d_in[11];
  const float* w2  = (const float*)d_in[12];
  const float* b2  = (const float*)d_in[13];
  const float* g1  = (const float*)d_in[14];
  const float* be1 = (const float*)d_in[15];
  const float* g2  = (const float*)d_in[16];
  const float* be2 = (const float*)d_in[17];

  const int S = 4096, D = 512, F = 2048;
  char* ws = (char*)d_ws;
  size_t cur = 0;
  auto alloc = [&](size_t bytes) {
    char* p = ws + cur;
    cur += (bytes + 255) & ~(size_t)255;
    return p;
  };
  u16* wqT = (u16*)alloc((size_t)D * D * 2);
  u16* wkT = (u16*)alloc((size_t)D * D * 2);
  u16* wvT = (u16*)alloc((size_t)D * D * 2);
  u16* woT = (u16*)alloc((size_t)D * D * 2);
  u16* w1T = (u16*)alloc((size_t)D * F * 2);
  u16* w2T = (u16*)alloc((size_t)D * F * 2);
  u32* mbits = (u32*)alloc((size_t)S * S / 8);
  u16* xh = (u16*)alloc((size_t)S * D * 2);
  u16* xl = (u16*)alloc((size_t)S * D * 2);
  // Qh,Kh,Vt,hx contiguous (16MB): FF1's hbuf spans them
  u16* Qh = (u16*)alloc((size_t)S * D * 2);
  u16* Kh = (u16*)alloc((size_t)S * D * 2);
  u16* Vt = (u16*)alloc((size_t)S * D * 2);
  u16* hx = (u16*)alloc((size_t)S * D * 2); (void)hx;
  u16* ctx = (u16*)alloc((size_t)S * D * 2);
  float* x1 = (float*)alloc((size_t)S * D * 4);
  u16* x1h = (u16*)alloc((size_t)S * D * 2);
  float* Oex = (float*)alloc((size_t)2 * S * D * 4);   // O2,O3 (16MB fresh)
  // aliases (lifetimes disjoint by stream order):
  AttnIO io;
  io.O[0] = (float*)xh;            // 8MB over xh+xl (dead after QKV gemm)
  io.O[1] = x1;                    // 8MB (x1 written later by resid_ln, after combine)
  io.O[2] = Oex;
  io.O[3] = Oex + (size_t)S * D;
  io.lp = (float*)x1h;             // 512KB (x1h written later by resid_ln)
  float* proj = (float*)xh;        // OP partial 0 (after combine read O[0])
  float* projB = Oex + (size_t)S * D;  // OP partial 1 (O[3] region, after combine read)
  u16* hbuf = Qh;                  // FF1 output (16MB over Qh,Kh,Vt,hx), after attn
  float* ff2 = Oex;                // FF2 partial 0 (O[2] region, after combine read)
  float* ff2B = Oex + (size_t)S * D;   // FF2 partial 1 (O[3]; OP partial 1 dead after LN1)

  PrepArgs pa;
  pa.x = x; pa.xh = xh; pa.xl = xl;
  pa.mask = mask; pa.mbits = (unsigned long long*)mbits;
  pa.pw[0] = {wq, wqT, nullptr, D, D, 15, 4};
  pa.pw[1] = {wk, wkT, nullptr, D, D, 15, 4};
  pa.pw[2] = {wv, wvT, nullptr, D, D, 15, 4};
  pa.pw[3] = {wo, woT, nullptr, D, D, 15, 4};
  pa.pw[4] = {w1, w1T, nullptr, D, F, 63, 6};
  pa.pw[5] = {w2, w2T, nullptr, F, D, 15, 4};

  QkvArgs qa;
  qa.Ah = xh; qa.Al = xl;
  qa.Bh[0] = wqT; qa.Bh[1] = wkT; qa.Bh[2] = wvT;
  qa.bias[0] = bq; qa.bias[1] = bk; qa.bias[2] = bv;
  qa.Qh = Qh; qa.Kh = Kh; qa.Vt = Vt;

  // 1. fused prep
  prep<<<70656, 256, 0, stream>>>(pa);
  // 2. QKV projection (x hi/lo, w bf16; Q prescaled; V transposed)
  gemm_qkv<<<dim3(4, 32, 3), 256, 0, stream>>>(qa);
  // 3. flash attention (split-phase pipeline, split-K x4) + combine
  attn<<<dim3(32, 32), 256, 0, stream>>>(Qh, Kh, Vt, (const u64*)mbits, io);
  attn_combine<<<(S * D / 4) / 256, 256, 0, stream>>>(io, ctx);
  // 4. output projection, split-K x2 -> two partial buffers (256 blocks)
  gemm_bt<0, 0, 2><<<dim3(4, 32, 2), 256, 0, stream>>>(ctx, woT, bo, proj, projB, nullptr, D, D);
  // 5. residual + LN1 (x + proj0 + proj1)
  resid_ln<<<S / 4, 256, 0, stream>>>(x, proj, projB, g1, be1, x1, x1h);
  // 6. FFN: FF1 direct (512 blocks); FF2 split-K x2 (256 blocks)
  gemm_bt<1, 1, 1><<<dim3(16, 32), 256, 0, stream>>>(x1h, w1T, b1, nullptr, nullptr, hbuf, F, D);
  gemm_bt<0, 0, 2><<<dim3(4, 32, 2), 256, 0, stream>>>(hbuf, w2T, b2, ff2, ff2B, nullptr, D, F);
  // 7. residual + LN2 (x1 + ff2a + ff2b) -> final fp32 output
  resid_ln<<<S / 4, 256, 0, stream>>>(x1, ff2, ff2B, g2, be2, (float*)d_out, nullptr);
}

// Round 14
// 298.799 us; speedup vs baseline: 2.1509x; 1.0339x over previous
//
#include <hip/hip_runtime.h>

typedef unsigned short u16;
typedef unsigned int u32;
typedef unsigned long long u64;
typedef __attribute__((ext_vector_type(4))) float f32x4;
typedef __attribute__((ext_vector_type(8))) short bf16x8;   // 8 bf16 (4 VGPRs)
typedef __attribute__((ext_vector_type(4))) u16 u16x4;
typedef __attribute__((ext_vector_type(2))) u32 u32x2;

#define DEV __device__ __forceinline__

DEV u16 f2bf(float f) {               // RNE fp32 -> bf16
  union { float f; u32 u; } c; c.f = f;
  u32 u = c.u;
  u += 0x7fffu + ((u >> 16) & 1u);
  return (u16)(u >> 16);
}
DEV u32 fbits(float f) { union { float f; u32 u; } c; c.f = f; return c.u; }
// pack two truncated-bf16 (given as fp32 bit patterns) into one u32: 1x v_perm_b32
DEV u32 packbits(u32 a, u32 b) {
  return __builtin_amdgcn_perm(b, a, 0x07060302u);
}

// async global->LDS, 16B per lane. Dest is WAVE-UNIFORM base + lane*16 (m104/m108).
DEV void gload_lds16(const void* g, void* l) {
  __builtin_amdgcn_global_load_lds(
      (const __attribute__((address_space(1))) u32*)(u64)g,
      (__attribute__((address_space(3))) u32*)(u32)(u64)l,   // low 32 bits = LDS offset
      16, 0, 0);
}

// ---------------- fused prep: x->bf16 + 6 weight transposes + mask pack ----------------
struct PrepW { const float* w; u16* th; int R, C, gxmask, gxshift; };
struct PrepArgs {
  const float* x; u16* xh;
  const int* mask; unsigned long long* mbits;
  PrepW pw[6];
};

__global__ __launch_bounds__(256) void prep(PrepArgs a) {
  __shared__ float t[32][33];
  int b = blockIdx.x, tid = threadIdx.x;
  if (b < 2048) {                       // x -> bf16
    int i = (b * 256 + tid) * 4;
    f32x4 v = *(const f32x4*)(a.x + i);
    u16x4 h;
#pragma unroll
    for (int j = 0; j < 4; ++j) h[j] = f2bf(v[j]);
    *(u16x4*)(a.xh + i) = h;
    return;
  }
  b -= 2048;
  if (b < 3072) {                       // weight (R,C) -> transposed (C,R)
    int wi, base;
    if (b < 1024) { wi = b >> 8; base = b & 255; }
    else if (b < 2048) { wi = 4; base = b - 1024; }
    else { wi = 5; base = b - 2048; }
    PrepW p = a.pw[wi];
    int c0 = (base & p.gxmask) * 32, r0 = (base >> p.gxshift) * 32;
    int tx = tid & 31, ty = tid >> 5;
#pragma unroll
    for (int i = 0; i < 4; ++i)
      t[ty + 8 * i][tx] = p.w[(size_t)(r0 + ty + 8 * i) * p.C + c0 + tx];
    __syncthreads();
#pragma unroll
    for (int i = 0; i < 4; ++i)
      p.th[(size_t)(c0 + ty + 8 * i) * p.R + r0 + tx] = f2bf(t[tx][ty + 8 * i]);
    return;
  }
  b -= 3072;                            // mask -> bitmask
  size_t i = (size_t)b * 256 + tid;
  unsigned long long bb = __ballot(a.mask[i] != 0);
  if ((tid & 63) == 0) a.mbits[i >> 6] = bb;
}

// ---------------- QKV GEMM: double-buffered, single-bf16 (1 MFMA), 32KB LDS ----------
// 5 blocks/CU (was 1.5 at 48KB + 2x MFMA with the x hi/lo split).
// z=0 -> Qh (prescaled by log2e), z=1 -> Kh, z=2 -> Vt (transposed bf16).
struct QkvArgs {
  const u16* Ah;
  const u16* Bh[3];
  const float* bias[3];
  u16 *Qh, *Kh, *Vt;
};

__global__ __launch_bounds__(256) void gemm_qkv(QkvArgs a) {
  const int K = 512;
  const float L2E = 1.44269504088896340736f;
  const int z = blockIdx.z;
  const u16* __restrict__ Bh = a.Bh[z];
  const float* __restrict__ bias = a.bias[z];
  const int bn = blockIdx.x * 128, bm = blockIdx.y * 128;
  const int tid = threadIdx.x;
  const int wave = tid >> 6, lane = tid & 63;
  const int l16 = lane & 15, quad = lane >> 4;
  const int wm = (wave >> 1) * 64, wn = (wave & 1) * 64;

  __shared__ u16 sA[2][128 * 32];
  __shared__ u16 sB[2][128 * 32];

  const int srow = wave * 32 + (lane >> 2);
  const int scol = (lane & 3) * 8;
  const u16* srcA0 = a.Ah + (size_t)(bm + srow) * K + scol;
  const u16* srcB0 = Bh + (size_t)(bn + srow) * K + scol;
  const size_t half_off = (size_t)16 * K;

  auto prefetchG = [&](int kt, int buf) {
    u16* dA = sA[buf] + wave * 1024;
    u16* dB = sB[buf] + wave * 1024;
    gload_lds16(srcA0 + kt, dA);
    gload_lds16(srcA0 + half_off + kt, dA + 512);
    gload_lds16(srcB0 + kt, dB);
    gload_lds16(srcB0 + half_off + kt, dB + 512);
  };

  f32x4 acc[4][4] = {};
  prefetchG(0, 0);

  for (int i = 0; i < 16; ++i) {
    __syncthreads();
    if (i + 1 < 16) prefetchG((i + 1) << 5, (i + 1) & 1);
    const u16* bufA = sA[i & 1];
    const u16* bufB = sB[i & 1];

    bf16x8 a_h[4], b_h[4];
#pragma unroll
    for (int mt = 0; mt < 4; ++mt)
      a_h[mt] = *(const bf16x8*)(bufA + (wm + mt * 16 + l16) * 32 + quad * 8);
#pragma unroll
    for (int nt = 0; nt < 4; ++nt)
      b_h[nt] = *(const bf16x8*)(bufB + (wn + nt * 16 + l16) * 32 + quad * 8);
#pragma unroll
    for (int mt = 0; mt < 4; ++mt)
#pragma unroll
      for (int nt = 0; nt < 4; ++nt)
        acc[mt][nt] = __builtin_amdgcn_mfma_f32_16x16x32_bf16(a_h[mt], b_h[nt], acc[mt][nt], 0, 0, 0);
  }

  if (z == 2) {
    // V: write transposed bf16 Vt[dim][seq]; r-regs are seq-contiguous -> 8B stores
#pragma unroll
    for (int nt = 0; nt < 4; ++nt) {
      int col = bn + wn + nt * 16 + l16;
      float bv = bias[col];
#pragma unroll
      for (int mt = 0; mt < 4; ++mt) {
        int row0 = bm + wm + mt * 16 + quad * 4;
        u16x4 o;
#pragma unroll
        for (int r = 0; r < 4; ++r) o[r] = f2bf(acc[mt][nt][r] + bv);
        *(u16x4*)(a.Vt + (size_t)col * 4096 + row0) = o;
      }
    }
  } else {
    u16* __restrict__ C = (z == 0) ? a.Qh : a.Kh;
    float scale = (z == 0) ? L2E : 1.f;
#pragma unroll
    for (int mt = 0; mt < 4; ++mt)
#pragma unroll
      for (int nt = 0; nt < 4; ++nt) {
        int col = bn + wn + nt * 16 + l16;
        float bv = bias[col];
#pragma unroll
        for (int r = 0; r < 4; ++r) {
          int row = bm + wm + mt * 16 + quad * 4 + r;
          C[(size_t)row * 512 + col] = f2bf((acc[mt][nt][r] + bv) * scale);
        }
      }
  }
}

// ---------------- generic staged GEMM, double-buffered, optional split-K x2 ----------
template <int RELU, int BF16OUT, int NSPLIT>
__global__ __launch_bounds__(256) void gemm_bt(const u16* __restrict__ Ah,
                                               const u16* __restrict__ Bh,
                                               const float* __restrict__ bias,
                                               float* __restrict__ Cf,
                                               float* __restrict__ Cf2,
                                               u16* __restrict__ Ch,
                                               int N, int K) {
  const int z = (NSPLIT > 1) ? blockIdx.z : 0;
  const int Ksub = K / NSPLIT;
  const int kbeg = z * Ksub;
  const int bn = blockIdx.x * 128, bm = blockIdx.y * 128;
  const int tid = threadIdx.x;
  const int wave = tid >> 6, lane = tid & 63;
  const int l16 = lane & 15, quad = lane >> 4;
  const int wm = (wave >> 1) * 64, wn = (wave & 1) * 64;

  __shared__ u16 sA[2][128 * 32];
  __shared__ u16 sB[2][128 * 32];

  const int srow = wave * 32 + (lane >> 2);
  const int scol = (lane & 3) * 8;
  const u16* srcA0 = Ah + (size_t)(bm + srow) * K + kbeg + scol;
  const u16* srcB0 = Bh + (size_t)(bn + srow) * K + kbeg + scol;
  const size_t half_off = (size_t)16 * K;

  auto prefetchG = [&](int kt, int buf) {
    u16* dA = sA[buf] + wave * 1024;
    u16* dB = sB[buf] + wave * 1024;
    gload_lds16(srcA0 + kt, dA);
    gload_lds16(srcA0 + half_off + kt, dA + 512);
    gload_lds16(srcB0 + kt, dB);
    gload_lds16(srcB0 + half_off + kt, dB + 512);
  };

  f32x4 acc[4][4] = {};
  prefetchG(0, 0);

  const int steps = Ksub >> 5;
  for (int i = 0; i < steps; ++i) {
    __syncthreads();
    if (i + 1 < steps) prefetchG((i + 1) << 5, (i + 1) & 1);
    const u16* bufA = sA[i & 1];
    const u16* bufB = sB[i & 1];

    bf16x8 a_h[4], b_h[4];
#pragma unroll
    for (int mt = 0; mt < 4; ++mt)
      a_h[mt] = *(const bf16x8*)(bufA + (wm + mt * 16 + l16) * 32 + quad * 8);
#pragma unroll
    for (int nt = 0; nt < 4; ++nt)
      b_h[nt] = *(const bf16x8*)(bufB + (wn + nt * 16 + l16) * 32 + quad * 8);
#pragma unroll
    for (int mt = 0; mt < 4; ++mt)
#pragma unroll
      for (int nt = 0; nt < 4; ++nt)
        acc[mt][nt] = __builtin_amdgcn_mfma_f32_16x16x32_bf16(a_h[mt], b_h[nt], acc[mt][nt], 0, 0, 0);
  }

  float* __restrict__ Co = (NSPLIT > 1 && z == 1) ? Cf2 : Cf;
#pragma unroll
  for (int mt = 0; mt < 4; ++mt)
#pragma unroll
    for (int nt = 0; nt < 4; ++nt) {
      int col = bn + wn + nt * 16 + l16;
      float bv = (bias && z == 0) ? bias[col] : 0.f;
#pragma unroll
      for (int r = 0; r < 4; ++r) {
        int row = bm + wm + mt * 16 + quad * 4 + r;
        float v = acc[mt][nt][r] + bv;
        if (RELU) v = fmaxf(v, 0.f);
        size_t oidx = (size_t)row * N + col;
        if (BF16OUT) Ch[oidx] = f2bf(v);
        else Co[oidx] = v;
      }
    }
}

// ---------------- flash attention v9 (frozen from r13) ----------------
struct AttnIO { float* O[4]; float* lp; };

__global__ __launch_bounds__(256) void attn(const u16* __restrict__ Qh,
                                            const u16* __restrict__ Kh,
                                            const u16* __restrict__ Vt,
                                            const u64* __restrict__ mb64,
                                            AttnIO io) {
  const int S = 4096, D = 512;
  const int h = blockIdx.x >> 2, chunk = blockIdx.x & 3;
  const int tid = threadIdx.x, wave = tid >> 6, lane = tid & 63;
  const int l16 = lane & 15, quad = lane >> 4;
  const int q0w = blockIdx.y * 128 + wave * 32;
  const int kbeg = chunk * 1024;
  const int sw = l16 & 7;                       // bank-swizzle key

  __shared__ u16 sK[64 * 64];                   // [key][dim]              8 KB
  __shared__ u16 sV[2][80 * 64];                // [dim][key] dbuf, row64=1  20 KB
  __shared__ u16 sP[4][32 * 40];                // per-wave P             10 KB
  u16* myP = &sP[wave][0];

  // ones row (dim 64 -> l column) in both buffers; rows 65..79 garbage (cols unused)
  if (tid < 32) ((u64*)(sV[tid >> 4] + 64 * 64))[tid & 15] = 0x3F803F803F803F80ULL;

  const int skey = lane >> 3;
  const int sch  = lane & 7;
  const u16* srcK = Kh + (size_t)(kbeg + wave * 8 + skey) * D + h * 64 + ((sch ^ skey) * 8);
  const u16* srcV = Vt + (size_t)(h * 64 + wave * 8 + skey) * S + kbeg + ((sch ^ skey) * 8);
  u16* dstK = sK + wave * 512;

  auto stageK = [&](int it) {
    const u16* p = srcK + (size_t)it * 64 * D;
    gload_lds16(p, dstK);
    gload_lds16(p + (size_t)32 * D, dstK + 32 * 64);
  };
  auto stageV = [&](int it) {
    const u16* p = srcV + it * 64;
    u16* d = sV[it & 1] + wave * 512;
    gload_lds16(p, d);
    gload_lds16(p + (size_t)32 * S, d + 32 * 64);
  };

  // Q prefetch: B-frags (n=l16 -> q, k=quad*8 dims), single bf16 prescaled
  bf16x8 qf[2][2];
#pragma unroll
  for (int qt = 0; qt < 2; ++qt)
#pragma unroll
    for (int kd = 0; kd < 2; ++kd)
      qf[qt][kd] = *(const bf16x8*)(Qh + (size_t)(q0w + qt * 16 + l16) * D + h * 64 + kd * 32 + quad * 8);

  f32x4 accO[2][5] = {};
  const int wbase = kbeg >> 6;

  stageV(0);
  stageK(0);
  u64 wmCur[2];
#pragma unroll
  for (int qt = 0; qt < 2; ++qt)
    wmCur[qt] = mb64[(size_t)(q0w + qt * 16 + l16) * 64 + wbase];

  for (int it = 0; it < 16; ++it) {
    __syncthreads();                          // A: V(it)/K(it) staged (issued a phase ago)
    if (it + 1 < 16) stageV(it + 1);          // into the other V buffer
    u64 wmNext[2] = {0, 0};
    if (it + 1 < 16) {
#pragma unroll
      for (int qt = 0; qt < 2; ++qt)
        wmNext[qt] = mb64[(size_t)(q0w + qt * 16 + l16) * 64 + wbase + it + 1];
    }
    // hoist lane-dependent mask shift: bit (k2*16+r) of wlo/whi
    u32 wlo[2], whi[2];
#pragma unroll
    for (int qt = 0; qt < 2; ++qt) {
      wlo[qt] = (u32)(wmCur[qt] >> (quad * 4));
      whi[qt] = (u32)(wmCur[qt] >> (quad * 4 + 32));
    }

    // ---- QK phase: the ONLY sK reads ----
    f32x4 sc[4][2];
#pragma unroll
    for (int kt4 = 0; kt4 < 4; ++kt4) {
      const u16* arow = sK + (kt4 * 16 + l16) * 64;
      bf16x8 ka0 = *(const bf16x8*)(arow + ((quad ^ sw) * 8));
      bf16x8 ka1 = *(const bf16x8*)(arow + (((4 + quad) ^ sw) * 8));
#pragma unroll
      for (int qt = 0; qt < 2; ++qt) {
        f32x4 s = {};
        s = __builtin_amdgcn_mfma_f32_16x16x32_bf16(ka0, qf[qt][0], s, 0, 0, 0);
        s = __builtin_amdgcn_mfma_f32_16x16x32_bf16(ka1, qf[qt][1], s, 0, 0, 0);
        sc[kt4][qt] = s;
      }
    }
    // ---- softmax + P write, half 0 (keys 0..31) ----
#pragma unroll
    for (int k2 = 0; k2 < 2; ++k2) {
#pragma unroll
      for (int qt = 0; qt < 2; ++qt) {
        u32 pb[4];
#pragma unroll
        for (int r = 0; r < 4; ++r) {
          u32 m = (u32)((int)(wlo[qt] << (31 - (k2 * 16 + r))) >> 31);  // sext(bit)
          pb[r] = fbits(__builtin_amdgcn_exp2f(sc[k2][qt][r])) & m;
        }
        u32x2 pk = {packbits(pb[0], pb[1]), packbits(pb[2], pb[3])};
        *(u32x2*)(myP + (qt * 16 + l16) * 40 + k2 * 16 + quad * 4) = pk;
      }
    }
    __syncthreads();                          // B: all waves done with sK
    if (it + 1 < 16) stageK(it + 1);
    const u16* bV = sV[it & 1];

    // ---- PV half 0 (5 n-tiles; nt=4 = ones-row -> l) ----
    {
      bf16x8 pa[2];
#pragma unroll
      for (int qt = 0; qt < 2; ++qt)
        pa[qt] = *(const bf16x8*)(myP + (qt * 16 + l16) * 40 + quad * 8);
#pragma unroll
      for (int nt = 0; nt < 5; ++nt) {
        bf16x8 vf = *(const bf16x8*)(bV + (nt * 16 + l16) * 64 + ((quad ^ sw) * 8));
#pragma unroll
        for (int qt = 0; qt < 2; ++qt)
          accO[qt][nt] = __builtin_amdgcn_mfma_f32_16x16x32_bf16(pa[qt], vf, accO[qt][nt], 0, 0, 0);
      }
    }
    // ---- softmax + P write, half 1 (keys 32..63) ----
#pragma unroll
    for (int k2 = 0; k2 < 2; ++k2) {
#pragma unroll
      for (int qt = 0; qt < 2; ++qt) {
        u32 pb[4];
#pragma unroll
        for (int r = 0; r < 4; ++r) {
          u32 m = (u32)((int)(whi[qt] << (31 - (k2 * 16 + r))) >> 31);
          pb[r] = fbits(__builtin_amdgcn_exp2f(sc[2 + k2][qt][r])) & m;
        }
        u32x2 pk = {packbits(pb[0], pb[1]), packbits(pb[2], pb[3])};
        *(u32x2*)(myP + (qt * 16 + l16) * 40 + k2 * 16 + quad * 4) = pk;
      }
    }
    // ---- PV half 1 ----
    {
      bf16x8 pa[2];
#pragma unroll
      for (int qt = 0; qt < 2; ++qt)
        pa[qt] = *(const bf16x8*)(myP + (qt * 16 + l16) * 40 + quad * 8);
#pragma unroll
      for (int nt = 0; nt < 5; ++nt) {
        bf16x8 vf = *(const bf16x8*)(bV + (nt * 16 + l16) * 64 + (((4 + quad) ^ sw) * 8));
#pragma unroll
        for (int qt = 0; qt < 2; ++qt)
          accO[qt][nt] = __builtin_amdgcn_mfma_f32_16x16x32_bf16(pa[qt], vf, accO[qt][nt], 0, 0, 0);
      }
    }
    wmCur[0] = wmNext[0];
    wmCur[1] = wmNext[1];
  }

  float* Op = io.O[chunk];
#pragma unroll
  for (int qt = 0; qt < 2; ++qt)
#pragma unroll
    for (int nt = 0; nt < 4; ++nt)
#pragma unroll
      for (int r = 0; r < 4; ++r) {
        int row = q0w + qt * 16 + quad * 4 + r;
        Op[((size_t)h * S + row) * 64 + nt * 16 + l16] = accO[qt][nt][r];
      }
  // l lives in accO[qt][4] column 0 (l16 == 0), rows quad*4+r
  if (l16 == 0)
#pragma unroll
    for (int qt = 0; qt < 2; ++qt)
#pragma unroll
      for (int r = 0; r < 4; ++r)
        io.lp[((size_t)h * 4 + chunk) * S + q0w + qt * 16 + quad * 4 + r] = accO[qt][4][r];
}

// ---------------- combine 4 split-K partials -> ctx (bf16) ----------------
__global__ __launch_bounds__(256) void attn_combine(AttnIO io, u16* __restrict__ ctx) {
  const int S = 4096;
  int i = (blockIdx.x * 256 + threadIdx.x);
  int row = i >> 7;
  int col4 = (i & 127) * 4;
  int h = col4 >> 6, c = col4 & 63;
  size_t ob = ((size_t)h * S + row) * 64 + c;
  f32x4 o = {0.f, 0.f, 0.f, 0.f};
  float l = 0.f;
#pragma unroll
  for (int p = 0; p < 4; ++p) {
    o += *(const f32x4*)(io.O[p] + ob);
    l += io.lp[((size_t)h * 4 + p) * S + row];
  }
  float rl = 1.f / l;
  u16x4 out;
#pragma unroll
  for (int j = 0; j < 4; ++j) out[j] = f2bf(o[j] * rl);
  *(u16x4*)(ctx + (size_t)row * 512 + col4) = out;
}

// ---------------- residual + layernorm (rows of 512), optional 3rd input ----------
__global__ __launch_bounds__(256) void resid_ln(const float* __restrict__ X,
                                                const float* __restrict__ Y,
                                                const float* __restrict__ Y2,
                                                const float* __restrict__ g,
                                                const float* __restrict__ b,
                                                float* __restrict__ outF,
                                                u16* __restrict__ outH) {
  int row = blockIdx.x * 4 + (int)(threadIdx.x >> 6);
  int lane = threadIdx.x & 63;
  const float* x0 = X + (size_t)row * 512;
  const float* y0 = Y + (size_t)row * 512;
  int c0 = lane * 4, c1 = 256 + lane * 4;
  f32x4 v0 = *(const f32x4*)(x0 + c0) + *(const f32x4*)(y0 + c0);
  f32x4 v1 = *(const f32x4*)(x0 + c1) + *(const f32x4*)(y0 + c1);
  if (Y2) {
    const float* y2 = Y2 + (size_t)row * 512;
    v0 += *(const f32x4*)(y2 + c0);
    v1 += *(const f32x4*)(y2 + c1);
  }
  float s = 0.f, s2 = 0.f;
#pragma unroll
  for (int j = 0; j < 4; ++j) {
    s += v0[j] + v1[j];
    s2 += v0[j] * v0[j] + v1[j] * v1[j];
  }
#pragma unroll
  for (int m = 1; m < 64; m <<= 1) {
    s += __shfl_xor(s, m);
    s2 += __shfl_xor(s2, m);
  }
  float mean = s * (1.f / 512.f);
  float var = s2 * (1.f / 512.f) - mean * mean;
  float rs = rsqrtf(var + 1e-5f);
  f32x4 o0, o1;
#pragma unroll
  for (int j = 0; j < 4; ++j) {
    o0[j] = (v0[j] - mean) * rs * g[c0 + j] + b[c0 + j];
    o1[j] = (v1[j] - mean) * rs * g[c1 + j] + b[c1 + j];
  }
  if (outF) {
    *(f32x4*)(outF + (size_t)row * 512 + c0) = o0;
    *(f32x4*)(outF + (size_t)row * 512 + c1) = o1;
  }
  if (outH) {
    u16x4 h0, h1;
#pragma unroll
    for (int j = 0; j < 4; ++j) { h0[j] = f2bf(o0[j]); h1[j] = f2bf(o1[j]); }
    *(u16x4*)(outH + (size_t)row * 512 + c0) = h0;
    *(u16x4*)(outH + (size_t)row * 512 + c1) = h1;
  }
}

extern "C" void kernel_launch(void* const* d_in, const int* in_sizes, int n_in,
                              void* d_out, int out_size, void* d_ws, size_t ws_size,
                              hipStream_t stream) {
  (void)in_sizes; (void)n_in; (void)out_size; (void)ws_size;
  const float* x   = (const float*)d_in[0];
  const int*   mask= (const int*)d_in[1];
  const float* wq  = (const float*)d_in[2];
  const float* bq  = (const float*)d_in[3];
  const float* wk  = (const float*)d_in[4];
  const float* bk  = (const float*)d_in[5];
  const float* wv  = (const float*)d_in[6];
  const float* bv  = (const float*)d_in[7];
  const float* wo  = (const float*)d_in[8];
  const float* bo  = (const float*)d_in[9];
  const float* w1  = (const float*)d_in[10];
  const float* b1  = (const float*)d_in[11];
  const float* w2  = (const float*)d_in[12];
  const float* b2  = (const float*)d_in[13];
  const float* g1  = (const float*)d_in[14];
  const float* be1 = (const float*)d_in[15];
  const float* g2  = (const float*)d_in[16];
  const float* be2 = (const float*)d_in[17];

  const int S = 4096, D = 512, F = 2048;
  char* ws = (char*)d_ws;
  size_t cur = 0;
  auto alloc = [&](size_t bytes) {
    char* p = ws + cur;
    cur += (bytes + 255) & ~(size_t)255;
    return p;
  };
  u16* wqT = (u16*)alloc((size_t)D * D * 2);
  u16* wkT = (u16*)alloc((size_t)D * D * 2);
  u16* wvT = (u16*)alloc((size_t)D * D * 2);
  u16* woT = (u16*)alloc((size_t)D * D * 2);
  u16* w1T = (u16*)alloc((size_t)D * F * 2);
  u16* w2T = (u16*)alloc((size_t)D * F * 2);
  u32* mbits = (u32*)alloc((size_t)S * S / 8);
  u16* xh = (u16*)alloc((size_t)S * D * 2);
  // Qh,Kh,Vt,hx contiguous (16MB): FF1's hbuf spans them
  u16* Qh = (u16*)alloc((size_t)S * D * 2);
  u16* Kh = (u16*)alloc((size_t)S * D * 2);
  u16* Vt = (u16*)alloc((size_t)S * D * 2);
  u16* hx = (u16*)alloc((size_t)S * D * 2); (void)hx;
  u16* ctx = (u16*)alloc((size_t)S * D * 2);
  float* x1 = (float*)alloc((size_t)S * D * 4);
  u16* x1h = (u16*)alloc((size_t)S * D * 2);
  float* Opart0 = (float*)alloc((size_t)S * D * 4);    // O0 (8MB fresh)
  float* Oex = (float*)alloc((size_t)2 * S * D * 4);   // O2,O3 (16MB fresh)
  // aliases (lifetimes disjoint by stream order):
  AttnIO io;
  io.O[0] = Opart0;
  io.O[1] = x1;                    // 8MB (x1 written later by resid_ln, after combine)
  io.O[2] = Oex;
  io.O[3] = Oex + (size_t)S * D;
  io.lp = (float*)x1h;             // 512KB (x1h written later by resid_ln)
  float* proj = Opart0;            // OP partial 0 (after combine read O[0])
  float* projB = Oex + (size_t)S * D;  // OP partial 1 (O[3] region, after combine read)
  u16* hbuf = Qh;                  // FF1 output (16MB over Qh,Kh,Vt,hx), after attn
  float* ff2 = Oex;                // FF2 partial 0 (O[2] region, after combine read)
  float* ff2B = Oex + (size_t)S * D;   // FF2 partial 1 (O[3]; OP partial 1 dead after LN1)

  PrepArgs pa;
  pa.x = x; pa.xh = xh;
  pa.mask = mask; pa.mbits = (unsigned long long*)mbits;
  pa.pw[0] = {wq, wqT, D, D, 15, 4};
  pa.pw[1] = {wk, wkT, D, D, 15, 4};
  pa.pw[2] = {wv, wvT, D, D, 15, 4};
  pa.pw[3] = {wo, woT, D, D, 15, 4};
  pa.pw[4] = {w1, w1T, D, F, 63, 6};
  pa.pw[5] = {w2, w2T, F, D, 15, 4};

  QkvArgs qa;
  qa.Ah = xh;
  qa.Bh[0] = wqT; qa.Bh[1] = wkT; qa.Bh[2] = wvT;
  qa.bias[0] = bq; qa.bias[1] = bk; qa.bias[2] = bv;
  qa.Qh = Qh; qa.Kh = Kh; qa.Vt = Vt;

  // 1. fused prep
  prep<<<70656, 256, 0, stream>>>(pa);
  // 2. QKV projection (single bf16; Q prescaled; V transposed)
  gemm_qkv<<<dim3(4, 32, 3), 256, 0, stream>>>(qa);
  // 3. flash attention (split-phase pipeline, split-K x4) + combine
  attn<<<dim3(32, 32), 256, 0, stream>>>(Qh, Kh, Vt, (const u64*)mbits, io);
  attn_combine<<<(S * D / 4) / 256, 256, 0, stream>>>(io, ctx);
  // 4. output projection, split-K x2 -> two partial buffers (256 blocks)
  gemm_bt<0, 0, 2><<<dim3(4, 32, 2), 256, 0, stream>>>(ctx, woT, bo, proj, projB, nullptr, D, D);
  // 5. residual + LN1 (x + proj0 + proj1)
  resid_ln<<<S / 4, 256, 0, stream>>>(x, proj, projB, g1, be1, x1, x1h);
  // 6. FFN: FF1 direct (512 blocks); FF2 split-K x2 (256 blocks)
  gemm_bt<1, 1, 1><<<dim3(16, 32), 256, 0, stream>>>(x1h, w1T, b1, nullptr, nullptr, hbuf, F, D);
  gemm_bt<0, 0, 2><<<dim3(4, 32, 2), 256, 0, stream>>>(hbuf, w2T, b2, ff2, ff2B, nullptr, D, F);
  // 7. residual + LN2 (x1 + ff2a + ff2b) -> final fp32 output
  resid_ln<<<S / 4, 256, 0, stream>>>(x1, ff2, ff2B, g2, be2, (float*)d_out, nullptr);
}